// Round 2
// baseline (7203.567 us; speedup 1.0000x reference)
//
#include <hip/hip_runtime.h>
#include <hip/hip_bf16.h>
#include <math.h>

typedef __hip_bfloat16 bf16;

#define BB   256
#define W1c  1280
#define W2c  160
#define W3c  20
#define C0c  2
#define C1c  64
#define C2c  128
#define KKc  11
#define PPc  5
#define LLc  8
#define DDc  64
#define GSc  32   // BB/LLc rows per label per side

// ---------------- encoder conv1: x[B,2,1280] -> relu -> back1 (bf16) ----------------
__global__ void conv1_k(const float* __restrict__ x, const float* __restrict__ w,
                        const float* __restrict__ bias, bf16* __restrict__ out) {
  int idx = blockIdx.x * 256 + threadIdx.x;           // B*64*1280 threads
  int wp = idx % W1c;
  int oc = (idx / W1c) % C1c;
  int b  = idx / (W1c * C1c);
  const float* xb = x + b * C0c * W1c;
  const float* wk = w + oc * C0c * KKc;
  float s = bias[oc];
#pragma unroll
  for (int k = 0; k < KKc; k++) {
    int p = wp - PPc + k;
    if (p >= 0 && p < W1c) s += xb[p] * wk[k] + xb[W1c + p] * wk[KKc + k];
  }
  out[idx] = __float2bfloat16(fmaxf(s, 0.f));
}

// ---------------- maxpool8 bf16 -> f32 ----------------
__global__ void pool8_bf16_k(const bf16* __restrict__ in, float* __restrict__ out,
                             int total, int Wout) {
  int idx = blockIdx.x * 256 + threadIdx.x;
  if (idx >= total) return;
  int wo = idx % Wout;
  int bc = idx / Wout;
  const bf16* p = in + (size_t)bc * Wout * 8 + wo * 8;
  float m = __bfloat162float(p[0]);
#pragma unroll
  for (int j = 1; j < 8; j++) m = fmaxf(m, __bfloat162float(p[j]));
  out[idx] = m;
}

// ---------------- maxpool8 f32 -> f32 ----------------
__global__ void pool8_f32_k(const float* __restrict__ in, float* __restrict__ out,
                            int total, int Wout) {
  int idx = blockIdx.x * 256 + threadIdx.x;
  if (idx >= total) return;
  int wo = idx % Wout;
  int bc = idx / Wout;
  const float* p = in + (size_t)bc * Wout * 8 + wo * 8;
  float m = p[0];
#pragma unroll
  for (int j = 1; j < 8; j++) m = fmaxf(m, p[j]);
  out[idx] = m;
}

// ---------------- encoder conv2: pool1[B,64,160] -> relu -> back2[B,128,160] ----------------
// thread computes 8 consecutive w outputs for one (b, oc)
__global__ void conv2_k(const float* __restrict__ in, const float* __restrict__ w,
                        const float* __restrict__ bias, float* __restrict__ out) {
  int idx = blockIdx.x * 256 + threadIdx.x;           // B*128*20 threads
  int wg = idx % (W2c / 8);
  int oc = (idx / (W2c / 8)) % C2c;
  int b  = idx / ((W2c / 8) * C2c);
  int w0 = wg * 8;
  float acc[8];
  float bv = bias[oc];
#pragma unroll
  for (int r = 0; r < 8; r++) acc[r] = bv;
  const float* inb  = in + (size_t)b * C1c * W2c;
  const float* wrow = w + (size_t)oc * C1c * KKc;
  for (int ic = 0; ic < C1c; ic++) {
    const float* ip = inb + ic * W2c;
    float win[18];
#pragma unroll
    for (int j = 0; j < 18; j++) {
      int p = w0 - PPc + j;
      win[j] = (p >= 0 && p < W2c) ? ip[p] : 0.f;
    }
#pragma unroll
    for (int k = 0; k < KKc; k++) {
      float wv = wrow[ic * KKc + k];
#pragma unroll
      for (int r = 0; r < 8; r++) acc[r] += win[k + r] * wv;
    }
  }
  float* op = out + ((size_t)b * C2c + oc) * W2c + w0;
#pragma unroll
  for (int r = 0; r < 8; r++) op[r] = fmaxf(acc[r], 0.f);
}

// ---------------- generic FC: out[b,o] = act(dot(in[b,:K], W[o,:K]) + bias[o]) ----------------
__global__ void fc_k(const float* __restrict__ in, const float* __restrict__ wt,
                     const float* __restrict__ bias, float* __restrict__ out,
                     int Bn, int On, int Kn, int act) {  // act: 0=relu 1=sigmoid
  int idx = blockIdx.x * 256 + threadIdx.x;
  if (idx >= Bn * On) return;
  int o = idx % On;
  int b = idx / On;
  const float4* a  = (const float4*)(in + (size_t)b * Kn);
  const float4* wv = (const float4*)(wt + (size_t)o * Kn);
  float s = 0.f;
  int n4 = Kn >> 2;
  for (int i = 0; i < n4; i++) {
    float4 av = a[i], bv = wv[i];
    s += av.x * bv.x + av.y * bv.y + av.z * bv.z + av.w * bv.w;
  }
  s += bias[o];
  if (act == 0) s = fmaxf(s, 0.f);
  else          s = 1.f / (1.f + expf(-s));
  out[idx] = s;
}

// ---------------- decoder conv2: concat(upsample8(df2[B,128,20]), back2[B,128,160]) -> [B,64,160] ----------------
__global__ void convd2_k(const float* __restrict__ up, const float* __restrict__ skip,
                         const float* __restrict__ w, const float* __restrict__ bias,
                         float* __restrict__ out) {
  int idx = blockIdx.x * 256 + threadIdx.x;           // B*64*20 threads
  int wg = idx % (W2c / 8);
  int oc = (idx / (W2c / 8)) % C1c;
  int b  = idx / ((W2c / 8) * C1c);
  int w0 = wg * 8;
  float acc[8];
  float bv = bias[oc];
#pragma unroll
  for (int r = 0; r < 8; r++) acc[r] = bv;
  const float* wrow = w + (size_t)oc * (2 * C2c) * KKc;
  // first 128 input channels: nearest-upsample of df2
  const float* ub = up + (size_t)b * C2c * W3c;
  for (int ic = 0; ic < C2c; ic++) {
    const float* us = ub + ic * W3c;
    float win[18];
#pragma unroll
    for (int j = 0; j < 18; j++) {
      int p = w0 - PPc + j;
      win[j] = (p >= 0 && p < W2c) ? us[p >> 3] : 0.f;
    }
#pragma unroll
    for (int k = 0; k < KKc; k++) {
      float wv = wrow[ic * KKc + k];
#pragma unroll
      for (int r = 0; r < 8; r++) acc[r] += win[k + r] * wv;
    }
  }
  // second 128 input channels: back2 skip
  const float* sb = skip + (size_t)b * C2c * W2c;
  for (int ic = 0; ic < C2c; ic++) {
    const float* sp = sb + ic * W2c;
    float win[18];
#pragma unroll
    for (int j = 0; j < 18; j++) {
      int p = w0 - PPc + j;
      win[j] = (p >= 0 && p < W2c) ? sp[p] : 0.f;
    }
#pragma unroll
    for (int k = 0; k < KKc; k++) {
      float wv = wrow[(C2c + ic) * KKc + k];
#pragma unroll
      for (int r = 0; r < 8; r++) acc[r] += win[k + r] * wv;
    }
  }
  float* op = out + ((size_t)b * C1c + oc) * W2c + w0;
#pragma unroll
  for (int r = 0; r < 8; r++) op[r] = fmaxf(acc[r], 0.f);
}

// ---------------- decoder conv1: concat(upsample8(dc2[B,64,160]), back1[B,64,1280]) -> [B,2,1280] ----------------
__global__ void convd1_k(const float* __restrict__ up, const bf16* __restrict__ skip,
                         const float* __restrict__ w, const float* __restrict__ bias,
                         float* __restrict__ out) {
  int idx = blockIdx.x * 256 + threadIdx.x;           // B*2*160 threads
  int wg = idx % (W1c / 8);
  int oc = (idx / (W1c / 8)) % C0c;
  int b  = idx / ((W1c / 8) * C0c);
  int w0 = wg * 8;
  float acc[8];
  float bv = bias[oc];
#pragma unroll
  for (int r = 0; r < 8; r++) acc[r] = bv;
  const float* wrow = w + (size_t)oc * C2c * KKc;
  const float* ub = up + (size_t)b * C1c * W2c;
  for (int ic = 0; ic < C1c; ic++) {
    const float* us = ub + ic * W2c;
    float win[18];
#pragma unroll
    for (int j = 0; j < 18; j++) {
      int p = w0 - PPc + j;
      win[j] = (p >= 0 && p < W1c) ? us[p >> 3] : 0.f;
    }
#pragma unroll
    for (int k = 0; k < KKc; k++) {
      float wv = wrow[ic * KKc + k];
#pragma unroll
      for (int r = 0; r < 8; r++) acc[r] += win[k + r] * wv;
    }
  }
  const bf16* sb = skip + (size_t)b * C1c * W1c;
  for (int ic = 0; ic < C1c; ic++) {
    const bf16* sp = sb + (size_t)ic * W1c;
    float win[18];
#pragma unroll
    for (int j = 0; j < 18; j++) {
      int p = w0 - PPc + j;
      win[j] = (p >= 0 && p < W1c) ? __bfloat162float(sp[p]) : 0.f;
    }
#pragma unroll
    for (int k = 0; k < KKc; k++) {
      float wv = wrow[(C1c + ic) * KKc + k];
#pragma unroll
      for (int r = 0; r < 8; r++) acc[r] += win[k + r] * wv;
    }
  }
  float* op = out + ((size_t)b * C0c + oc) * W1c + w0;
#pragma unroll
  for (int r = 0; r < 8; r++) op[r] = fmaxf(acc[r], 0.f);
}

// ---------------- KL part 1: stable group-by-label, build T and logT [8,64,64] ----------------
__global__ void kl_build_k(const float* __restrict__ fea_s, const float* __restrict__ fea_t,
                           const int* __restrict__ lab_s, const int* __restrict__ lab_t,
                           float* __restrict__ T, float* __restrict__ logT) {
  __shared__ int srt_s[BB], srt_t[BB];
  int t = threadIdx.x;
  {
    int lab = lab_s[t];
    int pos = 0;
    for (int b = 0; b < BB; b++) {
      int lb = lab_s[b];
      pos += (lb < lab) + ((b < t) && (lb == lab));
    }
    srt_s[pos] = t;
  }
  {
    int lab = lab_t[t];
    int pos = 0;
    for (int b = 0; b < BB; b++) {
      int lb = lab_t[b];
      pos += (lb < lab) + ((b < t) && (lb == lab));
    }
    srt_t[pos] = t;
  }
  __syncthreads();
  const int total = LLc * 2 * GSc * DDc;              // 32768
  for (int e = t; e < total; e += BB) {
    int d = e & 63;
    int m = (e >> 6) & 63;
    int l = e >> 12;
    float v;
    if (m < GSc) v = fea_s[srt_s[l * GSc + m] * DDc + d];
    else         v = fea_t[srt_t[l * GSc + (m - GSc)] * DDc + d];
    T[e]    = v;
    logT[e] = logf(v);
  }
}

// ---------------- KL part 2: kl = (L*tr(C) - sum(C)) / 4096 / (L*L/2) ----------------
__global__ void kl_reduce_k(const float* __restrict__ T, const float* __restrict__ logT,
                            float* __restrict__ out) {
  int t = threadIdx.x;
  __shared__ float wsum[4];
  __shared__ float acc_tr, acc_tot;
  if (t == 0) { acc_tr = 0.f; acc_tot = 0.f; }
  __syncthreads();
  for (int i = 0; i < LLc; i++) {
    for (int j = 0; j < LLc; j++) {
      const float* li = logT + i * 4096;
      const float* tj = T + j * 4096;
      float s = 0.f;
      for (int e = t; e < 4096; e += BB) s += li[e] * tj[e];
      for (int off = 32; off > 0; off >>= 1) s += __shfl_down(s, off, 64);
      if ((t & 63) == 0) wsum[t >> 6] = s;
      __syncthreads();
      if (t == 0) {
        float v = wsum[0] + wsum[1] + wsum[2] + wsum[3];
        acc_tot += v;
        if (i == j) acc_tr += v;
      }
      __syncthreads();
    }
  }
  if (t == 0) {
    float kl = (LLc * acc_tr - acc_tot) / 4096.f / (LLc * LLc / 2.0f);
    out[0] = kl;
  }
}

extern "C" void kernel_launch(void* const* d_in, const int* in_sizes, int n_in,
                              void* d_out, int out_size, void* d_ws, size_t ws_size,
                              hipStream_t stream) {
  const float* x_s  = (const float*)d_in[0];
  const float* x_t  = (const float*)d_in[1];
  const int* lab_s  = (const int*)d_in[2];
  const int* lab_t  = (const int*)d_in[3];
  const float* ec1w = (const float*)d_in[5];  const float* ec1b = (const float*)d_in[6];
  const float* ec2w = (const float*)d_in[7];  const float* ec2b = (const float*)d_in[8];
  const float* ef1w = (const float*)d_in[9];  const float* ef1b = (const float*)d_in[10];
  const float* ef2w = (const float*)d_in[11]; const float* ef2b = (const float*)d_in[12];
  const float* df1w = (const float*)d_in[13]; const float* df1b = (const float*)d_in[14];
  const float* df2w = (const float*)d_in[15]; const float* df2b = (const float*)d_in[16];
  const float* dc2w = (const float*)d_in[17]; const float* dc2b = (const float*)d_in[18];
  const float* dc1w = (const float*)d_in[19]; const float* dc1b = (const float*)d_in[20];

  char* p = (char*)d_ws;
  auto alloc = [&](size_t bytes) -> char* {
    char* r = p;
    p += (bytes + 255) & ~(size_t)255;
    return r;
  };
  bf16*  back1_s = (bf16*)alloc((size_t)BB * C1c * W1c * 2);
  bf16*  back1_t = (bf16*)alloc((size_t)BB * C1c * W1c * 2);
  float* pool1_s = (float*)alloc((size_t)BB * C1c * W2c * 4);
  float* pool1_t = (float*)alloc((size_t)BB * C1c * W2c * 4);
  float* back2_s = (float*)alloc((size_t)BB * C2c * W2c * 4);
  float* back2_t = (float*)alloc((size_t)BB * C2c * W2c * 4);
  float* pool2_s = (float*)alloc((size_t)BB * C2c * W3c * 4);
  float* pool2_t = (float*)alloc((size_t)BB * C2c * W3c * 4);
  float* ef1_s   = (float*)alloc((size_t)BB * 512 * 4);
  float* ef1_t   = (float*)alloc((size_t)BB * 512 * 4);
  float* fea_s   = (float*)alloc((size_t)BB * 64 * 4);
  float* fea_t   = (float*)alloc((size_t)BB * 64 * 4);
  float* df1_s   = (float*)alloc((size_t)BB * 256 * 4);
  float* df1_t   = (float*)alloc((size_t)BB * 256 * 4);
  float* df2_s   = (float*)alloc((size_t)BB * 2560 * 4);
  float* df2_t   = (float*)alloc((size_t)BB * 2560 * 4);
  float* dc2_s   = (float*)alloc((size_t)BB * C1c * W2c * 4);
  float* dc2_t   = (float*)alloc((size_t)BB * C1c * W2c * 4);
  float* Tbuf    = (float*)alloc((size_t)32768 * 4);
  float* logTbuf = (float*)alloc((size_t)32768 * 4);

  float* out_s = (float*)d_out;
  float* out_t = out_s + (size_t)BB * C0c * W1c;
  float* out_kl = out_s + (size_t)2 * BB * C0c * W1c;

  dim3 blk(256);

  // encoders
  conv1_k<<<dim3((BB * C1c * W1c) / 256), blk, 0, stream>>>(x_s, ec1w, ec1b, back1_s);
  conv1_k<<<dim3((BB * C1c * W1c) / 256), blk, 0, stream>>>(x_t, ec1w, ec1b, back1_t);
  {
    int total = BB * C1c * W2c;
    pool8_bf16_k<<<dim3((total + 255) / 256), blk, 0, stream>>>(back1_s, pool1_s, total, W2c);
    pool8_bf16_k<<<dim3((total + 255) / 256), blk, 0, stream>>>(back1_t, pool1_t, total, W2c);
  }
  conv2_k<<<dim3((BB * C2c * (W2c / 8)) / 256), blk, 0, stream>>>(pool1_s, ec2w, ec2b, back2_s);
  conv2_k<<<dim3((BB * C2c * (W2c / 8)) / 256), blk, 0, stream>>>(pool1_t, ec2w, ec2b, back2_t);
  {
    int total = BB * C2c * W3c;
    pool8_f32_k<<<dim3((total + 255) / 256), blk, 0, stream>>>(back2_s, pool2_s, total, W3c);
    pool8_f32_k<<<dim3((total + 255) / 256), blk, 0, stream>>>(back2_t, pool2_t, total, W3c);
  }
  fc_k<<<dim3((BB * 512) / 256), blk, 0, stream>>>(pool2_s, ef1w, ef1b, ef1_s, BB, 512, 2560, 0);
  fc_k<<<dim3((BB * 512) / 256), blk, 0, stream>>>(pool2_t, ef1w, ef1b, ef1_t, BB, 512, 2560, 0);
  fc_k<<<dim3((BB * 64) / 256), blk, 0, stream>>>(ef1_s, ef2w, ef2b, fea_s, BB, 64, 512, 1);
  fc_k<<<dim3((BB * 64) / 256), blk, 0, stream>>>(ef1_t, ef2w, ef2b, fea_t, BB, 64, 512, 1);

  // decoders (cross skips: out_s uses back*_t, out_t uses back*_s)
  fc_k<<<dim3((BB * 256) / 256), blk, 0, stream>>>(fea_s, df1w, df1b, df1_s, BB, 256, 64, 0);
  fc_k<<<dim3((BB * 256) / 256), blk, 0, stream>>>(fea_t, df1w, df1b, df1_t, BB, 256, 64, 0);
  fc_k<<<dim3((BB * 2560) / 256), blk, 0, stream>>>(df1_s, df2w, df2b, df2_s, BB, 2560, 256, 0);
  fc_k<<<dim3((BB * 2560) / 256), blk, 0, stream>>>(df1_t, df2w, df2b, df2_t, BB, 2560, 256, 0);
  convd2_k<<<dim3((BB * C1c * (W2c / 8)) / 256), blk, 0, stream>>>(df2_s, back2_t, dc2w, dc2b, dc2_s);
  convd2_k<<<dim3((BB * C1c * (W2c / 8)) / 256), blk, 0, stream>>>(df2_t, back2_s, dc2w, dc2b, dc2_t);
  convd1_k<<<dim3((BB * C0c * (W1c / 8)) / 256), blk, 0, stream>>>(dc2_s, back1_t, dc1w, dc1b, out_s);
  convd1_k<<<dim3((BB * C0c * (W1c / 8)) / 256), blk, 0, stream>>>(dc2_t, back1_s, dc1w, dc1b, out_t);

  // pairwise KL
  kl_build_k<<<dim3(1), blk, 0, stream>>>(fea_s, fea_t, lab_s, lab_t, Tbuf, logTbuf);
  kl_reduce_k<<<dim3(1), blk, 0, stream>>>(Tbuf, logTbuf, out_kl);
}

// Round 3
// 1694.474 us; speedup vs baseline: 4.2512x; 4.2512x over previous
//
#include <hip/hip_runtime.h>
#include <hip/hip_bf16.h>
#include <math.h>

#define BB   256
#define W1c  1280
#define W2c  160
#define C1c  64
#define C2c  128
#define KKc  11
#define LLc  8
#define DDc  64
#define GSc  32

typedef __attribute__((ext_vector_type(8))) short short8;
typedef __attribute__((ext_vector_type(4))) float f32x4;
typedef unsigned short u16;

__device__ inline float b2f(u16 h) { return __uint_as_float(((unsigned)h) << 16); }
__device__ inline u16 f2b(float f) {
  unsigned u = __float_as_uint(f);
  return (u16)((u + 0x7fffu + ((u >> 16) & 1u)) >> 16);
}

// ================= weight prepack + pad-zero (one kernel, index ranges) =================
// W2p[11][128][64]bf16  Wd2p[11][64][256]bf16  dc1wp[2][128][12]f32  ef1wbf[512][2560]bf16
// + zero pad rows (0-7,168-175) of back2T_s/t
__global__ __launch_bounds__(256) void prep_k(const float* __restrict__ ec2w, const float* __restrict__ dc2w,
                       const float* __restrict__ dc1w, const float* __restrict__ ef1w,
                       u16* __restrict__ W2p, u16* __restrict__ Wd2p, float* __restrict__ dc1wp,
                       u16* __restrict__ ef1wbf, u16* __restrict__ b2T_s, u16* __restrict__ b2T_t) {
  int idx = blockIdx.x * 256 + threadIdx.x;
  if (idx < 90112) {
    int k = idx / 8192, oc = (idx / 64) % 128, ic = idx % 64;
    W2p[idx] = f2b(ec2w[(oc * 64 + ic) * 11 + k]);
  } else if (idx < 270336) {
    int j = idx - 90112;
    int k = j / 16384, oc = (j / 256) % 64, icc = j % 256;
    Wd2p[j] = f2b(dc2w[(oc * 256 + icc) * 11 + k]);
  } else if (idx < 273408) {
    int j = idx - 270336;
    int oc = j / 1536, ic = (j / 12) % 128, k = j % 12;
    dc1wp[j] = (k < 11) ? dc1w[(oc * 128 + ic) * 11 + k] : 0.f;
  } else if (idx < 1584128) {
    int j = idx - 273408;
    ef1wbf[j] = f2b(ef1w[j]);
  } else if (idx < 2632704) {
    int j = idx - 1584128;
    int ic = j % 128, pr = (j / 128) % 16, b = (j / 2048) % 256, side = j / 524288;
    int row = (pr < 8) ? pr : pr + 160;
    (side ? b2T_t : b2T_s)[((size_t)b * 176 + row) * 128 + ic] = 0;
  }
}

// ================= encoder conv1 (f32 vector, unchanged math) -> back1 bf16 =================
__global__ __launch_bounds__(256) void conv1_k(const float* __restrict__ x, const float* __restrict__ w,
                        const float* __restrict__ bias, u16* __restrict__ out) {
  int idx = blockIdx.x * 256 + threadIdx.x;
  int wp = idx % W1c;
  int oc = (idx / W1c) % C1c;
  int b  = idx / (W1c * C1c);
  const float* xb = x + b * 2 * W1c;
  const float* wk = w + oc * 2 * KKc;
  float s = bias[oc];
#pragma unroll
  for (int k = 0; k < KKc; k++) {
    int p = wp - 5 + k;
    if (p >= 0 && p < W1c) s += xb[p] * wk[k] + xb[W1c + p] * wk[KKc + k];
  }
  out[idx] = f2b(fmaxf(s, 0.f));
}

// ================= pool8 + transpose: back1 bf16 -> p1T[b][176][64] bf16 (pad rows zero) ====
__global__ __launch_bounds__(256) void pool1T_k(const u16* __restrict__ back1, u16* __restrict__ p1T) {
  int idx = blockIdx.x * 256 + threadIdx.x;          // 256*176*64
  int ic = idx % 64, row = (idx / 64) % 176, b = idx / 11264;
  u16 val = 0;
  if (row >= 8 && row < 168) {
    const u16* pp = back1 + ((size_t)b * 64 + ic) * 1280 + (row - 8) * 8;
    uint4 v = *(const uint4*)pp;
    float m = b2f((u16)(v.x & 0xffff));
    m = fmaxf(m, b2f((u16)(v.x >> 16)));
    m = fmaxf(m, b2f((u16)(v.y & 0xffff))); m = fmaxf(m, b2f((u16)(v.y >> 16)));
    m = fmaxf(m, b2f((u16)(v.z & 0xffff))); m = fmaxf(m, b2f((u16)(v.z >> 16)));
    m = fmaxf(m, b2f((u16)(v.w & 0xffff))); m = fmaxf(m, b2f((u16)(v.w >> 16)));
    val = f2b(m);
  }
  p1T[idx] = val;
}

// ================= conv2 implicit-GEMM MFMA: p1T x W2p -> back2T (bf16, bias+relu) =========
// block = (b, w-half of 80); 4 waves; wave = 32 oc x 80 w
__global__ __launch_bounds__(256) void conv2_mfma(const u16* __restrict__ p1T, const u16* __restrict__ W2p,
                           const float* __restrict__ bias, u16* __restrict__ back2T) {
  int blk = blockIdx.x;
  int b = blk >> 1, wh = blk & 1;
  int tid = threadIdx.x, wid = tid >> 6, l = tid & 63;
  int l15 = l & 15, lq = l >> 4;
  int oc0 = wid * 32;
  int w0 = wh * 80;
  f32x4 zero = {0.f, 0.f, 0.f, 0.f};
  f32x4 acc[2][5];
#pragma unroll
  for (int i = 0; i < 2; i++)
#pragma unroll
    for (int j = 0; j < 5; j++) acc[i][j] = zero;
  const u16* pb = p1T + (size_t)b * 176 * 64;
  for (int k = 0; k < 11; k++) {
    for (int ic0 = 0; ic0 < 64; ic0 += 32) {
      short8 a0 = *(const short8*)(W2p + ((k * 128 + oc0 + l15) * 64 + ic0 + lq * 8));
      short8 a1 = *(const short8*)(W2p + ((k * 128 + oc0 + 16 + l15) * 64 + ic0 + lq * 8));
      short8 bf[5];
#pragma unroll
      for (int nf = 0; nf < 5; nf++) {
        int w = w0 + nf * 16 + l15;
        bf[nf] = *(const short8*)(pb + ((w + k + 3) * 64 + ic0 + lq * 8));
      }
#pragma unroll
      for (int nf = 0; nf < 5; nf++) {
        acc[0][nf] = __builtin_amdgcn_mfma_f32_16x16x32_bf16(a0, bf[nf], acc[0][nf], 0, 0, 0);
        acc[1][nf] = __builtin_amdgcn_mfma_f32_16x16x32_bf16(a1, bf[nf], acc[1][nf], 0, 0, 0);
      }
    }
  }
#pragma unroll
  for (int mf = 0; mf < 2; mf++) {
    int ocb = oc0 + mf * 16 + lq * 4;
    float b0 = bias[ocb], b1 = bias[ocb + 1], b2 = bias[ocb + 2], b3 = bias[ocb + 3];
#pragma unroll
    for (int nf = 0; nf < 5; nf++) {
      int w = w0 + nf * 16 + l15;
      f32x4 v = acc[mf][nf];
      unsigned r0 = (unsigned)f2b(fmaxf(v[0] + b0, 0.f)) | ((unsigned)f2b(fmaxf(v[1] + b1, 0.f)) << 16);
      unsigned r1 = (unsigned)f2b(fmaxf(v[2] + b2, 0.f)) | ((unsigned)f2b(fmaxf(v[3] + b3, 0.f)) << 16);
      uint2 st; st.x = r0; st.y = r1;
      *(uint2*)(back2T + ((size_t)(b * 176 + 8 + w) * 128 + ocb)) = st;
    }
  }
}

// ================= pool2: back2T -> pool2bf[b][2560] bf16 =================
__global__ __launch_bounds__(256) void pool2_k(const u16* __restrict__ b2T, u16* __restrict__ pool2bf) {
  int idx = blockIdx.x * 256 + threadIdx.x;          // 256*128*20
  int wo = idx % 20, oc = (idx / 20) % 128, b = idx / 2560;
  float m = -1e30f;
#pragma unroll
  for (int j = 0; j < 8; j++)
    m = fmaxf(m, b2f(b2T[((size_t)b * 176 + 8 + wo * 8 + j) * 128 + oc]));
  pool2bf[idx] = f2b(m);
}

// ================= e_f1 GEMM MFMA: pool2bf[256][2560] x ef1wbf[512][2560] -> ef1 f32 relu ===
__global__ __launch_bounds__(256) void ef1_gemm(const u16* __restrict__ A, const u16* __restrict__ Bw,
                         const float* __restrict__ bias, float* __restrict__ out) {
  int n0 = blockIdx.x * 64;
  int tid = threadIdx.x, wid = tid >> 6, l = tid & 63;
  int l15 = l & 15, lq = l >> 4;
  int m0 = wid * 64;
  f32x4 zero = {0.f, 0.f, 0.f, 0.f};
  f32x4 acc[4][4];
#pragma unroll
  for (int i = 0; i < 4; i++)
#pragma unroll
    for (int j = 0; j < 4; j++) acc[i][j] = zero;
  for (int k0 = 0; k0 < 2560; k0 += 32) {
    short8 af[4], bf[4];
#pragma unroll
    for (int mf = 0; mf < 4; mf++)
      af[mf] = *(const short8*)(A + ((size_t)(m0 + mf * 16 + l15) * 2560 + k0 + lq * 8));
#pragma unroll
    for (int nf = 0; nf < 4; nf++)
      bf[nf] = *(const short8*)(Bw + ((size_t)(n0 + nf * 16 + l15) * 2560 + k0 + lq * 8));
#pragma unroll
    for (int mf = 0; mf < 4; mf++)
#pragma unroll
      for (int nf = 0; nf < 4; nf++)
        acc[mf][nf] = __builtin_amdgcn_mfma_f32_16x16x32_bf16(af[mf], bf[nf], acc[mf][nf], 0, 0, 0);
  }
#pragma unroll
  for (int mf = 0; mf < 4; mf++) {
    int bb = m0 + mf * 16 + lq * 4;
#pragma unroll
    for (int nf = 0; nf < 4; nf++) {
      int oc = n0 + nf * 16 + l15;
      float bi = bias[oc];
#pragma unroll
      for (int r = 0; r < 4; r++)
        out[(size_t)(bb + r) * 512 + oc] = fmaxf(acc[mf][nf][r] + bi, 0.f);
    }
  }
}

// ================= generic f32 FC (kept for ef2/df1/df2) =================
__global__ __launch_bounds__(256) void fc_k(const float* __restrict__ in, const float* __restrict__ wt,
                     const float* __restrict__ bias, float* __restrict__ out,
                     int Bn, int On, int Kn, int act) {
  int idx = blockIdx.x * 256 + threadIdx.x;
  if (idx >= Bn * On) return;
  int o = idx % On;
  int b = idx / On;
  const float4* a  = (const float4*)(in + (size_t)b * Kn);
  const float4* wv = (const float4*)(wt + (size_t)o * Kn);
  float s = 0.f;
  int n4 = Kn >> 2;
  for (int i = 0; i < n4; i++) {
    float4 av = a[i], bv = wv[i];
    s += av.x * bv.x + av.y * bv.y + av.z * bv.z + av.w * bv.w;
  }
  s += bias[o];
  if (act == 0) s = fmaxf(s, 0.f);
  else          s = 1.f / (1.f + expf(-s));
  out[idx] = s;
}

// ================= upT build: df2 f32 -> upT[b][24][128] bf16 (rows 1..20 = df2, else 0) ====
__global__ __launch_bounds__(256) void upT_k(const float* __restrict__ df2, u16* __restrict__ upT) {
  int idx = blockIdx.x * 256 + threadIdx.x;          // 256*24*128
  int ic = idx % 128, r = (idx / 128) % 24, b = idx / 3072;
  float v = (r >= 1 && r <= 20) ? df2[(size_t)b * 2560 + ic * 20 + (r - 1)] : 0.f;
  upT[idx] = f2b(v);
}

// ================= decoder conv2 implicit-GEMM MFMA =================
// block = (b, w-half); 4 waves; wave = 16 oc x 80 w; K = 11 taps x 256 concat-ic
__global__ __launch_bounds__(256) void convd2_mfma(const u16* __restrict__ upT, const u16* __restrict__ skipT,
                            const u16* __restrict__ Wd2p, const float* __restrict__ bias,
                            float* __restrict__ dc2) {
  int blk = blockIdx.x;
  int b = blk >> 1, wh = blk & 1;
  int tid = threadIdx.x, wid = tid >> 6, l = tid & 63;
  int l15 = l & 15, lq = l >> 4;
  int oc0 = wid * 16;
  int w0 = wh * 80;
  f32x4 zero = {0.f, 0.f, 0.f, 0.f};
  f32x4 acc[5];
#pragma unroll
  for (int j = 0; j < 5; j++) acc[j] = zero;
  const u16* ub = upT + (size_t)b * 24 * 128;
  const u16* sb = skipT + (size_t)b * 176 * 128;
  for (int k = 0; k < 11; k++) {
    for (int ic0 = 0; ic0 < 128; ic0 += 32) {      // up half (concat ch 0..127)
      short8 a = *(const short8*)(Wd2p + ((k * 64 + oc0 + l15) * 256 + ic0 + lq * 8));
#pragma unroll
      for (int nf = 0; nf < 5; nf++) {
        int w = w0 + nf * 16 + l15;
        int r = (w + k + 3) >> 3;
        short8 bf = *(const short8*)(ub + (r * 128 + ic0 + lq * 8));
        acc[nf] = __builtin_amdgcn_mfma_f32_16x16x32_bf16(a, bf, acc[nf], 0, 0, 0);
      }
    }
    for (int ic0 = 0; ic0 < 128; ic0 += 32) {      // skip half (concat ch 128..255)
      short8 a = *(const short8*)(Wd2p + ((k * 64 + oc0 + l15) * 256 + 128 + ic0 + lq * 8));
#pragma unroll
      for (int nf = 0; nf < 5; nf++) {
        int w = w0 + nf * 16 + l15;
        short8 bf = *(const short8*)(sb + ((size_t)(w + k + 3) * 128 + ic0 + lq * 8));
        acc[nf] = __builtin_amdgcn_mfma_f32_16x16x32_bf16(a, bf, acc[nf], 0, 0, 0);
      }
    }
  }
  int ocb = oc0 + lq * 4;
  float bb0 = bias[ocb], bb1 = bias[ocb + 1], bb2 = bias[ocb + 2], bb3 = bias[ocb + 3];
#pragma unroll
  for (int nf = 0; nf < 5; nf++) {
    int w = w0 + nf * 16 + l15;
    dc2[((size_t)b * 64 + ocb + 0) * 160 + w] = fmaxf(acc[nf][0] + bb0, 0.f);
    dc2[((size_t)b * 64 + ocb + 1) * 160 + w] = fmaxf(acc[nf][1] + bb1, 0.f);
    dc2[((size_t)b * 64 + ocb + 2) * 160 + w] = fmaxf(acc[nf][2] + bb2, 0.f);
    dc2[((size_t)b * 64 + ocb + 3) * 160 + w] = fmaxf(acc[nf][3] + bb3, 0.f);
  }
}

// ================= out init (bias) / relu =================
__global__ __launch_bounds__(256) void init_out_k(float* __restrict__ out, const float* __restrict__ bias) {
  int idx = blockIdx.x * 256 + threadIdx.x;          // 2*256*2*1280
  int oc = (idx / 1280) & 1;
  out[idx] = bias[oc];
}
__global__ __launch_bounds__(256) void relu_out_k(float* __restrict__ out) {
  int idx = blockIdx.x * 256 + threadIdx.x;
  out[idx] = fmaxf(out[idx], 0.f);
}

// ================= decoder conv1 (f32, ic-split x4, atomic accumulate) =================
// thread = (b, oc, wgroup8); channels c in [split*32, split*32+32): c<64 -> up(dc2), else skip(back1 bf16)
__global__ __launch_bounds__(256) void convd1_part(const float* __restrict__ up, const u16* __restrict__ skip,
                            const float* __restrict__ wp, float* __restrict__ out) {
  int idx = blockIdx.x * 256 + threadIdx.x;          // 4*256*2*160
  int wg = idx % 160, oc = (idx / 160) % 2, split = (idx / 320) % 4, b = idx / 1280;
  int w0 = wg * 8;
  float acc[8];
#pragma unroll
  for (int r = 0; r < 8; r++) acc[r] = 0.f;
  int c0 = split * 32;
  for (int c = c0; c < c0 + 32; c++) {
    const float4* wr = (const float4*)(wp + ((size_t)oc * 128 + c) * 12);
    float4 q0 = wr[0], q1 = wr[1], q2 = wr[2];
    float wt[11] = {q0.x, q0.y, q0.z, q0.w, q1.x, q1.y, q1.z, q1.w, q2.x, q2.y, q2.z};
    if (c < 64) {
      const float* dr = up + ((size_t)b * 64 + c) * 160;
      float u[3];
      u[0] = (wg > 0)   ? dr[wg - 1] : 0.f;
      u[1] = dr[wg];
      u[2] = (wg < 159) ? dr[wg + 1] : 0.f;
#pragma unroll
      for (int k = 0; k < 11; k++)
#pragma unroll
        for (int r = 0; r < 8; r++)
          acc[r] += wt[k] * u[(r + k + 3) >> 3];
    } else {
      int sc = c - 64;
      const u16* sr = skip + ((size_t)b * 64 + sc) * 1280;
      float s[20];
#pragma unroll
      for (int p = 0; p < 10; p++) {
        int wlo = w0 - 6 + 2 * p;
        if (wlo >= 0 && wlo + 1 < 1280) {
          unsigned v = *(const unsigned*)(sr + wlo);
          s[2 * p]     = __uint_as_float(v << 16);
          s[2 * p + 1] = __uint_as_float(v & 0xffff0000u);
        } else {
          s[2 * p]     = (wlo >= 0 && wlo < 1280)         ? b2f(sr[wlo])     : 0.f;
          s[2 * p + 1] = (wlo + 1 >= 0 && wlo + 1 < 1280) ? b2f(sr[wlo + 1]) : 0.f;
        }
      }
#pragma unroll
      for (int k = 0; k < 11; k++)
#pragma unroll
        for (int r = 0; r < 8; r++)
          acc[r] += wt[k] * s[k + r + 1];
    }
  }
  float* ob = out + ((size_t)b * 2 + oc) * 1280 + w0;
#pragma unroll
  for (int r = 0; r < 8; r++) atomicAdd(ob + r, acc[r]);
}

// ================= KL (unchanged) =================
__global__ void kl_build_k(const float* __restrict__ fea_s, const float* __restrict__ fea_t,
                           const int* __restrict__ lab_s, const int* __restrict__ lab_t,
                           float* __restrict__ T, float* __restrict__ logT) {
  __shared__ int srt_s[BB], srt_t[BB];
  int t = threadIdx.x;
  {
    int lab = lab_s[t];
    int pos = 0;
    for (int b = 0; b < BB; b++) {
      int lb = lab_s[b];
      pos += (lb < lab) + ((b < t) && (lb == lab));
    }
    srt_s[pos] = t;
  }
  {
    int lab = lab_t[t];
    int pos = 0;
    for (int b = 0; b < BB; b++) {
      int lb = lab_t[b];
      pos += (lb < lab) + ((b < t) && (lb == lab));
    }
    srt_t[pos] = t;
  }
  __syncthreads();
  const int total = LLc * 2 * GSc * DDc;
  for (int e = t; e < total; e += BB) {
    int d = e & 63;
    int m = (e >> 6) & 63;
    int l = e >> 12;
    float v;
    if (m < GSc) v = fea_s[srt_s[l * GSc + m] * DDc + d];
    else         v = fea_t[srt_t[l * GSc + (m - GSc)] * DDc + d];
    T[e]    = v;
    logT[e] = logf(v);
  }
}

__global__ void kl_reduce_k(const float* __restrict__ T, const float* __restrict__ logT,
                            float* __restrict__ out) {
  int t = threadIdx.x;
  __shared__ float wsum[4];
  __shared__ float acc_tr, acc_tot;
  if (t == 0) { acc_tr = 0.f; acc_tot = 0.f; }
  __syncthreads();
  for (int i = 0; i < LLc; i++) {
    for (int j = 0; j < LLc; j++) {
      const float* li = logT + i * 4096;
      const float* tj = T + j * 4096;
      float s = 0.f;
      for (int e = t; e < 4096; e += BB) s += li[e] * tj[e];
      for (int off = 32; off > 0; off >>= 1) s += __shfl_down(s, off, 64);
      if ((t & 63) == 0) wsum[t >> 6] = s;
      __syncthreads();
      if (t == 0) {
        float v = wsum[0] + wsum[1] + wsum[2] + wsum[3];
        acc_tot += v;
        if (i == j) acc_tr += v;
      }
      __syncthreads();
    }
  }
  if (t == 0) {
    float kl = (LLc * acc_tr - acc_tot) / 4096.f / (LLc * LLc / 2.0f);
    out[0] = kl;
  }
}

extern "C" void kernel_launch(void* const* d_in, const int* in_sizes, int n_in,
                              void* d_out, int out_size, void* d_ws, size_t ws_size,
                              hipStream_t stream) {
  const float* x_s  = (const float*)d_in[0];
  const float* x_t  = (const float*)d_in[1];
  const int* lab_s  = (const int*)d_in[2];
  const int* lab_t  = (const int*)d_in[3];
  const float* ec1w = (const float*)d_in[5];  const float* ec1b = (const float*)d_in[6];
  const float* ec2w = (const float*)d_in[7];  const float* ec2b = (const float*)d_in[8];
  const float* ef1w = (const float*)d_in[9];  const float* ef1b = (const float*)d_in[10];
  const float* ef2w = (const float*)d_in[11]; const float* ef2b = (const float*)d_in[12];
  const float* df1w = (const float*)d_in[13]; const float* df1b = (const float*)d_in[14];
  const float* df2w = (const float*)d_in[15]; const float* df2b = (const float*)d_in[16];
  const float* dc2w = (const float*)d_in[17]; const float* dc2b = (const float*)d_in[18];
  const float* dc1w = (const float*)d_in[19]; const float* dc1b = (const float*)d_in[20];

  char* p = (char*)d_ws;
  auto alloc = [&](size_t bytes) -> char* {
    char* r = p;
    p += (bytes + 255) & ~(size_t)255;
    return r;
  };
  u16*   back1_s = (u16*)alloc((size_t)BB * 64 * 1280 * 2);
  u16*   back1_t = (u16*)alloc((size_t)BB * 64 * 1280 * 2);
  u16*   p1T_s   = (u16*)alloc((size_t)BB * 176 * 64 * 2);
  u16*   p1T_t   = (u16*)alloc((size_t)BB * 176 * 64 * 2);
  u16*   b2T_s   = (u16*)alloc((size_t)BB * 176 * 128 * 2);
  u16*   b2T_t   = (u16*)alloc((size_t)BB * 176 * 128 * 2);
  u16*   upT_s   = (u16*)alloc((size_t)BB * 24 * 128 * 2);
  u16*   upT_t   = (u16*)alloc((size_t)BB * 24 * 128 * 2);
  u16*   p2bf_s  = (u16*)alloc((size_t)BB * 2560 * 2);
  u16*   p2bf_t  = (u16*)alloc((size_t)BB * 2560 * 2);
  float* ef1_s   = (float*)alloc((size_t)BB * 512 * 4);
  float* ef1_t   = (float*)alloc((size_t)BB * 512 * 4);
  float* fea_s   = (float*)alloc((size_t)BB * 64 * 4);
  float* fea_t   = (float*)alloc((size_t)BB * 64 * 4);
  float* df1_s   = (float*)alloc((size_t)BB * 256 * 4);
  float* df1_t   = (float*)alloc((size_t)BB * 256 * 4);
  float* df2_s   = (float*)alloc((size_t)BB * 2560 * 4);
  float* df2_t   = (float*)alloc((size_t)BB * 2560 * 4);
  float* dc2_s   = (float*)alloc((size_t)BB * 64 * 160 * 4);
  float* dc2_t   = (float*)alloc((size_t)BB * 64 * 160 * 4);
  u16*   W2p     = (u16*)alloc(90112 * 2);
  u16*   Wd2p    = (u16*)alloc(180224 * 2);
  float* dc1wp   = (float*)alloc(3072 * 4);
  u16*   ef1wbf  = (u16*)alloc((size_t)1310720 * 2);
  float* Tbuf    = (float*)alloc((size_t)32768 * 4);
  float* logTbuf = (float*)alloc((size_t)32768 * 4);

  float* out_s  = (float*)d_out;
  float* out_t  = out_s + (size_t)BB * 2 * 1280;
  float* out_kl = out_s + (size_t)2 * BB * 2 * 1280;

  dim3 blk(256);

  // weight prepack + pad zeros
  prep_k<<<dim3(10284), blk, 0, stream>>>(ec2w, dc2w, dc1w, ef1w, W2p, Wd2p, dc1wp, ef1wbf, b2T_s, b2T_t);

  // encoders
  conv1_k<<<dim3(81920), blk, 0, stream>>>(x_s, ec1w, ec1b, back1_s);
  conv1_k<<<dim3(81920), blk, 0, stream>>>(x_t, ec1w, ec1b, back1_t);
  pool1T_k<<<dim3(11264), blk, 0, stream>>>(back1_s, p1T_s);
  pool1T_k<<<dim3(11264), blk, 0, stream>>>(back1_t, p1T_t);
  conv2_mfma<<<dim3(512), blk, 0, stream>>>(p1T_s, W2p, ec2b, b2T_s);
  conv2_mfma<<<dim3(512), blk, 0, stream>>>(p1T_t, W2p, ec2b, b2T_t);
  pool2_k<<<dim3(2560), blk, 0, stream>>>(b2T_s, p2bf_s);
  pool2_k<<<dim3(2560), blk, 0, stream>>>(b2T_t, p2bf_t);
  ef1_gemm<<<dim3(8), blk, 0, stream>>>(p2bf_s, ef1wbf, ef1b, ef1_s);
  ef1_gemm<<<dim3(8), blk, 0, stream>>>(p2bf_t, ef1wbf, ef1b, ef1_t);
  fc_k<<<dim3(64), blk, 0, stream>>>(ef1_s, ef2w, ef2b, fea_s, BB, 64, 512, 1);
  fc_k<<<dim3(64), blk, 0, stream>>>(ef1_t, ef2w, ef2b, fea_t, BB, 64, 512, 1);

  // decoder FC chain
  fc_k<<<dim3(256), blk, 0, stream>>>(fea_s, df1w, df1b, df1_s, BB, 256, 64, 0);
  fc_k<<<dim3(256), blk, 0, stream>>>(fea_t, df1w, df1b, df1_t, BB, 256, 64, 0);
  fc_k<<<dim3(2560), blk, 0, stream>>>(df1_s, df2w, df2b, df2_s, BB, 2560, 256, 0);
  fc_k<<<dim3(2560), blk, 0, stream>>>(df1_t, df2w, df2b, df2_t, BB, 2560, 256, 0);
  upT_k<<<dim3(3072), blk, 0, stream>>>(df2_s, upT_s);
  upT_k<<<dim3(3072), blk, 0, stream>>>(df2_t, upT_t);

  // decoder conv2 (cross skips: out_s uses back2_t)
  convd2_mfma<<<dim3(512), blk, 0, stream>>>(upT_s, b2T_t, Wd2p, dc2b, dc2_s);
  convd2_mfma<<<dim3(512), blk, 0, stream>>>(upT_t, b2T_s, Wd2p, dc2b, dc2_t);

  // decoder conv1 (cross skips: out_s uses back1_t)
  init_out_k<<<dim3(5120), blk, 0, stream>>>(out_s, dc1b);
  convd1_part<<<dim3(1280), blk, 0, stream>>>(dc2_s, back1_t, dc1wp, out_s);
  convd1_part<<<dim3(1280), blk, 0, stream>>>(dc2_t, back1_s, dc1wp, out_t);
  relu_out_k<<<dim3(5120), blk, 0, stream>>>(out_s);

  // pairwise KL
  kl_build_k<<<dim3(1), blk, 0, stream>>>(fea_s, fea_t, lab_s, lab_t, Tbuf, logTbuf);
  kl_reduce_k<<<dim3(1), blk, 0, stream>>>(Tbuf, logTbuf, out_kl);
}

// Round 6
// 1280.551 us; speedup vs baseline: 5.6254x; 1.3232x over previous
//
#include <hip/hip_runtime.h>
#include <hip/hip_bf16.h>
#include <math.h>

#define BB   256
#define W1c  1280
#define W2c  160
#define C1c  64
#define C2c  128
#define KKc  11
#define LLc  8
#define DDc  64
#define GSc  32

typedef __attribute__((ext_vector_type(8))) short short8;
typedef __attribute__((ext_vector_type(4))) float f32x4;
typedef unsigned short u16;

__device__ inline float b2f(u16 h) { return __uint_as_float(((unsigned)h) << 16); }
__device__ inline u16 f2b(float f) {
  unsigned u = __float_as_uint(f);
  return (u16)((u + 0x7fffu + ((u >> 16) & 1u)) >> 16);
}

// ================= weight prepack + pad-zero (one kernel, index ranges) =================
// W2p[11][128][64]bf16  Wd2p[11][64][256]bf16  dc1wp[2][128][12]f32  ef1wbf[512][2560]bf16
// df2wbf[2560][256]bf16 + zero pad rows of upT (0,21,22,23) and back2T (0-7,168-175)
#define PRE_W2P   90112
#define PRE_WD2P  270336
#define PRE_DC1   273408
#define PRE_EF1   1584128
#define PRE_DF2   2239488
#define PRE_UPT   2501632
#define PRE_B2T   3550208
__global__ __launch_bounds__(256) void prep_k(const float* __restrict__ ec2w, const float* __restrict__ dc2w,
                       const float* __restrict__ dc1w, const float* __restrict__ ef1w,
                       const float* __restrict__ df2w,
                       u16* __restrict__ W2p, u16* __restrict__ Wd2p, float* __restrict__ dc1wp,
                       u16* __restrict__ ef1wbf, u16* __restrict__ df2wbf,
                       u16* __restrict__ upT_s, u16* __restrict__ upT_t,
                       u16* __restrict__ b2T_s, u16* __restrict__ b2T_t) {
  int idx = blockIdx.x * 256 + threadIdx.x;
  if (idx < PRE_W2P) {
    int k = idx / 8192, oc = (idx / 64) % 128, ic = idx % 64;
    W2p[idx] = f2b(ec2w[(oc * 64 + ic) * 11 + k]);
  } else if (idx < PRE_WD2P) {
    int j = idx - PRE_W2P;
    int k = j / 16384, oc = (j / 256) % 64, icc = j % 256;
    Wd2p[j] = f2b(dc2w[(oc * 256 + icc) * 11 + k]);
  } else if (idx < PRE_DC1) {
    int j = idx - PRE_WD2P;
    int oc = j / 1536, ic = (j / 12) % 128, k = j % 12;
    dc1wp[j] = (k < 11) ? dc1w[(oc * 128 + ic) * 11 + k] : 0.f;
  } else if (idx < PRE_EF1) {
    int j = idx - PRE_DC1;
    ef1wbf[j] = f2b(ef1w[j]);
  } else if (idx < PRE_DF2) {
    int j = idx - PRE_EF1;
    df2wbf[j] = f2b(df2w[j]);
  } else if (idx < PRE_UPT) {
    int j = idx - PRE_DF2;
    int ic = j % 128, r4 = (j / 128) % 4, b = (j / 512) % 256, side = j / 131072;
    int row = (r4 == 0) ? 0 : (20 + r4);             // rows 0,21,22,23
    (side ? upT_t : upT_s)[((size_t)b * 24 + row) * 128 + ic] = 0;
  } else if (idx < PRE_B2T) {
    int j = idx - PRE_UPT;
    int ic = j % 128, pr = (j / 128) % 16, b = (j / 2048) % 256, side = j / 524288;
    int row = (pr < 8) ? pr : pr + 160;
    (side ? b2T_t : b2T_s)[((size_t)b * 176 + row) * 128 + ic] = 0;
  }
}

// ================= encoder conv1 (8 outputs/thread) -> back1 bf16 =================
__global__ __launch_bounds__(256) void conv1_k(const float* __restrict__ x, const float* __restrict__ w,
                        const float* __restrict__ bias, u16* __restrict__ out) {
  int idx = blockIdx.x * 256 + threadIdx.x;          // 256*64*160 threads
  int wg = idx % 160, oc = (idx / 160) % 64, b = idx / 10240;
  int w0 = wg * 8;
  const float* xb = x + (size_t)b * 2560;
  float win0[18], win1[18];
#pragma unroll
  for (int j = 0; j < 18; j++) {
    int p = w0 - 5 + j;
    bool in = (p >= 0 && p < 1280);
    win0[j] = in ? xb[p] : 0.f;
    win1[j] = in ? xb[1280 + p] : 0.f;
  }
  const float* wk = w + oc * 22;
  float bv = bias[oc];
  float acc[8];
#pragma unroll
  for (int r = 0; r < 8; r++) acc[r] = bv;
#pragma unroll
  for (int k = 0; k < 11; k++) {
    float w0v = wk[k], w1v = wk[11 + k];
#pragma unroll
    for (int r = 0; r < 8; r++) acc[r] += win0[k + r] * w0v + win1[k + r] * w1v;
  }
  uint4 st;
  st.x = (unsigned)f2b(fmaxf(acc[0], 0.f)) | ((unsigned)f2b(fmaxf(acc[1], 0.f)) << 16);
  st.y = (unsigned)f2b(fmaxf(acc[2], 0.f)) | ((unsigned)f2b(fmaxf(acc[3], 0.f)) << 16);
  st.z = (unsigned)f2b(fmaxf(acc[4], 0.f)) | ((unsigned)f2b(fmaxf(acc[5], 0.f)) << 16);
  st.w = (unsigned)f2b(fmaxf(acc[6], 0.f)) | ((unsigned)f2b(fmaxf(acc[7], 0.f)) << 16);
  *(uint4*)(out + ((size_t)(b * 64 + oc) * 1280 + w0)) = st;
}

// ================= pool8 + transpose: back1 bf16 -> p1T[b][176][64] bf16 (pad rows zero) ====
__global__ __launch_bounds__(256) void pool1T_k(const u16* __restrict__ back1, u16* __restrict__ p1T) {
  int idx = blockIdx.x * 256 + threadIdx.x;          // 256*176*64
  int ic = idx % 64, row = (idx / 64) % 176, b = idx / 11264;
  u16 val = 0;
  if (row >= 8 && row < 168) {
    const u16* pp = back1 + ((size_t)b * 64 + ic) * 1280 + (row - 8) * 8;
    uint4 v = *(const uint4*)pp;
    float m = b2f((u16)(v.x & 0xffff));
    m = fmaxf(m, b2f((u16)(v.x >> 16)));
    m = fmaxf(m, b2f((u16)(v.y & 0xffff))); m = fmaxf(m, b2f((u16)(v.y >> 16)));
    m = fmaxf(m, b2f((u16)(v.z & 0xffff))); m = fmaxf(m, b2f((u16)(v.z >> 16)));
    m = fmaxf(m, b2f((u16)(v.w & 0xffff))); m = fmaxf(m, b2f((u16)(v.w >> 16)));
    val = f2b(m);
  }
  p1T[idx] = val;
}

// ================= conv2 implicit-GEMM MFMA: p1T x W2p -> back2T (bf16, bias+relu) =========
__global__ __launch_bounds__(256) void conv2_mfma(const u16* __restrict__ p1T, const u16* __restrict__ W2p,
                           const float* __restrict__ bias, u16* __restrict__ back2T) {
  int blk = blockIdx.x;
  int b = blk >> 1, wh = blk & 1;
  int tid = threadIdx.x, wid = tid >> 6, l = tid & 63;
  int l15 = l & 15, lq = l >> 4;
  int oc0 = wid * 32;
  int w0 = wh * 80;
  f32x4 zero = {0.f, 0.f, 0.f, 0.f};
  f32x4 acc[2][5];
#pragma unroll
  for (int i = 0; i < 2; i++)
#pragma unroll
    for (int j = 0; j < 5; j++) acc[i][j] = zero;
  const u16* pb = p1T + (size_t)b * 176 * 64;
  for (int k = 0; k < 11; k++) {
    for (int ic0 = 0; ic0 < 64; ic0 += 32) {
      short8 a0 = *(const short8*)(W2p + ((k * 128 + oc0 + l15) * 64 + ic0 + lq * 8));
      short8 a1 = *(const short8*)(W2p + ((k * 128 + oc0 + 16 + l15) * 64 + ic0 + lq * 8));
      short8 bf[5];
#pragma unroll
      for (int nf = 0; nf < 5; nf++) {
        int w = w0 + nf * 16 + l15;
        bf[nf] = *(const short8*)(pb + ((w + k + 3) * 64 + ic0 + lq * 8));
      }
#pragma unroll
      for (int nf = 0; nf < 5; nf++) {
        acc[0][nf] = __builtin_amdgcn_mfma_f32_16x16x32_bf16(a0, bf[nf], acc[0][nf], 0, 0, 0);
        acc[1][nf] = __builtin_amdgcn_mfma_f32_16x16x32_bf16(a1, bf[nf], acc[1][nf], 0, 0, 0);
      }
    }
  }
#pragma unroll
  for (int mf = 0; mf < 2; mf++) {
    int ocb = oc0 + mf * 16 + lq * 4;
    float b0 = bias[ocb], b1 = bias[ocb + 1], b2 = bias[ocb + 2], b3 = bias[ocb + 3];
#pragma unroll
    for (int nf = 0; nf < 5; nf++) {
      int w = w0 + nf * 16 + l15;
      f32x4 v = acc[mf][nf];
      unsigned r0 = (unsigned)f2b(fmaxf(v[0] + b0, 0.f)) | ((unsigned)f2b(fmaxf(v[1] + b1, 0.f)) << 16);
      unsigned r1 = (unsigned)f2b(fmaxf(v[2] + b2, 0.f)) | ((unsigned)f2b(fmaxf(v[3] + b3, 0.f)) << 16);
      uint2 st; st.x = r0; st.y = r1;
      *(uint2*)(back2T + ((size_t)(b * 176 + 8 + w) * 128 + ocb)) = st;
    }
  }
}

// ================= pool2: back2T -> pool2bf[b][2560] bf16 =================
__global__ __launch_bounds__(256) void pool2_k(const u16* __restrict__ b2T, u16* __restrict__ pool2bf) {
  int idx = blockIdx.x * 256 + threadIdx.x;          // 256*128*20
  int wo = idx % 20, oc = (idx / 20) % 128, b = idx / 2560;
  float m = -1e30f;
#pragma unroll
  for (int j = 0; j < 8; j++)
    m = fmaxf(m, b2f(b2T[((size_t)b * 176 + 8 + wo * 8 + j) * 128 + oc]));
  pool2bf[idx] = f2b(m);
}

// ================= e_f1 GEMM MFMA: pool2bf[256][2560] x ef1wbf[512][2560] -> ef1 f32 relu ===
__global__ __launch_bounds__(256) void ef1_gemm(const u16* __restrict__ A, const u16* __restrict__ Bw,
                         const float* __restrict__ bias, float* __restrict__ out) {
  int n0 = blockIdx.x * 64;
  int tid = threadIdx.x, wid = tid >> 6, l = tid & 63;
  int l15 = l & 15, lq = l >> 4;
  int m0 = wid * 64;
  f32x4 zero = {0.f, 0.f, 0.f, 0.f};
  f32x4 acc[4][4];
#pragma unroll
  for (int i = 0; i < 4; i++)
#pragma unroll
    for (int j = 0; j < 4; j++) acc[i][j] = zero;
  for (int k0 = 0; k0 < 2560; k0 += 32) {
    short8 af[4], bf[4];
#pragma unroll
    for (int mf = 0; mf < 4; mf++)
      af[mf] = *(const short8*)(A + ((size_t)(m0 + mf * 16 + l15) * 2560 + k0 + lq * 8));
#pragma unroll
    for (int nf = 0; nf < 4; nf++)
      bf[nf] = *(const short8*)(Bw + ((size_t)(n0 + nf * 16 + l15) * 2560 + k0 + lq * 8));
#pragma unroll
    for (int mf = 0; mf < 4; mf++)
#pragma unroll
      for (int nf = 0; nf < 4; nf++)
        acc[mf][nf] = __builtin_amdgcn_mfma_f32_16x16x32_bf16(af[mf], bf[nf], acc[mf][nf], 0, 0, 0);
  }
#pragma unroll
  for (int mf = 0; mf < 4; mf++) {
    int bb = m0 + mf * 16 + lq * 4;
#pragma unroll
    for (int nf = 0; nf < 4; nf++) {
      int oc = n0 + nf * 16 + l15;
      float bi = bias[oc];
#pragma unroll
      for (int r = 0; r < 4; r++)
        out[(size_t)(bb + r) * 512 + oc] = fmaxf(acc[mf][nf][r] + bi, 0.f);
    }
  }
}

// ================= fused e_f2(sigmoid) + d_f1(relu): one block per batch row =================
// emits fea (f32, for KL) and df1bf (bf16 A-matrix for the df2 GEMM)
__global__ __launch_bounds__(256) void ef2df1_k(const float* __restrict__ ef1, const float* __restrict__ ef2w,
                         const float* __restrict__ ef2b, const float* __restrict__ df1w,
                         const float* __restrict__ df1b, float* __restrict__ fea,
                         u16* __restrict__ df1bf) {
  __shared__ float row[512];
  __shared__ float part[256];
  __shared__ float fea_sh[64];
  int b = blockIdx.x, tid = threadIdx.x;
  row[tid] = ef1[(size_t)b * 512 + tid];
  row[tid + 256] = ef1[(size_t)b * 512 + tid + 256];
  __syncthreads();
  {
    int o = tid & 63, q = tid >> 6;
    const float4* wr = (const float4*)(ef2w + (size_t)o * 512 + q * 128);
    float s = 0.f;
    int base = q * 128;
#pragma unroll
    for (int i = 0; i < 32; i++) {
      float4 wv = wr[i];
      s += row[base + 4 * i] * wv.x + row[base + 4 * i + 1] * wv.y +
           row[base + 4 * i + 2] * wv.z + row[base + 4 * i + 3] * wv.w;
    }
    part[q * 64 + o] = s;
  }
  __syncthreads();
  if (tid < 64) {
    float v = part[tid] + part[64 + tid] + part[128 + tid] + part[192 + tid] + ef2b[tid];
    float sg = 1.f / (1.f + expf(-v));
    fea_sh[tid] = sg;
    fea[(size_t)b * 64 + tid] = sg;
  }
  __syncthreads();
  {
    const float4* wr = (const float4*)(df1w + (size_t)tid * 64);
    float s = 0.f;
#pragma unroll
    for (int i = 0; i < 16; i++) {
      float4 wv = wr[i];
      s += fea_sh[4 * i] * wv.x + fea_sh[4 * i + 1] * wv.y +
           fea_sh[4 * i + 2] * wv.z + fea_sh[4 * i + 3] * wv.w;
    }
    df1bf[(size_t)b * 256 + tid] = f2b(fmaxf(s + df1b[tid], 0.f));
  }
}

// ================= d_f2 GEMM MFMA fused with upT build: df1bf x df2wbf -> upT bf16 ==========
// M=256(b) N=2560(o) K=256; epilogue: relu, o=(ch*20+t) -> upT[b][1+t][ch]
__global__ __launch_bounds__(256) void df2_gemm(const u16* __restrict__ A, const u16* __restrict__ Bw,
                         const float* __restrict__ bias, u16* __restrict__ upT) {
  int n0 = blockIdx.x * 64;
  int tid = threadIdx.x, wid = tid >> 6, l = tid & 63;
  int l15 = l & 15, lq = l >> 4;
  int m0 = wid * 64;
  f32x4 zero = {0.f, 0.f, 0.f, 0.f};
  f32x4 acc[4][4];
#pragma unroll
  for (int i = 0; i < 4; i++)
#pragma unroll
    for (int j = 0; j < 4; j++) acc[i][j] = zero;
  for (int k0 = 0; k0 < 256; k0 += 32) {
    short8 af[4], bf[4];
#pragma unroll
    for (int mf = 0; mf < 4; mf++)
      af[mf] = *(const short8*)(A + ((size_t)(m0 + mf * 16 + l15) * 256 + k0 + lq * 8));
#pragma unroll
    for (int nf = 0; nf < 4; nf++)
      bf[nf] = *(const short8*)(Bw + ((size_t)(n0 + nf * 16 + l15) * 256 + k0 + lq * 8));
#pragma unroll
    for (int mf = 0; mf < 4; mf++)
#pragma unroll
      for (int nf = 0; nf < 4; nf++)
        acc[mf][nf] = __builtin_amdgcn_mfma_f32_16x16x32_bf16(af[mf], bf[nf], acc[mf][nf], 0, 0, 0);
  }
#pragma unroll
  for (int nf = 0; nf < 4; nf++) {
    int o = n0 + nf * 16 + l15;
    float bi = bias[o];
    int ch = o / 20, t = o - ch * 20;
#pragma unroll
    for (int mf = 0; mf < 4; mf++) {
      int bb = m0 + mf * 16 + lq * 4;
#pragma unroll
      for (int r = 0; r < 4; r++)
        upT[((size_t)(bb + r) * 24 + 1 + t) * 128 + ch] = f2b(fmaxf(acc[mf][nf][r] + bi, 0.f));
    }
  }
}

// ================= decoder conv2 implicit-GEMM MFMA =================
__global__ __launch_bounds__(256) void convd2_mfma(const u16* __restrict__ upT, const u16* __restrict__ skipT,
                            const u16* __restrict__ Wd2p, const float* __restrict__ bias,
                            float* __restrict__ dc2) {
  int blk = blockIdx.x;
  int b = blk >> 1, wh = blk & 1;
  int tid = threadIdx.x, wid = tid >> 6, l = tid & 63;
  int l15 = l & 15, lq = l >> 4;
  int oc0 = wid * 16;
  int w0 = wh * 80;
  f32x4 zero = {0.f, 0.f, 0.f, 0.f};
  f32x4 acc[5];
#pragma unroll
  for (int j = 0; j < 5; j++) acc[j] = zero;
  const u16* ub = upT + (size_t)b * 24 * 128;
  const u16* sb = skipT + (size_t)b * 176 * 128;
  for (int k = 0; k < 11; k++) {
    for (int ic0 = 0; ic0 < 128; ic0 += 32) {
      short8 a = *(const short8*)(Wd2p + ((k * 64 + oc0 + l15) * 256 + ic0 + lq * 8));
#pragma unroll
      for (int nf = 0; nf < 5; nf++) {
        int w = w0 + nf * 16 + l15;
        int r = (w + k + 3) >> 3;
        short8 bf = *(const short8*)(ub + (r * 128 + ic0 + lq * 8));
        acc[nf] = __builtin_amdgcn_mfma_f32_16x16x32_bf16(a, bf, acc[nf], 0, 0, 0);
      }
    }
    for (int ic0 = 0; ic0 < 128; ic0 += 32) {
      short8 a = *(const short8*)(Wd2p + ((k * 64 + oc0 + l15) * 256 + 128 + ic0 + lq * 8));
#pragma unroll
      for (int nf = 0; nf < 5; nf++) {
        int w = w0 + nf * 16 + l15;
        short8 bf = *(const short8*)(sb + ((size_t)(w + k + 3) * 128 + ic0 + lq * 8));
        acc[nf] = __builtin_amdgcn_mfma_f32_16x16x32_bf16(a, bf, acc[nf], 0, 0, 0);
      }
    }
  }
  int ocb = oc0 + lq * 4;
  float bb0 = bias[ocb], bb1 = bias[ocb + 1], bb2 = bias[ocb + 2], bb3 = bias[ocb + 3];
#pragma unroll
  for (int nf = 0; nf < 5; nf++) {
    int w = w0 + nf * 16 + l15;
    dc2[((size_t)b * 64 + ocb + 0) * 160 + w] = fmaxf(acc[nf][0] + bb0, 0.f);
    dc2[((size_t)b * 64 + ocb + 1) * 160 + w] = fmaxf(acc[nf][1] + bb1, 0.f);
    dc2[((size_t)b * 64 + ocb + 2) * 160 + w] = fmaxf(acc[nf][2] + bb2, 0.f);
    dc2[((size_t)b * 64 + ocb + 3) * 160 + w] = fmaxf(acc[nf][3] + bb3, 0.f);
  }
}

// ================= out init (bias) / relu =================
__global__ __launch_bounds__(256) void init_out_k(float* __restrict__ out, const float* __restrict__ bias) {
  int idx = blockIdx.x * 256 + threadIdx.x;
  int oc = (idx / 1280) & 1;
  out[idx] = bias[oc];
}
__global__ __launch_bounds__(256) void relu_out_k(float* __restrict__ out) {
  int idx = blockIdx.x * 256 + threadIdx.x;
  out[idx] = fmaxf(out[idx], 0.f);
}

// ================= decoder conv1 (f32, ic-split x4, atomic accumulate) =================
__global__ __launch_bounds__(256) void convd1_part(const float* __restrict__ up, const u16* __restrict__ skip,
                            const float* __restrict__ wp, float* __restrict__ out) {
  int idx = blockIdx.x * 256 + threadIdx.x;          // 4*256*2*160
  int wg = idx % 160, oc = (idx / 160) % 2, split = (idx / 320) % 4, b = idx / 1280;
  int w0 = wg * 8;
  float acc[8];
#pragma unroll
  for (int r = 0; r < 8; r++) acc[r] = 0.f;
  int c0 = split * 32;
  for (int c = c0; c < c0 + 32; c++) {
    const float4* wr = (const float4*)(wp + ((size_t)oc * 128 + c) * 12);
    float4 q0 = wr[0], q1 = wr[1], q2 = wr[2];
    float wt[11] = {q0.x, q0.y, q0.z, q0.w, q1.x, q1.y, q1.z, q1.w, q2.x, q2.y, q2.z};
    if (c < 64) {
      const float* dr = up + ((size_t)b * 64 + c) * 160;
      float u[3];
      u[0] = (wg > 0)   ? dr[wg - 1] : 0.f;
      u[1] = dr[wg];
      u[2] = (wg < 159) ? dr[wg + 1] : 0.f;
#pragma unroll
      for (int k = 0; k < 11; k++)
#pragma unroll
        for (int r = 0; r < 8; r++)
          acc[r] += wt[k] * u[(r + k + 3) >> 3];
    } else {
      int sc = c - 64;
      const u16* sr = skip + ((size_t)b * 64 + sc) * 1280;
      float s[20];
#pragma unroll
      for (int p = 0; p < 10; p++) {
        int wlo = w0 - 6 + 2 * p;
        if (wlo >= 0 && wlo + 1 < 1280) {
          unsigned v = *(const unsigned*)(sr + wlo);
          s[2 * p]     = __uint_as_float(v << 16);
          s[2 * p + 1] = __uint_as_float(v & 0xffff0000u);
        } else {
          s[2 * p]     = (wlo >= 0 && wlo < 1280)         ? b2f(sr[wlo])     : 0.f;
          s[2 * p + 1] = (wlo + 1 >= 0 && wlo + 1 < 1280) ? b2f(sr[wlo + 1]) : 0.f;
        }
      }
#pragma unroll
      for (int k = 0; k < 11; k++)
#pragma unroll
        for (int r = 0; r < 8; r++)
          acc[r] += wt[k] * s[k + r + 1];
      }
  }
  float* ob = out + ((size_t)b * 2 + oc) * 1280 + w0;
#pragma unroll
  for (int r = 0; r < 8; r++) atomicAdd(ob + r, acc[r]);
}

// ================= KL: sort -> build -> pair-dots -> finalize =================
__global__ void kl_sort_k(const int* __restrict__ lab_s, const int* __restrict__ lab_t,
                          int* __restrict__ srt) {
  int t = threadIdx.x;
  {
    int lab = lab_s[t];
    int pos = 0;
    for (int b = 0; b < BB; b++) {
      int lb = lab_s[b];
      pos += (lb < lab) + ((b < t) && (lb == lab));
    }
    srt[pos] = t;
  }
  {
    int lab = lab_t[t];
    int pos = 0;
    for (int b = 0; b < BB; b++) {
      int lb = lab_t[b];
      pos += (lb < lab) + ((b < t) && (lb == lab));
    }
    srt[256 + pos] = t;
  }
}

__global__ void kl_build_k(const float* __restrict__ fea_s, const float* __restrict__ fea_t,
                           const int* __restrict__ srt,
                           float* __restrict__ T, float* __restrict__ logT) {
  int idx = blockIdx.x * 256 + threadIdx.x;          // 8192 threads, 4 elems each
#pragma unroll
  for (int r = 0; r < 4; r++) {
    int e = idx + r * 8192;
    int d = e & 63;
    int m = (e >> 6) & 63;
    int l = e >> 12;
    float v;
    if (m < GSc) v = fea_s[srt[l * GSc + m] * DDc + d];
    else         v = fea_t[srt[256 + l * GSc + (m - GSc)] * DDc + d];
    T[e]    = v;
    logT[e] = logf(v);
  }
}

__global__ void kl_pairs_k(const float* __restrict__ T, const float* __restrict__ logT,
                           float* __restrict__ C) {
  int blk = blockIdx.x;                              // 64 blocks: (i,j)
  int i = blk >> 3, j = blk & 7;
  int t = threadIdx.x;
  __shared__ float wsum[4];
  const float* li = logT + i * 4096;
  const float* tj = T + j * 4096;
  float s = 0.f;
  for (int e = t; e < 4096; e += 256) s += li[e] * tj[e];
  for (int off = 32; off > 0; off >>= 1) s += __shfl_down(s, off, 64);
  if ((t & 63) == 0) wsum[t >> 6] = s;
  __syncthreads();
  if (t == 0) C[blk] = wsum[0] + wsum[1] + wsum[2] + wsum[3];
}

__global__ void kl_final_k(const float* __restrict__ C, float* __restrict__ out) {
  int t = threadIdx.x;                               // 64 threads
  float c = C[t];
  float tr = ((t >> 3) == (t & 7)) ? c : 0.f;
  for (int off = 32; off > 0; off >>= 1) {
    c  += __shfl_down(c, off, 64);
    tr += __shfl_down(tr, off, 64);
  }
  if (t == 0) out[0] = (LLc * tr - c) / 4096.f / (LLc * LLc / 2.0f);
}

extern "C" void kernel_launch(void* const* d_in, const int* in_sizes, int n_in,
                              void* d_out, int out_size, void* d_ws, size_t ws_size,
                              hipStream_t stream) {
  const float* x_s  = (const float*)d_in[0];
  const float* x_t  = (const float*)d_in[1];
  const int* lab_s  = (const int*)d_in[2];
  const int* lab_t  = (const int*)d_in[3];
  const float* ec1w = (const float*)d_in[5];  const float* ec1b = (const float*)d_in[6];
  const float* ec2w = (const float*)d_in[7];  const float* ec2b = (const float*)d_in[8];
  const float* ef1w = (const float*)d_in[9];  const float* ef1b = (const float*)d_in[10];
  const float* ef2w = (const float*)d_in[11]; const float* ef2b = (const float*)d_in[12];
  const float* df1w = (const float*)d_in[13]; const float* df1b = (const float*)d_in[14];
  const float* df2w = (const float*)d_in[15]; const float* df2b = (const float*)d_in[16];
  const float* dc2w = (const float*)d_in[17]; const float* dc2b = (const float*)d_in[18];
  const float* dc1w = (const float*)d_in[19]; const float* dc1b = (const float*)d_in[20];

  char* p = (char*)d_ws;
  auto alloc = [&](size_t bytes) -> char* {
    char* r = p;
    p += (bytes + 255) & ~(size_t)255;
    return r;
  };
  u16*   back1_s = (u16*)alloc((size_t)BB * 64 * 1280 * 2);
  u16*   back1_t = (u16*)alloc((size_t)BB * 64 * 1280 * 2);
  u16*   p1T_s   = (u16*)alloc((size_t)BB * 176 * 64 * 2);
  u16*   p1T_t   = (u16*)alloc((size_t)BB * 176 * 64 * 2);
  u16*   b2T_s   = (u16*)alloc((size_t)BB * 176 * 128 * 2);
  u16*   b2T_t   = (u16*)alloc((size_t)BB * 176 * 128 * 2);
  u16*   upT_s   = (u16*)alloc((size_t)BB * 24 * 128 * 2);
  u16*   upT_t   = (u16*)alloc((size_t)BB * 24 * 128 * 2);
  u16*   p2bf_s  = (u16*)alloc((size_t)BB * 2560 * 2);
  u16*   p2bf_t  = (u16*)alloc((size_t)BB * 2560 * 2);
  float* ef1_s   = (float*)alloc((size_t)BB * 512 * 4);
  float* ef1_t   = (float*)alloc((size_t)BB * 512 * 4);
  float* fea_s   = (float*)alloc((size_t)BB * 64 * 4);
  float* fea_t   = (float*)alloc((size_t)BB * 64 * 4);
  u16*   df1bf_s = (u16*)alloc((size_t)BB * 256 * 2);
  u16*   df1bf_t = (u16*)alloc((size_t)BB * 256 * 2);
  float* dc2_s   = (float*)alloc((size_t)BB * 64 * 160 * 4);
  float* dc2_t   = (float*)alloc((size_t)BB * 64 * 160 * 4);
  u16*   W2p     = (u16*)alloc(90112 * 2);
  u16*   Wd2p    = (u16*)alloc(180224 * 2);
  float* dc1wp   = (float*)alloc(3072 * 4);
  u16*   ef1wbf  = (u16*)alloc((size_t)1310720 * 2);
  u16*   df2wbf  = (u16*)alloc((size_t)655360 * 2);
  float* Tbuf    = (float*)alloc((size_t)32768 * 4);
  float* logTbuf = (float*)alloc((size_t)32768 * 4);
  int*   srt     = (int*)alloc(512 * 4);
  float* Cbuf    = (float*)alloc(64 * 4);

  float* out_s  = (float*)d_out;
  float* out_t  = out_s + (size_t)BB * 2 * 1280;
  float* out_kl = out_s + (size_t)2 * BB * 2 * 1280;

  dim3 blk(256);

  // weight prepack + pad zeros
  prep_k<<<dim3(13868), blk, 0, stream>>>(ec2w, dc2w, dc1w, ef1w, df2w,
                                          W2p, Wd2p, dc1wp, ef1wbf, df2wbf,
                                          upT_s, upT_t, b2T_s, b2T_t);

  // encoders
  conv1_k<<<dim3(10240), blk, 0, stream>>>(x_s, ec1w, ec1b, back1_s);
  conv1_k<<<dim3(10240), blk, 0, stream>>>(x_t, ec1w, ec1b, back1_t);
  pool1T_k<<<dim3(11264), blk, 0, stream>>>(back1_s, p1T_s);
  pool1T_k<<<dim3(11264), blk, 0, stream>>>(back1_t, p1T_t);
  conv2_mfma<<<dim3(512), blk, 0, stream>>>(p1T_s, W2p, ec2b, b2T_s);
  conv2_mfma<<<dim3(512), blk, 0, stream>>>(p1T_t, W2p, ec2b, b2T_t);
  pool2_k<<<dim3(2560), blk, 0, stream>>>(b2T_s, p2bf_s);
  pool2_k<<<dim3(2560), blk, 0, stream>>>(b2T_t, p2bf_t);
  ef1_gemm<<<dim3(8), blk, 0, stream>>>(p2bf_s, ef1wbf, ef1b, ef1_s);
  ef1_gemm<<<dim3(8), blk, 0, stream>>>(p2bf_t, ef1wbf, ef1b, ef1_t);
  ef2df1_k<<<dim3(256), blk, 0, stream>>>(ef1_s, ef2w, ef2b, df1w, df1b, fea_s, df1bf_s);
  ef2df1_k<<<dim3(256), blk, 0, stream>>>(ef1_t, ef2w, ef2b, df1w, df1b, fea_t, df1bf_t);

  // d_f2 GEMM fused with upT build
  df2_gemm<<<dim3(40), blk, 0, stream>>>(df1bf_s, df2wbf, df2b, upT_s);
  df2_gemm<<<dim3(40), blk, 0, stream>>>(df1bf_t, df2wbf, df2b, upT_t);

  // decoder conv2 (cross skips: out_s uses back2_t)
  convd2_mfma<<<dim3(512), blk, 0, stream>>>(upT_s, b2T_t, Wd2p, dc2b, dc2_s);
  convd2_mfma<<<dim3(512), blk, 0, stream>>>(upT_t, b2T_s, Wd2p, dc2b, dc2_t);

  // decoder conv1 (cross skips: out_s uses back1_t)
  init_out_k<<<dim3(5120), blk, 0, stream>>>(out_s, dc1b);
  convd1_part<<<dim3(1280), blk, 0, stream>>>(dc2_s, back1_t, dc1wp, out_s);
  convd1_part<<<dim3(1280), blk, 0, stream>>>(dc2_t, back1_s, dc1wp, out_t);
  relu_out_k<<<dim3(5120), blk, 0, stream>>>(out_s);

  // pairwise KL
  kl_sort_k<<<dim3(1), blk, 0, stream>>>(lab_s, lab_t, srt);
  kl_build_k<<<dim3(32), blk, 0, stream>>>(fea_s, fea_t, srt, Tbuf, logTbuf);
  kl_pairs_k<<<dim3(64), blk, 0, stream>>>(Tbuf, logTbuf, Cbuf);
  kl_final_k<<<dim3(1), dim3(64), 0, stream>>>(Cbuf, out_kl);
}

// Round 7
// 953.026 us; speedup vs baseline: 7.5586x; 1.3437x over previous
//
#include <hip/hip_runtime.h>
#include <hip/hip_bf16.h>
#include <math.h>

#define BB   256
#define W1c  1280
#define W2c  160
#define C1c  64
#define C2c  128
#define KKc  11
#define LLc  8
#define DDc  64
#define GSc  32

typedef __attribute__((ext_vector_type(8))) short short8;
typedef __attribute__((ext_vector_type(4))) float f32x4;
typedef unsigned short u16;

__device__ inline float b2f(u16 h) { return __uint_as_float(((unsigned)h) << 16); }
__device__ inline u16 f2b(float f) {
  unsigned u = __float_as_uint(f);
  return (u16)((u + 0x7fffu + ((u >> 16) & 1u)) >> 16);
}

// ================= weight prepack + pad-zero (one kernel, index ranges) =================
// W2p[11][128][64]bf16  Wd2p[11][64][256]bf16  dc1wp[2][128][12]f32  ef1wbf[512][2560]bf16
// df2wbf[2560][256]bf16  zero pads of upT/back2T  W1p[64][32]bf16 (kk=ic*16+k, k<11)
#define PRE_W2P   90112
#define PRE_WD2P  270336
#define PRE_DC1   273408
#define PRE_EF1   1584128
#define PRE_DF2   2239488
#define PRE_UPT   2501632
#define PRE_B2T   3550208
#define PRE_W1P   3552256
__global__ __launch_bounds__(256) void prep_k(const float* __restrict__ ec2w, const float* __restrict__ dc2w,
                       const float* __restrict__ dc1w, const float* __restrict__ ef1w,
                       const float* __restrict__ df2w, const float* __restrict__ ec1w,
                       u16* __restrict__ W2p, u16* __restrict__ Wd2p, float* __restrict__ dc1wp,
                       u16* __restrict__ ef1wbf, u16* __restrict__ df2wbf, u16* __restrict__ W1p,
                       u16* __restrict__ upT_s, u16* __restrict__ upT_t,
                       u16* __restrict__ b2T_s, u16* __restrict__ b2T_t) {
  int idx = blockIdx.x * 256 + threadIdx.x;
  if (idx < PRE_W2P) {
    int k = idx / 8192, oc = (idx / 64) % 128, ic = idx % 64;
    W2p[idx] = f2b(ec2w[(oc * 64 + ic) * 11 + k]);
  } else if (idx < PRE_WD2P) {
    int j = idx - PRE_W2P;
    int k = j / 16384, oc = (j / 256) % 64, icc = j % 256;
    Wd2p[j] = f2b(dc2w[(oc * 256 + icc) * 11 + k]);
  } else if (idx < PRE_DC1) {
    int j = idx - PRE_WD2P;
    int oc = j / 1536, ic = (j / 12) % 128, k = j % 12;
    dc1wp[j] = (k < 11) ? dc1w[(oc * 128 + ic) * 11 + k] : 0.f;
  } else if (idx < PRE_EF1) {
    int j = idx - PRE_DC1;
    ef1wbf[j] = f2b(ef1w[j]);
  } else if (idx < PRE_DF2) {
    int j = idx - PRE_EF1;
    df2wbf[j] = f2b(df2w[j]);
  } else if (idx < PRE_UPT) {
    int j = idx - PRE_DF2;
    int ic = j % 128, r4 = (j / 128) % 4, b = (j / 512) % 256, side = j / 131072;
    int row = (r4 == 0) ? 0 : (20 + r4);             // rows 0,21,22,23
    (side ? upT_t : upT_s)[((size_t)b * 24 + row) * 128 + ic] = 0;
  } else if (idx < PRE_B2T) {
    int j = idx - PRE_UPT;
    int ic = j % 128, pr = (j / 128) % 16, b = (j / 2048) % 256, side = j / 524288;
    int row = (pr < 8) ? pr : pr + 160;
    (side ? b2T_t : b2T_s)[((size_t)b * 176 + row) * 128 + ic] = 0;
  } else if (idx < PRE_W1P) {
    int j = idx - PRE_B2T;
    int oc = j >> 5, kk = j & 31, ic = kk >> 4, k = kk & 15;
    W1p[j] = (k < 11) ? f2b(ec1w[oc * 22 + ic * 11 + k]) : 0;
  }
}

// ================= im2col for conv1: x[b][2][1280]f32 -> xcol[b][w][32]bf16 =================
// kk = ic*16+k ; value = x[ic][w+k-5] (zeros outside, k>=11)
__global__ __launch_bounds__(256) void im2col1_k(const float* __restrict__ x, u16* __restrict__ xcol) {
  int idx = blockIdx.x * 256 + threadIdx.x;          // 256*2*160
  int wg = idx % 160, ic = (idx / 160) & 1, b = idx / 320;
  int w0 = wg * 8;
  const float* xb = x + (size_t)(b * 2 + ic) * 1280;
  u16 win[18];
#pragma unroll
  for (int j = 0; j < 18; j++) {
    int p = w0 - 5 + j;
    win[j] = (p >= 0 && p < 1280) ? f2b(xb[p]) : 0;
  }
#pragma unroll
  for (int r = 0; r < 8; r++) {
    uint4 s0, s1;
    s0.x = (unsigned)win[r + 0] | ((unsigned)win[r + 1] << 16);
    s0.y = (unsigned)win[r + 2] | ((unsigned)win[r + 3] << 16);
    s0.z = (unsigned)win[r + 4] | ((unsigned)win[r + 5] << 16);
    s0.w = (unsigned)win[r + 6] | ((unsigned)win[r + 7] << 16);
    s1.x = (unsigned)win[r + 8] | ((unsigned)win[r + 9] << 16);
    s1.y = (unsigned)win[r + 10];
    s1.z = 0; s1.w = 0;
    u16* dst = xcol + ((size_t)(b * 1280 + w0 + r) * 32 + ic * 16);
    *(uint4*)dst = s0;
    *(uint4*)(dst + 8) = s1;
  }
}

// ================= conv1 MFMA: W1p[64][32] x xcol -> back1 bf16 (bias+relu) =================
// grid = b*4 ; 4 waves = 4 oc-frags ; wave: 20 n-frags (320 w)
__global__ __launch_bounds__(256) void conv1_mfma(const u16* __restrict__ xcol, const u16* __restrict__ W1p,
                           const float* __restrict__ bias, u16* __restrict__ back1) {
  int blk = blockIdx.x;
  int b = blk >> 2, wq = blk & 3;
  int tid = threadIdx.x, wid = tid >> 6, l = tid & 63;
  int l15 = l & 15, lq = l >> 4;
  int oc0 = wid * 16;
  int w0 = wq * 320;
  short8 a = *(const short8*)(W1p + (oc0 + l15) * 32 + lq * 8);
  f32x4 zero = {0.f, 0.f, 0.f, 0.f};
  f32x4 acc[20];
#pragma unroll
  for (int j = 0; j < 20; j++) acc[j] = zero;
  const u16* xb = xcol + (size_t)b * 1280 * 32;
#pragma unroll
  for (int nf = 0; nf < 20; nf++) {
    int w = w0 + nf * 16 + l15;
    short8 bf = *(const short8*)(xb + (size_t)w * 32 + lq * 8);
    acc[nf] = __builtin_amdgcn_mfma_f32_16x16x32_bf16(a, bf, acc[nf], 0, 0, 0);
  }
  int ocb = oc0 + lq * 4;
  float b0 = bias[ocb], b1 = bias[ocb + 1], b2 = bias[ocb + 2], b3 = bias[ocb + 3];
#pragma unroll
  for (int nf = 0; nf < 20; nf++) {
    int w = w0 + nf * 16 + l15;
    back1[((size_t)b * 64 + ocb + 0) * 1280 + w] = f2b(fmaxf(acc[nf][0] + b0, 0.f));
    back1[((size_t)b * 64 + ocb + 1) * 1280 + w] = f2b(fmaxf(acc[nf][1] + b1, 0.f));
    back1[((size_t)b * 64 + ocb + 2) * 1280 + w] = f2b(fmaxf(acc[nf][2] + b2, 0.f));
    back1[((size_t)b * 64 + ocb + 3) * 1280 + w] = f2b(fmaxf(acc[nf][3] + b3, 0.f));
  }
}

// ================= pool8 + transpose: back1 bf16 -> p1T[b][176][64] bf16 (pad rows zero) ====
__global__ __launch_bounds__(256) void pool1T_k(const u16* __restrict__ back1, u16* __restrict__ p1T) {
  int idx = blockIdx.x * 256 + threadIdx.x;          // 256*176*64
  int ic = idx % 64, row = (idx / 64) % 176, b = idx / 11264;
  u16 val = 0;
  if (row >= 8 && row < 168) {
    const u16* pp = back1 + ((size_t)b * 64 + ic) * 1280 + (row - 8) * 8;
    uint4 v = *(const uint4*)pp;
    float m = b2f((u16)(v.x & 0xffff));
    m = fmaxf(m, b2f((u16)(v.x >> 16)));
    m = fmaxf(m, b2f((u16)(v.y & 0xffff))); m = fmaxf(m, b2f((u16)(v.y >> 16)));
    m = fmaxf(m, b2f((u16)(v.z & 0xffff))); m = fmaxf(m, b2f((u16)(v.z >> 16)));
    m = fmaxf(m, b2f((u16)(v.w & 0xffff))); m = fmaxf(m, b2f((u16)(v.w >> 16)));
    val = f2b(m);
  }
  p1T[idx] = val;
}

// ================= conv2 implicit-GEMM MFMA: p1T x W2p -> back2T (bf16, bias+relu) =========
__global__ __launch_bounds__(256) void conv2_mfma(const u16* __restrict__ p1T, const u16* __restrict__ W2p,
                           const float* __restrict__ bias, u16* __restrict__ back2T) {
  int blk = blockIdx.x;
  int b = blk >> 1, wh = blk & 1;
  int tid = threadIdx.x, wid = tid >> 6, l = tid & 63;
  int l15 = l & 15, lq = l >> 4;
  int oc0 = wid * 32;
  int w0 = wh * 80;
  f32x4 zero = {0.f, 0.f, 0.f, 0.f};
  f32x4 acc[2][5];
#pragma unroll
  for (int i = 0; i < 2; i++)
#pragma unroll
    for (int j = 0; j < 5; j++) acc[i][j] = zero;
  const u16* pb = p1T + (size_t)b * 176 * 64;
  for (int k = 0; k < 11; k++) {
    for (int ic0 = 0; ic0 < 64; ic0 += 32) {
      short8 a0 = *(const short8*)(W2p + ((k * 128 + oc0 + l15) * 64 + ic0 + lq * 8));
      short8 a1 = *(const short8*)(W2p + ((k * 128 + oc0 + 16 + l15) * 64 + ic0 + lq * 8));
      short8 bf[5];
#pragma unroll
      for (int nf = 0; nf < 5; nf++) {
        int w = w0 + nf * 16 + l15;
        bf[nf] = *(const short8*)(pb + ((w + k + 3) * 64 + ic0 + lq * 8));
      }
#pragma unroll
      for (int nf = 0; nf < 5; nf++) {
        acc[0][nf] = __builtin_amdgcn_mfma_f32_16x16x32_bf16(a0, bf[nf], acc[0][nf], 0, 0, 0);
        acc[1][nf] = __builtin_amdgcn_mfma_f32_16x16x32_bf16(a1, bf[nf], acc[1][nf], 0, 0, 0);
      }
    }
  }
#pragma unroll
  for (int mf = 0; mf < 2; mf++) {
    int ocb = oc0 + mf * 16 + lq * 4;
    float b0 = bias[ocb], b1 = bias[ocb + 1], b2 = bias[ocb + 2], b3 = bias[ocb + 3];
#pragma unroll
    for (int nf = 0; nf < 5; nf++) {
      int w = w0 + nf * 16 + l15;
      f32x4 v = acc[mf][nf];
      unsigned r0 = (unsigned)f2b(fmaxf(v[0] + b0, 0.f)) | ((unsigned)f2b(fmaxf(v[1] + b1, 0.f)) << 16);
      unsigned r1 = (unsigned)f2b(fmaxf(v[2] + b2, 0.f)) | ((unsigned)f2b(fmaxf(v[3] + b3, 0.f)) << 16);
      uint2 st; st.x = r0; st.y = r1;
      *(uint2*)(back2T + ((size_t)(b * 176 + 8 + w) * 128 + ocb)) = st;
    }
  }
}

// ================= pool2: back2T -> pool2bf[b][2560] bf16 =================
__global__ __launch_bounds__(256) void pool2_k(const u16* __restrict__ b2T, u16* __restrict__ pool2bf) {
  int idx = blockIdx.x * 256 + threadIdx.x;          // 256*128*20
  int wo = idx % 20, oc = (idx / 20) % 128, b = idx / 2560;
  float m = -1e30f;
#pragma unroll
  for (int j = 0; j < 8; j++)
    m = fmaxf(m, b2f(b2T[((size_t)b * 176 + 8 + wo * 8 + j) * 128 + oc]));
  pool2bf[idx] = f2b(m);
}

// ================= e_f1 GEMM MFMA (grid 32 = 8 n-blocks x 4 m-blocks) =================
__global__ __launch_bounds__(256) void ef1_gemm(const u16* __restrict__ A, const u16* __restrict__ Bw,
                         const float* __restrict__ bias, float* __restrict__ out) {
  int blk = blockIdx.x;
  int n0 = (blk & 7) * 64;
  int tid = threadIdx.x, wid = tid >> 6, l = tid & 63;
  int l15 = l & 15, lq = l >> 4;
  int m0 = (blk >> 3) * 64 + wid * 16;
  f32x4 zero = {0.f, 0.f, 0.f, 0.f};
  f32x4 acc[4];
#pragma unroll
  for (int j = 0; j < 4; j++) acc[j] = zero;
  for (int k0 = 0; k0 < 2560; k0 += 32) {
    short8 af = *(const short8*)(A + ((size_t)(m0 + l15) * 2560 + k0 + lq * 8));
    short8 bf[4];
#pragma unroll
    for (int nf = 0; nf < 4; nf++)
      bf[nf] = *(const short8*)(Bw + ((size_t)(n0 + nf * 16 + l15) * 2560 + k0 + lq * 8));
#pragma unroll
    for (int nf = 0; nf < 4; nf++)
      acc[nf] = __builtin_amdgcn_mfma_f32_16x16x32_bf16(af, bf[nf], acc[nf], 0, 0, 0);
  }
  int bb = m0 + lq * 4;
#pragma unroll
  for (int nf = 0; nf < 4; nf++) {
    int oc = n0 + nf * 16 + l15;
    float bi = bias[oc];
#pragma unroll
    for (int r = 0; r < 4; r++)
      out[(size_t)(bb + r) * 512 + oc] = fmaxf(acc[nf][r] + bi, 0.f);
  }
}

// ================= fused e_f2(sigmoid) + d_f1(relu): one block per batch row =================
__global__ __launch_bounds__(256) void ef2df1_k(const float* __restrict__ ef1, const float* __restrict__ ef2w,
                         const float* __restrict__ ef2b, const float* __restrict__ df1w,
                         const float* __restrict__ df1b, float* __restrict__ fea,
                         u16* __restrict__ df1bf) {
  __shared__ float row[512];
  __shared__ float part[256];
  __shared__ float fea_sh[64];
  int b = blockIdx.x, tid = threadIdx.x;
  row[tid] = ef1[(size_t)b * 512 + tid];
  row[tid + 256] = ef1[(size_t)b * 512 + tid + 256];
  __syncthreads();
  {
    int o = tid & 63, q = tid >> 6;
    const float4* wr = (const float4*)(ef2w + (size_t)o * 512 + q * 128);
    float s = 0.f;
    int base = q * 128;
#pragma unroll
    for (int i = 0; i < 32; i++) {
      float4 wv = wr[i];
      s += row[base + 4 * i] * wv.x + row[base + 4 * i + 1] * wv.y +
           row[base + 4 * i + 2] * wv.z + row[base + 4 * i + 3] * wv.w;
    }
    part[q * 64 + o] = s;
  }
  __syncthreads();
  if (tid < 64) {
    float v = part[tid] + part[64 + tid] + part[128 + tid] + part[192 + tid] + ef2b[tid];
    float sg = 1.f / (1.f + expf(-v));
    fea_sh[tid] = sg;
    fea[(size_t)b * 64 + tid] = sg;
  }
  __syncthreads();
  {
    const float4* wr = (const float4*)(df1w + (size_t)tid * 64);
    float s = 0.f;
#pragma unroll
    for (int i = 0; i < 16; i++) {
      float4 wv = wr[i];
      s += fea_sh[4 * i] * wv.x + fea_sh[4 * i + 1] * wv.y +
           fea_sh[4 * i + 2] * wv.z + fea_sh[4 * i + 3] * wv.w;
    }
    df1bf[(size_t)b * 256 + tid] = f2b(fmaxf(s + df1b[tid], 0.f));
  }
}

// ================= d_f2 GEMM MFMA fused with upT build =================
__global__ __launch_bounds__(256) void df2_gemm(const u16* __restrict__ A, const u16* __restrict__ Bw,
                         const float* __restrict__ bias, u16* __restrict__ upT) {
  int n0 = blockIdx.x * 64;
  int tid = threadIdx.x, wid = tid >> 6, l = tid & 63;
  int l15 = l & 15, lq = l >> 4;
  int m0 = wid * 64;
  f32x4 zero = {0.f, 0.f, 0.f, 0.f};
  f32x4 acc[4][4];
#pragma unroll
  for (int i = 0; i < 4; i++)
#pragma unroll
    for (int j = 0; j < 4; j++) acc[i][j] = zero;
  for (int k0 = 0; k0 < 256; k0 += 32) {
    short8 af[4], bf[4];
#pragma unroll
    for (int mf = 0; mf < 4; mf++)
      af[mf] = *(const short8*)(A + ((size_t)(m0 + mf * 16 + l15) * 256 + k0 + lq * 8));
#pragma unroll
    for (int nf = 0; nf < 4; nf++)
      bf[nf] = *(const short8*)(Bw + ((size_t)(n0 + nf * 16 + l15) * 256 + k0 + lq * 8));
#pragma unroll
    for (int mf = 0; mf < 4; mf++)
#pragma unroll
      for (int nf = 0; nf < 4; nf++)
        acc[mf][nf] = __builtin_amdgcn_mfma_f32_16x16x32_bf16(af[mf], bf[nf], acc[mf][nf], 0, 0, 0);
  }
#pragma unroll
  for (int nf = 0; nf < 4; nf++) {
    int o = n0 + nf * 16 + l15;
    float bi = bias[o];
    int ch = o / 20, t = o - ch * 20;
#pragma unroll
    for (int mf = 0; mf < 4; mf++) {
      int bb = m0 + mf * 16 + lq * 4;
#pragma unroll
      for (int r = 0; r < 4; r++)
        upT[((size_t)(bb + r) * 24 + 1 + t) * 128 + ch] = f2b(fmaxf(acc[mf][nf][r] + bi, 0.f));
    }
  }
}

// ================= decoder conv2 implicit-GEMM MFMA =================
__global__ __launch_bounds__(256) void convd2_mfma(const u16* __restrict__ upT, const u16* __restrict__ skipT,
                            const u16* __restrict__ Wd2p, const float* __restrict__ bias,
                            float* __restrict__ dc2) {
  int blk = blockIdx.x;
  int b = blk >> 1, wh = blk & 1;
  int tid = threadIdx.x, wid = tid >> 6, l = tid & 63;
  int l15 = l & 15, lq = l >> 4;
  int oc0 = wid * 16;
  int w0 = wh * 80;
  f32x4 zero = {0.f, 0.f, 0.f, 0.f};
  f32x4 acc[5];
#pragma unroll
  for (int j = 0; j < 5; j++) acc[j] = zero;
  const u16* ub = upT + (size_t)b * 24 * 128;
  const u16* sb = skipT + (size_t)b * 176 * 128;
  for (int k = 0; k < 11; k++) {
    for (int ic0 = 0; ic0 < 128; ic0 += 32) {
      short8 a = *(const short8*)(Wd2p + ((k * 64 + oc0 + l15) * 256 + ic0 + lq * 8));
#pragma unroll
      for (int nf = 0; nf < 5; nf++) {
        int w = w0 + nf * 16 + l15;
        int r = (w + k + 3) >> 3;
        short8 bf = *(const short8*)(ub + (r * 128 + ic0 + lq * 8));
        acc[nf] = __builtin_amdgcn_mfma_f32_16x16x32_bf16(a, bf, acc[nf], 0, 0, 0);
      }
    }
    for (int ic0 = 0; ic0 < 128; ic0 += 32) {
      short8 a = *(const short8*)(Wd2p + ((k * 64 + oc0 + l15) * 256 + 128 + ic0 + lq * 8));
#pragma unroll
      for (int nf = 0; nf < 5; nf++) {
        int w = w0 + nf * 16 + l15;
        short8 bf = *(const short8*)(sb + ((size_t)(w + k + 3) * 128 + ic0 + lq * 8));
        acc[nf] = __builtin_amdgcn_mfma_f32_16x16x32_bf16(a, bf, acc[nf], 0, 0, 0);
      }
    }
  }
  int ocb = oc0 + lq * 4;
  float bb0 = bias[ocb], bb1 = bias[ocb + 1], bb2 = bias[ocb + 2], bb3 = bias[ocb + 3];
#pragma unroll
  for (int nf = 0; nf < 5; nf++) {
    int w = w0 + nf * 16 + l15;
    dc2[((size_t)b * 64 + ocb + 0) * 160 + w] = fmaxf(acc[nf][0] + bb0, 0.f);
    dc2[((size_t)b * 64 + ocb + 1) * 160 + w] = fmaxf(acc[nf][1] + bb1, 0.f);
    dc2[((size_t)b * 64 + ocb + 2) * 160 + w] = fmaxf(acc[nf][2] + bb2, 0.f);
    dc2[((size_t)b * 64 + ocb + 3) * 160 + w] = fmaxf(acc[nf][3] + bb3, 0.f);
  }
}

// ================= out init (bias) / relu =================
__global__ __launch_bounds__(256) void init_out_k(float* __restrict__ out, const float* __restrict__ bias) {
  int idx = blockIdx.x * 256 + threadIdx.x;
  int oc = (idx / 1280) & 1;
  out[idx] = bias[oc];
}
__global__ __launch_bounds__(256) void relu_out_k(float* __restrict__ out) {
  int idx = blockIdx.x * 256 + threadIdx.x;
  out[idx] = fmaxf(out[idx], 0.f);
}

// ================= decoder conv1 (f32, ic-split x4, atomic accumulate) =================
__global__ __launch_bounds__(256) void convd1_part(const float* __restrict__ up, const u16* __restrict__ skip,
                            const float* __restrict__ wp, float* __restrict__ out) {
  int idx = blockIdx.x * 256 + threadIdx.x;          // 4*256*2*160
  int wg = idx % 160, oc = (idx / 160) % 2, split = (idx / 320) % 4, b = idx / 1280;
  int w0 = wg * 8;
  float acc[8];
#pragma unroll
  for (int r = 0; r < 8; r++) acc[r] = 0.f;
  int c0 = split * 32;
  for (int c = c0; c < c0 + 32; c++) {
    const float4* wr = (const float4*)(wp + ((size_t)oc * 128 + c) * 12);
    float4 q0 = wr[0], q1 = wr[1], q2 = wr[2];
    float wt[11] = {q0.x, q0.y, q0.z, q0.w, q1.x, q1.y, q1.z, q1.w, q2.x, q2.y, q2.z};
    if (c < 64) {
      const float* dr = up + ((size_t)b * 64 + c) * 160;
      float u[3];
      u[0] = (wg > 0)   ? dr[wg - 1] : 0.f;
      u[1] = dr[wg];
      u[2] = (wg < 159) ? dr[wg + 1] : 0.f;
#pragma unroll
      for (int k = 0; k < 11; k++)
#pragma unroll
        for (int r = 0; r < 8; r++)
          acc[r] += wt[k] * u[(r + k + 3) >> 3];
    } else {
      int sc = c - 64;
      const u16* sr = skip + ((size_t)b * 64 + sc) * 1280;
      float s[20];
#pragma unroll
      for (int p = 0; p < 10; p++) {
        int wlo = w0 - 6 + 2 * p;
        if (wlo >= 0 && wlo + 1 < 1280) {
          unsigned v = *(const unsigned*)(sr + wlo);
          s[2 * p]     = __uint_as_float(v << 16);
          s[2 * p + 1] = __uint_as_float(v & 0xffff0000u);
        } else {
          s[2 * p]     = (wlo >= 0 && wlo < 1280)         ? b2f(sr[wlo])     : 0.f;
          s[2 * p + 1] = (wlo + 1 >= 0 && wlo + 1 < 1280) ? b2f(sr[wlo + 1]) : 0.f;
        }
      }
#pragma unroll
      for (int k = 0; k < 11; k++)
#pragma unroll
        for (int r = 0; r < 8; r++)
          acc[r] += wt[k] * s[k + r + 1];
      }
  }
  float* ob = out + ((size_t)b * 2 + oc) * 1280 + w0;
#pragma unroll
  for (int r = 0; r < 8; r++) atomicAdd(ob + r, acc[r]);
}

// ================= KL: sort -> build -> pair-dots -> finalize =================
__global__ void kl_sort_k(const int* __restrict__ lab_s, const int* __restrict__ lab_t,
                          int* __restrict__ srt) {
  int t = threadIdx.x;
  {
    int lab = lab_s[t];
    int pos = 0;
    for (int b = 0; b < BB; b++) {
      int lb = lab_s[b];
      pos += (lb < lab) + ((b < t) && (lb == lab));
    }
    srt[pos] = t;
  }
  {
    int lab = lab_t[t];
    int pos = 0;
    for (int b = 0; b < BB; b++) {
      int lb = lab_t[b];
      pos += (lb < lab) + ((b < t) && (lb == lab));
    }
    srt[256 + pos] = t;
  }
}

__global__ void kl_build_k(const float* __restrict__ fea_s, const float* __restrict__ fea_t,
                           const int* __restrict__ srt,
                           float* __restrict__ T, float* __restrict__ logT) {
  int idx = blockIdx.x * 256 + threadIdx.x;          // 8192 threads, 4 elems each
#pragma unroll
  for (int r = 0; r < 4; r++) {
    int e = idx + r * 8192;
    int d = e & 63;
    int m = (e >> 6) & 63;
    int l = e >> 12;
    float v;
    if (m < GSc) v = fea_s[srt[l * GSc + m] * DDc + d];
    else         v = fea_t[srt[256 + l * GSc + (m - GSc)] * DDc + d];
    T[e]    = v;
    logT[e] = logf(v);
  }
}

__global__ void kl_pairs_k(const float* __restrict__ T, const float* __restrict__ logT,
                           float* __restrict__ C) {
  int blk = blockIdx.x;                              // 64 blocks: (i,j)
  int i = blk >> 3, j = blk & 7;
  int t = threadIdx.x;
  __shared__ float wsum[4];
  const float* li = logT + i * 4096;
  const float* tj = T + j * 4096;
  float s = 0.f;
  for (int e = t; e < 4096; e += 256) s += li[e] * tj[e];
  for (int off = 32; off > 0; off >>= 1) s += __shfl_down(s, off, 64);
  if ((t & 63) == 0) wsum[t >> 6] = s;
  __syncthreads();
  if (t == 0) C[blk] = wsum[0] + wsum[1] + wsum[2] + wsum[3];
}

__global__ void kl_final_k(const float* __restrict__ C, float* __restrict__ out) {
  int t = threadIdx.x;                               // 64 threads
  float c = C[t];
  float tr = ((t >> 3) == (t & 7)) ? c : 0.f;
  for (int off = 32; off > 0; off >>= 1) {
    c  += __shfl_down(c, off, 64);
    tr += __shfl_down(tr, off, 64);
  }
  if (t == 0) out[0] = (LLc * tr - c) / 4096.f / (LLc * LLc / 2.0f);
}

extern "C" void kernel_launch(void* const* d_in, const int* in_sizes, int n_in,
                              void* d_out, int out_size, void* d_ws, size_t ws_size,
                              hipStream_t stream) {
  const float* x_s  = (const float*)d_in[0];
  const float* x_t  = (const float*)d_in[1];
  const int* lab_s  = (const int*)d_in[2];
  const int* lab_t  = (const int*)d_in[3];
  const float* ec1w = (const float*)d_in[5];  const float* ec1b = (const float*)d_in[6];
  const float* ec2w = (const float*)d_in[7];  const float* ec2b = (const float*)d_in[8];
  const float* ef1w = (const float*)d_in[9];  const float* ef1b = (const float*)d_in[10];
  const float* ef2w = (const float*)d_in[11]; const float* ef2b = (const float*)d_in[12];
  const float* df1w = (const float*)d_in[13]; const float* df1b = (const float*)d_in[14];
  const float* df2w = (const float*)d_in[15]; const float* df2b = (const float*)d_in[16];
  const float* dc2w = (const float*)d_in[17]; const float* dc2b = (const float*)d_in[18];
  const float* dc1w = (const float*)d_in[19]; const float* dc1b = (const float*)d_in[20];

  char* p = (char*)d_ws;
  auto alloc = [&](size_t bytes) -> char* {
    char* r = p;
    p += (bytes + 255) & ~(size_t)255;
    return r;
  };
  u16*   back1_s = (u16*)alloc((size_t)BB * 64 * 1280 * 2);
  u16*   back1_t = (u16*)alloc((size_t)BB * 64 * 1280 * 2);
  u16*   xcol_s  = (u16*)alloc((size_t)BB * 1280 * 32 * 2);
  u16*   xcol_t  = (u16*)alloc((size_t)BB * 1280 * 32 * 2);
  u16*   p1T_s   = (u16*)alloc((size_t)BB * 176 * 64 * 2);
  u16*   p1T_t   = (u16*)alloc((size_t)BB * 176 * 64 * 2);
  u16*   b2T_s   = (u16*)alloc((size_t)BB * 176 * 128 * 2);
  u16*   b2T_t   = (u16*)alloc((size_t)BB * 176 * 128 * 2);
  u16*   upT_s   = (u16*)alloc((size_t)BB * 24 * 128 * 2);
  u16*   upT_t   = (u16*)alloc((size_t)BB * 24 * 128 * 2);
  u16*   p2bf_s  = (u16*)alloc((size_t)BB * 2560 * 2);
  u16*   p2bf_t  = (u16*)alloc((size_t)BB * 2560 * 2);
  float* ef1_s   = (float*)alloc((size_t)BB * 512 * 4);
  float* ef1_t   = (float*)alloc((size_t)BB * 512 * 4);
  float* fea_s   = (float*)alloc((size_t)BB * 64 * 4);
  float* fea_t   = (float*)alloc((size_t)BB * 64 * 4);
  u16*   df1bf_s = (u16*)alloc((size_t)BB * 256 * 2);
  u16*   df1bf_t = (u16*)alloc((size_t)BB * 256 * 2);
  float* dc2_s   = (float*)alloc((size_t)BB * 64 * 160 * 4);
  float* dc2_t   = (float*)alloc((size_t)BB * 64 * 160 * 4);
  u16*   W2p     = (u16*)alloc(90112 * 2);
  u16*   Wd2p    = (u16*)alloc(180224 * 2);
  float* dc1wp   = (float*)alloc(3072 * 4);
  u16*   ef1wbf  = (u16*)alloc((size_t)1310720 * 2);
  u16*   df2wbf  = (u16*)alloc((size_t)655360 * 2);
  u16*   W1p     = (u16*)alloc(2048 * 2);
  float* Tbuf    = (float*)alloc((size_t)32768 * 4);
  float* logTbuf = (float*)alloc((size_t)32768 * 4);
  int*   srt     = (int*)alloc(512 * 4);
  float* Cbuf    = (float*)alloc(64 * 4);

  float* out_s  = (float*)d_out;
  float* out_t  = out_s + (size_t)BB * 2 * 1280;
  float* out_kl = out_s + (size_t)2 * BB * 2 * 1280;

  dim3 blk(256);

  // weight prepack + pad zeros
  prep_k<<<dim3(13876), blk, 0, stream>>>(ec2w, dc2w, dc1w, ef1w, df2w, ec1w,
                                          W2p, Wd2p, dc1wp, ef1wbf, df2wbf, W1p,
                                          upT_s, upT_t, b2T_s, b2T_t);

  // encoders
  im2col1_k<<<dim3(320), blk, 0, stream>>>(x_s, xcol_s);
  im2col1_k<<<dim3(320), blk, 0, stream>>>(x_t, xcol_t);
  conv1_mfma<<<dim3(1024), blk, 0, stream>>>(xcol_s, W1p, ec1b, back1_s);
  conv1_mfma<<<dim3(1024), blk, 0, stream>>>(xcol_t, W1p, ec1b, back1_t);
  pool1T_k<<<dim3(11264), blk, 0, stream>>>(back1_s, p1T_s);
  pool1T_k<<<dim3(11264), blk, 0, stream>>>(back1_t, p1T_t);
  conv2_mfma<<<dim3(512), blk, 0, stream>>>(p1T_s, W2p, ec2b, b2T_s);
  conv2_mfma<<<dim3(512), blk, 0, stream>>>(p1T_t, W2p, ec2b, b2T_t);
  pool2_k<<<dim3(2560), blk, 0, stream>>>(b2T_s, p2bf_s);
  pool2_k<<<dim3(2560), blk, 0, stream>>>(b2T_t, p2bf_t);
  ef1_gemm<<<dim3(32), blk, 0, stream>>>(p2bf_s, ef1wbf, ef1b, ef1_s);
  ef1_gemm<<<dim3(32), blk, 0, stream>>>(p2bf_t, ef1wbf, ef1b, ef1_t);
  ef2df1_k<<<dim3(256), blk, 0, stream>>>(ef1_s, ef2w, ef2b, df1w, df1b, fea_s, df1bf_s);
  ef2df1_k<<<dim3(256), blk, 0, stream>>>(ef1_t, ef2w, ef2b, df1w, df1b, fea_t, df1bf_t);

  // d_f2 GEMM fused with upT build
  df2_gemm<<<dim3(40), blk, 0, stream>>>(df1bf_s, df2wbf, df2b, upT_s);
  df2_gemm<<<dim3(40), blk, 0, stream>>>(df1bf_t, df2wbf, df2b, upT_t);

  // decoder conv2 (cross skips: out_s uses back2_t)
  convd2_mfma<<<dim3(512), blk, 0, stream>>>(upT_s, b2T_t, Wd2p, dc2b, dc2_s);
  convd2_mfma<<<dim3(512), blk, 0, stream>>>(upT_t, b2T_s, Wd2p, dc2b, dc2_t);

  // decoder conv1 (cross skips: out_s uses back1_t)
  init_out_k<<<dim3(5120), blk, 0, stream>>>(out_s, dc1b);
  convd1_part<<<dim3(1280), blk, 0, stream>>>(dc2_s, back1_t, dc1wp, out_s);
  convd1_part<<<dim3(1280), blk, 0, stream>>>(dc2_t, back1_s, dc1wp, out_t);
  relu_out_k<<<dim3(5120), blk, 0, stream>>>(out_s);

  // pairwise KL
  kl_sort_k<<<dim3(1), blk, 0, stream>>>(lab_s, lab_t, srt);
  kl_build_k<<<dim3(32), blk, 0, stream>>>(fea_s, fea_t, srt, Tbuf, logTbuf);
  kl_pairs_k<<<dim3(64), blk, 0, stream>>>(Tbuf, logTbuf, Cbuf);
  kl_final_k<<<dim3(1), dim3(64), 0, stream>>>(Cbuf, out_kl);
}

// Round 8
// 908.817 us; speedup vs baseline: 7.9263x; 1.0486x over previous
//
#include <hip/hip_runtime.h>
#include <hip/hip_bf16.h>
#include <math.h>

#define BB   256
#define W1c  1280
#define W2c  160
#define C1c  64
#define C2c  128
#define KKc  11
#define LLc  8
#define DDc  64
#define GSc  32

typedef __attribute__((ext_vector_type(8))) short short8;
typedef __attribute__((ext_vector_type(4))) float f32x4;
typedef unsigned short u16;

__device__ inline float b2f(u16 h) { return __uint_as_float(((unsigned)h) << 16); }
__device__ inline u16 f2b(float f) {
  unsigned u = __float_as_uint(f);
  return (u16)((u + 0x7fffu + ((u >> 16) & 1u)) >> 16);
}

// ================= weight prepack + pad-zero (one kernel, index ranges) =================
// W2p[11][128][64]  Wd2p[11][64][256]  Wd1p[11][4][16][32] (oc>=2 zero)  ef1wbf[512][2560]
// df2wbf[2560][256]  W1p[64][32]  + zero pads: upT rows{0,21-23}, b2T rows{0-7,168-175},
// back1T rows{0-4,1285-1295}, dc2T rows{0,161}
#define PRE_W2P   90112
#define PRE_WD2P  270336
#define PRE_WD1P  292864
#define PRE_EF1   1603584
#define PRE_DF2   2258944
#define PRE_UPT   2521088
#define PRE_B2T   3569664
#define PRE_W1P   3571712
#define PRE_B1T   4096000
#define PRE_D2T   4161536
__global__ __launch_bounds__(256) void prep_k(const float* __restrict__ ec2w, const float* __restrict__ dc2w,
                       const float* __restrict__ dc1w, const float* __restrict__ ef1w,
                       const float* __restrict__ df2w, const float* __restrict__ ec1w,
                       u16* __restrict__ W2p, u16* __restrict__ Wd2p, u16* __restrict__ Wd1p,
                       u16* __restrict__ ef1wbf, u16* __restrict__ df2wbf, u16* __restrict__ W1p,
                       u16* __restrict__ upT_s, u16* __restrict__ upT_t,
                       u16* __restrict__ b2T_s, u16* __restrict__ b2T_t,
                       u16* __restrict__ b1T_s, u16* __restrict__ b1T_t,
                       u16* __restrict__ d2T_s, u16* __restrict__ d2T_t) {
  int idx = blockIdx.x * 256 + threadIdx.x;
  if (idx < PRE_W2P) {
    int k = idx / 8192, oc = (idx / 64) % 128, ic = idx % 64;
    W2p[idx] = f2b(ec2w[(oc * 64 + ic) * 11 + k]);
  } else if (idx < PRE_WD2P) {
    int j = idx - PRE_W2P;
    int k = j / 16384, oc = (j / 256) % 64, icc = j % 256;
    Wd2p[j] = f2b(dc2w[(oc * 256 + icc) * 11 + k]);
  } else if (idx < PRE_WD1P) {
    int j = idx - PRE_WD2P;                          // [11][4][16][32]
    int k = j / 2048, rem = j % 2048;
    int chunk = rem / 512, oc = (rem / 32) % 16, c = rem % 32;
    Wd1p[j] = (oc < 2) ? f2b(dc1w[((size_t)oc * 128 + chunk * 32 + c) * 11 + k]) : 0;
  } else if (idx < PRE_EF1) {
    int j = idx - PRE_WD1P;
    ef1wbf[j] = f2b(ef1w[j]);
  } else if (idx < PRE_DF2) {
    int j = idx - PRE_EF1;
    df2wbf[j] = f2b(df2w[j]);
  } else if (idx < PRE_UPT) {
    int j = idx - PRE_DF2;
    int ic = j % 128, r4 = (j / 128) % 4, b = (j / 512) % 256, side = j / 131072;
    int row = (r4 == 0) ? 0 : (20 + r4);             // rows 0,21,22,23
    (side ? upT_t : upT_s)[((size_t)b * 24 + row) * 128 + ic] = 0;
  } else if (idx < PRE_B2T) {
    int j = idx - PRE_UPT;
    int ic = j % 128, pr = (j / 128) % 16, b = (j / 2048) % 256, side = j / 524288;
    int row = (pr < 8) ? pr : pr + 160;
    (side ? b2T_t : b2T_s)[((size_t)b * 176 + row) * 128 + ic] = 0;
  } else if (idx < PRE_W1P) {
    int j = idx - PRE_B2T;
    int oc = j >> 5, kk = j & 31, ic = kk >> 4, k = kk & 15;
    W1p[j] = (k < 11) ? f2b(ec1w[oc * 22 + ic * 11 + k]) : 0;
  } else if (idx < PRE_B1T) {
    int j = idx - PRE_W1P;                           // rows 0-4, 1285-1295
    int ic = j % 64, pr = (j / 64) % 16, b = (j / 1024) % 256, side = j / 262144;
    int row = (pr < 5) ? pr : 1280 + pr;             // pr 5..15 -> 1285..1295
    (side ? b1T_t : b1T_s)[((size_t)b * 1296 + row) * 64 + ic] = 0;
  } else if (idx < PRE_D2T) {
    int j = idx - PRE_B1T;                           // rows 0, 161
    int ic = j % 64, pr = (j / 64) & 1, b = (j / 128) % 256, side = j / 32768;
    int row = pr ? 161 : 0;
    (side ? d2T_t : d2T_s)[((size_t)b * 162 + row) * 64 + ic] = 0;
  }
}

// ================= im2col for conv1: x[b][2][1280]f32 -> xcol[b][w][32]bf16 =================
__global__ __launch_bounds__(256) void im2col1_k(const float* __restrict__ x, u16* __restrict__ xcol) {
  int idx = blockIdx.x * 256 + threadIdx.x;          // 256*2*160
  int wg = idx % 160, ic = (idx / 160) & 1, b = idx / 320;
  int w0 = wg * 8;
  const float* xb = x + (size_t)(b * 2 + ic) * 1280;
  u16 win[18];
#pragma unroll
  for (int j = 0; j < 18; j++) {
    int p = w0 - 5 + j;
    win[j] = (p >= 0 && p < 1280) ? f2b(xb[p]) : 0;
  }
#pragma unroll
  for (int r = 0; r < 8; r++) {
    uint4 s0, s1;
    s0.x = (unsigned)win[r + 0] | ((unsigned)win[r + 1] << 16);
    s0.y = (unsigned)win[r + 2] | ((unsigned)win[r + 3] << 16);
    s0.z = (unsigned)win[r + 4] | ((unsigned)win[r + 5] << 16);
    s0.w = (unsigned)win[r + 6] | ((unsigned)win[r + 7] << 16);
    s1.x = (unsigned)win[r + 8] | ((unsigned)win[r + 9] << 16);
    s1.y = (unsigned)win[r + 10];
    s1.z = 0; s1.w = 0;
    u16* dst = xcol + ((size_t)(b * 1280 + w0 + r) * 32 + ic * 16);
    *(uint4*)dst = s0;
    *(uint4*)(dst + 8) = s1;
  }
}

// ================= conv1 MFMA: W1p[64][32] x xcol -> back1T[b][1296][64] (bias+relu) ========
// row = w+5 ; per lane: 4 oc consecutive at fixed w -> uint2 store
__global__ __launch_bounds__(256) void conv1_mfma(const u16* __restrict__ xcol, const u16* __restrict__ W1p,
                           const float* __restrict__ bias, u16* __restrict__ back1T) {
  int blk = blockIdx.x;
  int b = blk >> 2, wq = blk & 3;
  int tid = threadIdx.x, wid = tid >> 6, l = tid & 63;
  int l15 = l & 15, lq = l >> 4;
  int oc0 = wid * 16;
  int w0 = wq * 320;
  short8 a = *(const short8*)(W1p + (oc0 + l15) * 32 + lq * 8);
  f32x4 zero = {0.f, 0.f, 0.f, 0.f};
  f32x4 acc[20];
#pragma unroll
  for (int j = 0; j < 20; j++) acc[j] = zero;
  const u16* xb = xcol + (size_t)b * 1280 * 32;
#pragma unroll
  for (int nf = 0; nf < 20; nf++) {
    int w = w0 + nf * 16 + l15;
    short8 bf = *(const short8*)(xb + (size_t)w * 32 + lq * 8);
    acc[nf] = __builtin_amdgcn_mfma_f32_16x16x32_bf16(a, bf, acc[nf], 0, 0, 0);
  }
  int ocb = oc0 + lq * 4;
  float b0 = bias[ocb], b1 = bias[ocb + 1], b2 = bias[ocb + 2], b3 = bias[ocb + 3];
#pragma unroll
  for (int nf = 0; nf < 20; nf++) {
    int w = w0 + nf * 16 + l15;
    uint2 st;
    st.x = (unsigned)f2b(fmaxf(acc[nf][0] + b0, 0.f)) | ((unsigned)f2b(fmaxf(acc[nf][1] + b1, 0.f)) << 16);
    st.y = (unsigned)f2b(fmaxf(acc[nf][2] + b2, 0.f)) | ((unsigned)f2b(fmaxf(acc[nf][3] + b3, 0.f)) << 16);
    *(uint2*)(back1T + ((size_t)b * 1296 + w + 5) * 64 + ocb) = st;
  }
}

// ================= pool8 + transpose: back1T -> p1T[b][176][64] (pad rows zero) =============
__global__ __launch_bounds__(256) void pool1T_k(const u16* __restrict__ back1T, u16* __restrict__ p1T) {
  int idx = blockIdx.x * 256 + threadIdx.x;          // 256*176*64
  int ic = idx % 64, row = (idx / 64) % 176, b = idx / 11264;
  u16 val = 0;
  if (row >= 8 && row < 168) {
    const u16* pp = back1T + ((size_t)b * 1296 + (row - 8) * 8 + 5) * 64 + ic;
    float m = b2f(pp[0]);
#pragma unroll
    for (int j = 1; j < 8; j++) m = fmaxf(m, b2f(pp[j * 64]));
    val = f2b(m);
  }
  p1T[idx] = val;
}

// ================= conv2 implicit-GEMM MFMA: p1T x W2p -> back2T (bf16, bias+relu) =========
__global__ __launch_bounds__(256) void conv2_mfma(const u16* __restrict__ p1T, const u16* __restrict__ W2p,
                           const float* __restrict__ bias, u16* __restrict__ back2T) {
  int blk = blockIdx.x;
  int b = blk >> 1, wh = blk & 1;
  int tid = threadIdx.x, wid = tid >> 6, l = tid & 63;
  int l15 = l & 15, lq = l >> 4;
  int oc0 = wid * 32;
  int w0 = wh * 80;
  f32x4 zero = {0.f, 0.f, 0.f, 0.f};
  f32x4 acc[2][5];
#pragma unroll
  for (int i = 0; i < 2; i++)
#pragma unroll
    for (int j = 0; j < 5; j++) acc[i][j] = zero;
  const u16* pb = p1T + (size_t)b * 176 * 64;
  for (int k = 0; k < 11; k++) {
    for (int ic0 = 0; ic0 < 64; ic0 += 32) {
      short8 a0 = *(const short8*)(W2p + ((k * 128 + oc0 + l15) * 64 + ic0 + lq * 8));
      short8 a1 = *(const short8*)(W2p + ((k * 128 + oc0 + 16 + l15) * 64 + ic0 + lq * 8));
      short8 bf[5];
#pragma unroll
      for (int nf = 0; nf < 5; nf++) {
        int w = w0 + nf * 16 + l15;
        bf[nf] = *(const short8*)(pb + ((w + k + 3) * 64 + ic0 + lq * 8));
      }
#pragma unroll
      for (int nf = 0; nf < 5; nf++) {
        acc[0][nf] = __builtin_amdgcn_mfma_f32_16x16x32_bf16(a0, bf[nf], acc[0][nf], 0, 0, 0);
        acc[1][nf] = __builtin_amdgcn_mfma_f32_16x16x32_bf16(a1, bf[nf], acc[1][nf], 0, 0, 0);
      }
    }
  }
#pragma unroll
  for (int mf = 0; mf < 2; mf++) {
    int ocb = oc0 + mf * 16 + lq * 4;
    float b0 = bias[ocb], b1 = bias[ocb + 1], b2 = bias[ocb + 2], b3 = bias[ocb + 3];
#pragma unroll
    for (int nf = 0; nf < 5; nf++) {
      int w = w0 + nf * 16 + l15;
      f32x4 v = acc[mf][nf];
      unsigned r0 = (unsigned)f2b(fmaxf(v[0] + b0, 0.f)) | ((unsigned)f2b(fmaxf(v[1] + b1, 0.f)) << 16);
      unsigned r1 = (unsigned)f2b(fmaxf(v[2] + b2, 0.f)) | ((unsigned)f2b(fmaxf(v[3] + b3, 0.f)) << 16);
      uint2 st; st.x = r0; st.y = r1;
      *(uint2*)(back2T + ((size_t)(b * 176 + 8 + w) * 128 + ocb)) = st;
    }
  }
}

// ================= pool2: back2T -> pool2bf[b][2560] bf16 =================
__global__ __launch_bounds__(256) void pool2_k(const u16* __restrict__ b2T, u16* __restrict__ pool2bf) {
  int idx = blockIdx.x * 256 + threadIdx.x;          // 256*128*20
  int wo = idx % 20, oc = (idx / 20) % 128, b = idx / 2560;
  float m = -1e30f;
#pragma unroll
  for (int j = 0; j < 8; j++)
    m = fmaxf(m, b2f(b2T[((size_t)b * 176 + 8 + wo * 8 + j) * 128 + oc]));
  pool2bf[idx] = f2b(m);
}

// ================= e_f1 GEMM MFMA (grid 32 = 8 n-blocks x 4 m-blocks) =================
__global__ __launch_bounds__(256) void ef1_gemm(const u16* __restrict__ A, const u16* __restrict__ Bw,
                         const float* __restrict__ bias, float* __restrict__ out) {
  int blk = blockIdx.x;
  int n0 = (blk & 7) * 64;
  int tid = threadIdx.x, wid = tid >> 6, l = tid & 63;
  int l15 = l & 15, lq = l >> 4;
  int m0 = (blk >> 3) * 64 + wid * 16;
  f32x4 zero = {0.f, 0.f, 0.f, 0.f};
  f32x4 acc[4];
#pragma unroll
  for (int j = 0; j < 4; j++) acc[j] = zero;
  for (int k0 = 0; k0 < 2560; k0 += 32) {
    short8 af = *(const short8*)(A + ((size_t)(m0 + l15) * 2560 + k0 + lq * 8));
    short8 bf[4];
#pragma unroll
    for (int nf = 0; nf < 4; nf++)
      bf[nf] = *(const short8*)(Bw + ((size_t)(n0 + nf * 16 + l15) * 2560 + k0 + lq * 8));
#pragma unroll
    for (int nf = 0; nf < 4; nf++)
      acc[nf] = __builtin_amdgcn_mfma_f32_16x16x32_bf16(af, bf[nf], acc[nf], 0, 0, 0);
  }
  int bb = m0 + lq * 4;
#pragma unroll
  for (int nf = 0; nf < 4; nf++) {
    int oc = n0 + nf * 16 + l15;
    float bi = bias[oc];
#pragma unroll
    for (int r = 0; r < 4; r++)
      out[(size_t)(bb + r) * 512 + oc] = fmaxf(acc[nf][r] + bi, 0.f);
  }
}

// ================= fused e_f2(sigmoid) + d_f1(relu): one block per batch row =================
__global__ __launch_bounds__(256) void ef2df1_k(const float* __restrict__ ef1, const float* __restrict__ ef2w,
                         const float* __restrict__ ef2b, const float* __restrict__ df1w,
                         const float* __restrict__ df1b, float* __restrict__ fea,
                         u16* __restrict__ df1bf) {
  __shared__ float row[512];
  __shared__ float part[256];
  __shared__ float fea_sh[64];
  int b = blockIdx.x, tid = threadIdx.x;
  row[tid] = ef1[(size_t)b * 512 + tid];
  row[tid + 256] = ef1[(size_t)b * 512 + tid + 256];
  __syncthreads();
  {
    int o = tid & 63, q = tid >> 6;
    const float4* wr = (const float4*)(ef2w + (size_t)o * 512 + q * 128);
    float s = 0.f;
    int base = q * 128;
#pragma unroll
    for (int i = 0; i < 32; i++) {
      float4 wv = wr[i];
      s += row[base + 4 * i] * wv.x + row[base + 4 * i + 1] * wv.y +
           row[base + 4 * i + 2] * wv.z + row[base + 4 * i + 3] * wv.w;
    }
    part[q * 64 + o] = s;
  }
  __syncthreads();
  if (tid < 64) {
    float v = part[tid] + part[64 + tid] + part[128 + tid] + part[192 + tid] + ef2b[tid];
    float sg = 1.f / (1.f + expf(-v));
    fea_sh[tid] = sg;
    fea[(size_t)b * 64 + tid] = sg;
  }
  __syncthreads();
  {
    const float4* wr = (const float4*)(df1w + (size_t)tid * 64);
    float s = 0.f;
#pragma unroll
    for (int i = 0; i < 16; i++) {
      float4 wv = wr[i];
      s += fea_sh[4 * i] * wv.x + fea_sh[4 * i + 1] * wv.y +
           fea_sh[4 * i + 2] * wv.z + fea_sh[4 * i + 3] * wv.w;
    }
    df1bf[(size_t)b * 256 + tid] = f2b(fmaxf(s + df1b[tid], 0.f));
  }
}

// ================= d_f2 GEMM MFMA fused with upT build =================
__global__ __launch_bounds__(256) void df2_gemm(const u16* __restrict__ A, const u16* __restrict__ Bw,
                         const float* __restrict__ bias, u16* __restrict__ upT) {
  int n0 = blockIdx.x * 64;
  int tid = threadIdx.x, wid = tid >> 6, l = tid & 63;
  int l15 = l & 15, lq = l >> 4;
  int m0 = wid * 64;
  f32x4 zero = {0.f, 0.f, 0.f, 0.f};
  f32x4 acc[4][4];
#pragma unroll
  for (int i = 0; i < 4; i++)
#pragma unroll
    for (int j = 0; j < 4; j++) acc[i][j] = zero;
  for (int k0 = 0; k0 < 256; k0 += 32) {
    short8 af[4], bf[4];
#pragma unroll
    for (int mf = 0; mf < 4; mf++)
      af[mf] = *(const short8*)(A + ((size_t)(m0 + mf * 16 + l15) * 256 + k0 + lq * 8));
#pragma unroll
    for (int nf = 0; nf < 4; nf++)
      bf[nf] = *(const short8*)(Bw + ((size_t)(n0 + nf * 16 + l15) * 256 + k0 + lq * 8));
#pragma unroll
    for (int mf = 0; mf < 4; mf++)
#pragma unroll
      for (int nf = 0; nf < 4; nf++)
        acc[mf][nf] = __builtin_amdgcn_mfma_f32_16x16x32_bf16(af[mf], bf[nf], acc[mf][nf], 0, 0, 0);
  }
#pragma unroll
  for (int nf = 0; nf < 4; nf++) {
    int o = n0 + nf * 16 + l15;
    float bi = bias[o];
    int ch = o / 20, t = o - ch * 20;
#pragma unroll
    for (int mf = 0; mf < 4; mf++) {
      int bb = m0 + mf * 16 + lq * 4;
#pragma unroll
      for (int r = 0; r < 4; r++)
        upT[((size_t)(bb + r) * 24 + 1 + t) * 128 + ch] = f2b(fmaxf(acc[mf][nf][r] + bi, 0.f));
    }
  }
}

// ================= decoder conv2 implicit-GEMM MFMA -> dc2T[b][162][64] bf16 ==============
// row = w'+1 ; per lane: 4 oc at fixed w -> uint2 store
__global__ __launch_bounds__(256) void convd2_mfma(const u16* __restrict__ upT, const u16* __restrict__ skipT,
                            const u16* __restrict__ Wd2p, const float* __restrict__ bias,
                            u16* __restrict__ dc2T) {
  int blk = blockIdx.x;
  int b = blk >> 1, wh = blk & 1;
  int tid = threadIdx.x, wid = tid >> 6, l = tid & 63;
  int l15 = l & 15, lq = l >> 4;
  int oc0 = wid * 16;
  int w0 = wh * 80;
  f32x4 zero = {0.f, 0.f, 0.f, 0.f};
  f32x4 acc[5];
#pragma unroll
  for (int j = 0; j < 5; j++) acc[j] = zero;
  const u16* ub = upT + (size_t)b * 24 * 128;
  const u16* sb = skipT + (size_t)b * 176 * 128;
  for (int k = 0; k < 11; k++) {
    for (int ic0 = 0; ic0 < 128; ic0 += 32) {
      short8 a = *(const short8*)(Wd2p + ((k * 64 + oc0 + l15) * 256 + ic0 + lq * 8));
#pragma unroll
      for (int nf = 0; nf < 5; nf++) {
        int w = w0 + nf * 16 + l15;
        int r = (w + k + 3) >> 3;
        short8 bf = *(const short8*)(ub + (r * 128 + ic0 + lq * 8));
        acc[nf] = __builtin_amdgcn_mfma_f32_16x16x32_bf16(a, bf, acc[nf], 0, 0, 0);
      }
    }
    for (int ic0 = 0; ic0 < 128; ic0 += 32) {
      short8 a = *(const short8*)(Wd2p + ((k * 64 + oc0 + l15) * 256 + 128 + ic0 + lq * 8));
#pragma unroll
      for (int nf = 0; nf < 5; nf++) {
        int w = w0 + nf * 16 + l15;
        short8 bf = *(const short8*)(sb + ((size_t)(w + k + 3) * 128 + ic0 + lq * 8));
        acc[nf] = __builtin_amdgcn_mfma_f32_16x16x32_bf16(a, bf, acc[nf], 0, 0, 0);
      }
    }
  }
  int ocb = oc0 + lq * 4;
  float bb0 = bias[ocb], bb1 = bias[ocb + 1], bb2 = bias[ocb + 2], bb3 = bias[ocb + 3];
#pragma unroll
  for (int nf = 0; nf < 5; nf++) {
    int w = w0 + nf * 16 + l15;
    uint2 st;
    st.x = (unsigned)f2b(fmaxf(acc[nf][0] + bb0, 0.f)) | ((unsigned)f2b(fmaxf(acc[nf][1] + bb1, 0.f)) << 16);
    st.y = (unsigned)f2b(fmaxf(acc[nf][2] + bb2, 0.f)) | ((unsigned)f2b(fmaxf(acc[nf][3] + bb3, 0.f)) << 16);
    *(uint2*)(dc2T + ((size_t)b * 162 + w + 1) * 64 + ocb) = st;
  }
}

// ================= decoder conv1 MFMA: D[w][oc] = in_frag x Wd1p -> d_out (bias+relu) ======
// grid = b*4 ; 4 waves x 5 w-frags = 320 w per block ; K = 11 taps x 4 ch-chunks
__global__ __launch_bounds__(256) void convd1_mfma(const u16* __restrict__ dc2T, const u16* __restrict__ back1T,
                            const u16* __restrict__ Wd1p, const float* __restrict__ bias,
                            float* __restrict__ out) {
  int blk = blockIdx.x;
  int b = blk >> 2, q = blk & 3;
  int tid = threadIdx.x, wid = tid >> 6, l = tid & 63;
  int l15 = l & 15, lq = l >> 4;
  int w0 = q * 320 + wid * 80;
  f32x4 zero = {0.f, 0.f, 0.f, 0.f};
  f32x4 acc[5];
#pragma unroll
  for (int j = 0; j < 5; j++) acc[j] = zero;
  const u16* ub = dc2T + (size_t)b * 162 * 64;
  const u16* sb = back1T + (size_t)b * 1296 * 64;
  for (int k = 0; k < 11; k++) {
#pragma unroll
    for (int ch = 0; ch < 2; ch++) {                 // up chunks (concat ch 0..63)
      short8 wf = *(const short8*)(Wd1p + ((k * 4 + ch) * 16 + l15) * 32 + lq * 8);
#pragma unroll
      for (int nf = 0; nf < 5; nf++) {
        int w = w0 + nf * 16 + l15;
        int r = (w + k + 3) >> 3;                    // = floor((w+k-5)/8)+1
        short8 af = *(const short8*)(ub + (r * 64 + ch * 32 + lq * 8));
        acc[nf] = __builtin_amdgcn_mfma_f32_16x16x32_bf16(af, wf, acc[nf], 0, 0, 0);
      }
    }
#pragma unroll
    for (int ch = 0; ch < 2; ch++) {                 // skip chunks (concat ch 64..127)
      short8 wf = *(const short8*)(Wd1p + ((k * 4 + 2 + ch) * 16 + l15) * 32 + lq * 8);
#pragma unroll
      for (int nf = 0; nf < 5; nf++) {
        int w = w0 + nf * 16 + l15;
        short8 af = *(const short8*)(sb + ((size_t)(w + k) * 64 + ch * 32 + lq * 8));
        acc[nf] = __builtin_amdgcn_mfma_f32_16x16x32_bf16(af, wf, acc[nf], 0, 0, 0);
      }
    }
  }
  // D rows = w (lq*4+r), cols = oc (l15); only oc 0,1 valid
  if (l15 < 2) {
    float bi = bias[l15];
    float* ob = out + ((size_t)b * 2 + l15) * 1280;
#pragma unroll
    for (int nf = 0; nf < 5; nf++) {
      int wbase = w0 + nf * 16 + lq * 4;
      float4 v;
      v.x = fmaxf(acc[nf][0] + bi, 0.f);
      v.y = fmaxf(acc[nf][1] + bi, 0.f);
      v.z = fmaxf(acc[nf][2] + bi, 0.f);
      v.w = fmaxf(acc[nf][3] + bi, 0.f);
      *(float4*)(ob + wbase) = v;
    }
  }
}

// ================= KL: sort -> build -> pair-dots -> finalize =================
__global__ void kl_sort_k(const int* __restrict__ lab_s, const int* __restrict__ lab_t,
                          int* __restrict__ srt) {
  int t = threadIdx.x;
  {
    int lab = lab_s[t];
    int pos = 0;
    for (int b = 0; b < BB; b++) {
      int lb = lab_s[b];
      pos += (lb < lab) + ((b < t) && (lb == lab));
    }
    srt[pos] = t;
  }
  {
    int lab = lab_t[t];
    int pos = 0;
    for (int b = 0; b < BB; b++) {
      int lb = lab_t[b];
      pos += (lb < lab) + ((b < t) && (lb == lab));
    }
    srt[256 + pos] = t;
  }
}

__global__ void kl_build_k(const float* __restrict__ fea_s, const float* __restrict__ fea_t,
                           const int* __restrict__ srt,
                           float* __restrict__ T, float* __restrict__ logT) {
  int idx = blockIdx.x * 256 + threadIdx.x;          // 8192 threads, 4 elems each
#pragma unroll
  for (int r = 0; r < 4; r++) {
    int e = idx + r * 8192;
    int d = e & 63;
    int m = (e >> 6) & 63;
    int l = e >> 12;
    float v;
    if (m < GSc) v = fea_s[srt[l * GSc + m] * DDc + d];
    else         v = fea_t[srt[256 + l * GSc + (m - GSc)] * DDc + d];
    T[e]    = v;
    logT[e] = logf(v);
  }
}

__global__ void kl_pairs_k(const float* __restrict__ T, const float* __restrict__ logT,
                           float* __restrict__ C) {
  int blk = blockIdx.x;                              // 64 blocks: (i,j)
  int i = blk >> 3, j = blk & 7;
  int t = threadIdx.x;
  __shared__ float wsum[4];
  const float* li = logT + i * 4096;
  const float* tj = T + j * 4096;
  float s = 0.f;
  for (int e = t; e < 4096; e += 256) s += li[e] * tj[e];
  for (int off = 32; off > 0; off >>= 1) s += __shfl_down(s, off, 64);
  if ((t & 63) == 0) wsum[t >> 6] = s;
  __syncthreads();
  if (t == 0) C[blk] = wsum[0] + wsum[1] + wsum[2] + wsum[3];
}

__global__ void kl_final_k(const float* __restrict__ C, float* __restrict__ out) {
  int t = threadIdx.x;                               // 64 threads
  float c = C[t];
  float tr = ((t >> 3) == (t & 7)) ? c : 0.f;
  for (int off = 32; off > 0; off >>= 1) {
    c  += __shfl_down(c, off, 64);
    tr += __shfl_down(tr, off, 64);
  }
  if (t == 0) out[0] = (LLc * tr - c) / 4096.f / (LLc * LLc / 2.0f);
}

extern "C" void kernel_launch(void* const* d_in, const int* in_sizes, int n_in,
                              void* d_out, int out_size, void* d_ws, size_t ws_size,
                              hipStream_t stream) {
  const float* x_s  = (const float*)d_in[0];
  const float* x_t  = (const float*)d_in[1];
  const int* lab_s  = (const int*)d_in[2];
  const int* lab_t  = (const int*)d_in[3];
  const float* ec1w = (const float*)d_in[5];  const float* ec1b = (const float*)d_in[6];
  const float* ec2w = (const float*)d_in[7];  const float* ec2b = (const float*)d_in[8];
  const float* ef1w = (const float*)d_in[9];  const float* ef1b = (const float*)d_in[10];
  const float* ef2w = (const float*)d_in[11]; const float* ef2b = (const float*)d_in[12];
  const float* df1w = (const float*)d_in[13]; const float* df1b = (const float*)d_in[14];
  const float* df2w = (const float*)d_in[15]; const float* df2b = (const float*)d_in[16];
  const float* dc2w = (const float*)d_in[17]; const float* dc2b = (const float*)d_in[18];
  const float* dc1w = (const float*)d_in[19]; const float* dc1b = (const float*)d_in[20];

  char* p = (char*)d_ws;
  auto alloc = [&](size_t bytes) -> char* {
    char* r = p;
    p += (bytes + 255) & ~(size_t)255;
    return r;
  };
  u16*   b1T_s   = (u16*)alloc((size_t)BB * 1296 * 64 * 2);
  u16*   b1T_t   = (u16*)alloc((size_t)BB * 1296 * 64 * 2);
  u16*   xcol_s  = (u16*)alloc((size_t)BB * 1280 * 32 * 2);
  u16*   xcol_t  = (u16*)alloc((size_t)BB * 1280 * 32 * 2);
  u16*   p1T_s   = (u16*)alloc((size_t)BB * 176 * 64 * 2);
  u16*   p1T_t   = (u16*)alloc((size_t)BB * 176 * 64 * 2);
  u16*   b2T_s   = (u16*)alloc((size_t)BB * 176 * 128 * 2);
  u16*   b2T_t   = (u16*)alloc((size_t)BB * 176 * 128 * 2);
  u16*   upT_s   = (u16*)alloc((size_t)BB * 24 * 128 * 2);
  u16*   upT_t   = (u16*)alloc((size_t)BB * 24 * 128 * 2);
  u16*   p2bf_s  = (u16*)alloc((size_t)BB * 2560 * 2);
  u16*   p2bf_t  = (u16*)alloc((size_t)BB * 2560 * 2);
  float* ef1_s   = (float*)alloc((size_t)BB * 512 * 4);
  float* ef1_t   = (float*)alloc((size_t)BB * 512 * 4);
  float* fea_s   = (float*)alloc((size_t)BB * 64 * 4);
  float* fea_t   = (float*)alloc((size_t)BB * 64 * 4);
  u16*   df1bf_s = (u16*)alloc((size_t)BB * 256 * 2);
  u16*   df1bf_t = (u16*)alloc((size_t)BB * 256 * 2);
  u16*   d2T_s   = (u16*)alloc((size_t)BB * 162 * 64 * 2);
  u16*   d2T_t   = (u16*)alloc((size_t)BB * 162 * 64 * 2);
  u16*   W2p     = (u16*)alloc(90112 * 2);
  u16*   Wd2p    = (u16*)alloc(180224 * 2);
  u16*   Wd1p    = (u16*)alloc(22528 * 2);
  u16*   ef1wbf  = (u16*)alloc((size_t)1310720 * 2);
  u16*   df2wbf  = (u16*)alloc((size_t)655360 * 2);
  u16*   W1p     = (u16*)alloc(2048 * 2);
  float* Tbuf    = (float*)alloc((size_t)32768 * 4);
  float* logTbuf = (float*)alloc((size_t)32768 * 4);
  int*   srt     = (int*)alloc(512 * 4);
  float* Cbuf    = (float*)alloc(64 * 4);

  float* out_s  = (float*)d_out;
  float* out_t  = out_s + (size_t)BB * 2 * 1280;
  float* out_kl = out_s + (size_t)2 * BB * 2 * 1280;

  dim3 blk(256);

  // weight prepack + pad zeros (PRE_D2T/256 = 16256 blocks exactly)
  prep_k<<<dim3(16256), blk, 0, stream>>>(ec2w, dc2w, dc1w, ef1w, df2w, ec1w,
                                          W2p, Wd2p, Wd1p, ef1wbf, df2wbf, W1p,
                                          upT_s, upT_t, b2T_s, b2T_t,
                                          b1T_s, b1T_t, d2T_s, d2T_t);

  // encoders
  im2col1_k<<<dim3(320), blk, 0, stream>>>(x_s, xcol_s);
  im2col1_k<<<dim3(320), blk, 0, stream>>>(x_t, xcol_t);
  conv1_mfma<<<dim3(1024), blk, 0, stream>>>(xcol_s, W1p, ec1b, b1T_s);
  conv1_mfma<<<dim3(1024), blk, 0, stream>>>(xcol_t, W1p, ec1b, b1T_t);
  pool1T_k<<<dim3(11264), blk, 0, stream>>>(b1T_s, p1T_s);
  pool1T_k<<<dim3(11264), blk, 0, stream>>>(b1T_t, p1T_t);
  conv2_mfma<<<dim3(512), blk, 0, stream>>>(p1T_s, W2p, ec2b, b2T_s);
  conv2_mfma<<<dim3(512), blk, 0, stream>>>(p1T_t, W2p, ec2b, b2T_t);
  pool2_k<<<dim3(2560), blk, 0, stream>>>(b2T_s, p2bf_s);
  pool2_k<<<dim3(2560), blk, 0, stream>>>(b2T_t, p2bf_t);
  ef1_gemm<<<dim3(32), blk, 0, stream>>>(p2bf_s, ef1wbf, ef1b, ef1_s);
  ef1_gemm<<<dim3(32), blk, 0, stream>>>(p2bf_t, ef1wbf, ef1b, ef1_t);
  ef2df1_k<<<dim3(256), blk, 0, stream>>>(ef1_s, ef2w, ef2b, df1w, df1b, fea_s, df1bf_s);
  ef2df1_k<<<dim3(256), blk, 0, stream>>>(ef1_t, ef2w, ef2b, df1w, df1b, fea_t, df1bf_t);

  // d_f2 GEMM fused with upT build
  df2_gemm<<<dim3(40), blk, 0, stream>>>(df1bf_s, df2wbf, df2b, upT_s);
  df2_gemm<<<dim3(40), blk, 0, stream>>>(df1bf_t, df2wbf, df2b, upT_t);

  // decoder conv2 (cross skips: out_s uses back2_t) -> dc2T bf16
  convd2_mfma<<<dim3(512), blk, 0, stream>>>(upT_s, b2T_t, Wd2p, dc2b, d2T_s);
  convd2_mfma<<<dim3(512), blk, 0, stream>>>(upT_t, b2T_s, Wd2p, dc2b, d2T_t);

  // decoder conv1 MFMA (cross skips: out_s uses back1_t) — writes d_out directly
  convd1_mfma<<<dim3(1024), blk, 0, stream>>>(d2T_s, b1T_t, Wd1p, dc1b, out_s);
  convd1_mfma<<<dim3(1024), blk, 0, stream>>>(d2T_t, b1T_s, Wd1p, dc1b, out_t);

  // pairwise KL
  kl_sort_k<<<dim3(1), blk, 0, stream>>>(lab_s, lab_t, srt);
  kl_build_k<<<dim3(32), blk, 0, stream>>>(fea_s, fea_t, srt, Tbuf, logTbuf);
  kl_pairs_k<<<dim3(64), blk, 0, stream>>>(Tbuf, logTbuf, Cbuf);
  kl_final_k<<<dim3(1), dim3(64), 0, stream>>>(Cbuf, out_kl);
}

// Round 9
// 619.999 us; speedup vs baseline: 11.6187x; 1.4658x over previous
//
#include <hip/hip_runtime.h>
#include <hip/hip_bf16.h>
#include <math.h>

#define BB   256
#define W1c  1280
#define W2c  160
#define C1c  64
#define C2c  128
#define KKc  11
#define LLc  8
#define DDc  64
#define GSc  32

typedef __attribute__((ext_vector_type(8))) short short8;
typedef __attribute__((ext_vector_type(4))) float f32x4;
typedef unsigned short u16;

__device__ inline float b2f(u16 h) { return __uint_as_float(((unsigned)h) << 16); }
__device__ inline u16 f2b(float f) {
  unsigned u = __float_as_uint(f);
  return (u16)((u + 0x7fffu + ((u >> 16) & 1u)) >> 16);
}

// ================= weight prepack + pad-zero (one kernel, index ranges) =================
#define PRE_W2P   90112
#define PRE_WD2P  270336
#define PRE_WD1P  292864
#define PRE_EF1   1603584
#define PRE_DF2   2258944
#define PRE_UPT   2521088
#define PRE_B2T   3569664
#define PRE_W1P   3571712
#define PRE_B1T   4096000
#define PRE_D2T   4161536
__global__ __launch_bounds__(256) void prep_k(const float* __restrict__ ec2w, const float* __restrict__ dc2w,
                       const float* __restrict__ dc1w, const float* __restrict__ ef1w,
                       const float* __restrict__ df2w, const float* __restrict__ ec1w,
                       u16* __restrict__ W2p, u16* __restrict__ Wd2p, u16* __restrict__ Wd1p,
                       u16* __restrict__ ef1wbf, u16* __restrict__ df2wbf, u16* __restrict__ W1p,
                       u16* __restrict__ upT_s, u16* __restrict__ upT_t,
                       u16* __restrict__ b2T_s, u16* __restrict__ b2T_t,
                       u16* __restrict__ b1T_s, u16* __restrict__ b1T_t,
                       u16* __restrict__ d2T_s, u16* __restrict__ d2T_t) {
  int idx = blockIdx.x * 256 + threadIdx.x;
  if (idx < PRE_W2P) {
    int k = idx / 8192, oc = (idx / 64) % 128, ic = idx % 64;
    W2p[idx] = f2b(ec2w[(oc * 64 + ic) * 11 + k]);
  } else if (idx < PRE_WD2P) {
    int j = idx - PRE_W2P;
    int k = j / 16384, oc = (j / 256) % 64, icc = j % 256;
    Wd2p[j] = f2b(dc2w[(oc * 256 + icc) * 11 + k]);
  } else if (idx < PRE_WD1P) {
    int j = idx - PRE_WD2P;                          // [11][4][16][32]
    int k = j / 2048, rem = j % 2048;
    int chunk = rem / 512, oc = (rem / 32) % 16, c = rem % 32;
    Wd1p[j] = (oc < 2) ? f2b(dc1w[((size_t)oc * 128 + chunk * 32 + c) * 11 + k]) : 0;
  } else if (idx < PRE_EF1) {
    int j = idx - PRE_WD1P;
    ef1wbf[j] = f2b(ef1w[j]);
  } else if (idx < PRE_DF2) {
    int j = idx - PRE_EF1;
    df2wbf[j] = f2b(df2w[j]);
  } else if (idx < PRE_UPT) {
    int j = idx - PRE_DF2;
    int ic = j % 128, r4 = (j / 128) % 4, b = (j / 512) % 256, side = j / 131072;
    int row = (r4 == 0) ? 0 : (20 + r4);             // rows 0,21,22,23
    (side ? upT_t : upT_s)[((size_t)b * 24 + row) * 128 + ic] = 0;
  } else if (idx < PRE_B2T) {
    int j = idx - PRE_UPT;
    int ic = j % 128, pr = (j / 128) % 16, b = (j / 2048) % 256, side = j / 524288;
    int row = (pr < 8) ? pr : pr + 160;
    (side ? b2T_t : b2T_s)[((size_t)b * 176 + row) * 128 + ic] = 0;
  } else if (idx < PRE_W1P) {
    int j = idx - PRE_B2T;
    int oc = j >> 5, kk = j & 31, ic = kk >> 4, k = kk & 15;
    W1p[j] = (k < 11) ? f2b(ec1w[oc * 22 + ic * 11 + k]) : 0;
  } else if (idx < PRE_B1T) {
    int j = idx - PRE_W1P;                           // rows 0-4, 1285-1295
    int ic = j % 64, pr = (j / 64) % 16, b = (j / 1024) % 256, side = j / 262144;
    int row = (pr < 5) ? pr : 1280 + pr;             // pr 5..15 -> 1285..1295
    (side ? b1T_t : b1T_s)[((size_t)b * 1296 + row) * 64 + ic] = 0;
  } else if (idx < PRE_D2T) {
    int j = idx - PRE_B1T;                           // rows 0, 161
    int ic = j % 64, pr = (j / 64) & 1, b = (j / 128) % 256, side = j / 32768;
    int row = pr ? 161 : 0;
    (side ? d2T_t : d2T_s)[((size_t)b * 162 + row) * 64 + ic] = 0;
  }
}

// ================= im2col for conv1: x[b][2][1280]f32 -> xcol[b][w][32]bf16 =================
__global__ __launch_bounds__(256) void im2col1_k(const float* __restrict__ x, u16* __restrict__ xcol) {
  int idx = blockIdx.x * 256 + threadIdx.x;          // 256*2*160
  int wg = idx % 160, ic = (idx / 160) & 1, b = idx / 320;
  int w0 = wg * 8;
  const float* xb = x + (size_t)(b * 2 + ic) * 1280;
  u16 win[18];
#pragma unroll
  for (int j = 0; j < 18; j++) {
    int p = w0 - 5 + j;
    win[j] = (p >= 0 && p < 1280) ? f2b(xb[p]) : 0;
  }
#pragma unroll
  for (int r = 0; r < 8; r++) {
    uint4 s0, s1;
    s0.x = (unsigned)win[r + 0] | ((unsigned)win[r + 1] << 16);
    s0.y = (unsigned)win[r + 2] | ((unsigned)win[r + 3] << 16);
    s0.z = (unsigned)win[r + 4] | ((unsigned)win[r + 5] << 16);
    s0.w = (unsigned)win[r + 6] | ((unsigned)win[r + 7] << 16);
    s1.x = (unsigned)win[r + 8] | ((unsigned)win[r + 9] << 16);
    s1.y = (unsigned)win[r + 10];
    s1.z = 0; s1.w = 0;
    u16* dst = xcol + ((size_t)(b * 1280 + w0 + r) * 32 + ic * 16);
    *(uint4*)dst = s0;
    *(uint4*)(dst + 8) = s1;
  }
}

// ================= conv1 MFMA: W1p[64][32] x xcol -> back1T[b][1296][64] (bias+relu) ========
__global__ __launch_bounds__(256) void conv1_mfma(const u16* __restrict__ xcol, const u16* __restrict__ W1p,
                           const float* __restrict__ bias, u16* __restrict__ back1T) {
  int blk = blockIdx.x;
  int b = blk >> 2, wq = blk & 3;
  int tid = threadIdx.x, wid = tid >> 6, l = tid & 63;
  int l15 = l & 15, lq = l >> 4;
  int oc0 = wid * 16;
  int w0 = wq * 320;
  short8 a = *(const short8*)(W1p + (oc0 + l15) * 32 + lq * 8);
  f32x4 zero = {0.f, 0.f, 0.f, 0.f};
  f32x4 acc[20];
#pragma unroll
  for (int j = 0; j < 20; j++) acc[j] = zero;
  const u16* xb = xcol + (size_t)b * 1280 * 32;
#pragma unroll
  for (int nf = 0; nf < 20; nf++) {
    int w = w0 + nf * 16 + l15;
    short8 bf = *(const short8*)(xb + (size_t)w * 32 + lq * 8);
    acc[nf] = __builtin_amdgcn_mfma_f32_16x16x32_bf16(a, bf, acc[nf], 0, 0, 0);
  }
  int ocb = oc0 + lq * 4;
  float b0 = bias[ocb], b1 = bias[ocb + 1], b2 = bias[ocb + 2], b3 = bias[ocb + 3];
#pragma unroll
  for (int nf = 0; nf < 20; nf++) {
    int w = w0 + nf * 16 + l15;
    uint2 st;
    st.x = (unsigned)f2b(fmaxf(acc[nf][0] + b0, 0.f)) | ((unsigned)f2b(fmaxf(acc[nf][1] + b1, 0.f)) << 16);
    st.y = (unsigned)f2b(fmaxf(acc[nf][2] + b2, 0.f)) | ((unsigned)f2b(fmaxf(acc[nf][3] + b3, 0.f)) << 16);
    *(uint2*)(back1T + ((size_t)b * 1296 + w + 5) * 64 + ocb) = st;
  }
}

// ================= pool8 + transpose: back1T -> p1T[b][176][64] (pad rows zero) =============
__global__ __launch_bounds__(256) void pool1T_k(const u16* __restrict__ back1T, u16* __restrict__ p1T) {
  int idx = blockIdx.x * 256 + threadIdx.x;          // 256*176*64
  int ic = idx % 64, row = (idx / 64) % 176, b = idx / 11264;
  u16 val = 0;
  if (row >= 8 && row < 168) {
    const u16* pp = back1T + ((size_t)b * 1296 + (row - 8) * 8 + 5) * 64 + ic;
    float m = b2f(pp[0]);
#pragma unroll
    for (int j = 1; j < 8; j++) m = fmaxf(m, b2f(pp[j * 64]));
    val = f2b(m);
  }
  p1T[idx] = val;
}

// ================= conv2 implicit-GEMM MFMA (LDS-staged input tile) =========
// block = (b, w-half of 80); stage p1T rows w0+3 .. w0+92 (90 rows x 64ch, pitch 72)
__global__ __launch_bounds__(256) void conv2_mfma(const u16* __restrict__ p1T, const u16* __restrict__ W2p,
                           const float* __restrict__ bias, u16* __restrict__ back2T) {
  __shared__ u16 smem[90 * 72];
  int blk = blockIdx.x;
  int b = blk >> 1, wh = blk & 1;
  int tid = threadIdx.x, wid = tid >> 6, l = tid & 63;
  int l15 = l & 15, lq = l >> 4;
  int oc0 = wid * 32;
  int w0 = wh * 80;
  const u16* pb = p1T + (size_t)b * 176 * 64;
  for (int i = tid; i < 720; i += 256) {             // 90 rows x 8 seg(16B)
    int row = i >> 3, seg = i & 7;
    *(uint4*)(&smem[row * 72 + seg * 8]) = *(const uint4*)(pb + ((size_t)(w0 + 3 + row)) * 64 + seg * 8);
  }
  __syncthreads();
  f32x4 zero = {0.f, 0.f, 0.f, 0.f};
  f32x4 acc[2][5];
#pragma unroll
  for (int i = 0; i < 2; i++)
#pragma unroll
    for (int j = 0; j < 5; j++) acc[i][j] = zero;
  for (int k = 0; k < 11; k++) {
    for (int ic0 = 0; ic0 < 64; ic0 += 32) {
      short8 a0 = *(const short8*)(W2p + ((k * 128 + oc0 + l15) * 64 + ic0 + lq * 8));
      short8 a1 = *(const short8*)(W2p + ((k * 128 + oc0 + 16 + l15) * 64 + ic0 + lq * 8));
      short8 bf[5];
#pragma unroll
      for (int nf = 0; nf < 5; nf++)
        bf[nf] = *(const short8*)(&smem[(nf * 16 + l15 + k) * 72 + ic0 + lq * 8]);
#pragma unroll
      for (int nf = 0; nf < 5; nf++) {
        acc[0][nf] = __builtin_amdgcn_mfma_f32_16x16x32_bf16(a0, bf[nf], acc[0][nf], 0, 0, 0);
        acc[1][nf] = __builtin_amdgcn_mfma_f32_16x16x32_bf16(a1, bf[nf], acc[1][nf], 0, 0, 0);
      }
    }
  }
#pragma unroll
  for (int mf = 0; mf < 2; mf++) {
    int ocb = oc0 + mf * 16 + lq * 4;
    float b0 = bias[ocb], b1 = bias[ocb + 1], b2 = bias[ocb + 2], b3 = bias[ocb + 3];
#pragma unroll
    for (int nf = 0; nf < 5; nf++) {
      int w = w0 + nf * 16 + l15;
      f32x4 v = acc[mf][nf];
      unsigned r0 = (unsigned)f2b(fmaxf(v[0] + b0, 0.f)) | ((unsigned)f2b(fmaxf(v[1] + b1, 0.f)) << 16);
      unsigned r1 = (unsigned)f2b(fmaxf(v[2] + b2, 0.f)) | ((unsigned)f2b(fmaxf(v[3] + b3, 0.f)) << 16);
      uint2 st; st.x = r0; st.y = r1;
      *(uint2*)(back2T + ((size_t)(b * 176 + 8 + w) * 128 + ocb)) = st;
    }
  }
}

// ================= pool2: back2T -> pool2bf[b][2560] bf16 =================
__global__ __launch_bounds__(256) void pool2_k(const u16* __restrict__ b2T, u16* __restrict__ pool2bf) {
  int idx = blockIdx.x * 256 + threadIdx.x;          // 256*128*20
  int wo = idx % 20, oc = (idx / 20) % 128, b = idx / 2560;
  float m = -1e30f;
#pragma unroll
  for (int j = 0; j < 8; j++)
    m = fmaxf(m, b2f(b2T[((size_t)b * 176 + 8 + wo * 8 + j) * 128 + oc]));
  pool2bf[idx] = f2b(m);
}

// ================= e_f1 GEMM MFMA (grid 32 = 8 n-blocks x 4 m-blocks) =================
__global__ __launch_bounds__(256) void ef1_gemm(const u16* __restrict__ A, const u16* __restrict__ Bw,
                         const float* __restrict__ bias, float* __restrict__ out) {
  int blk = blockIdx.x;
  int n0 = (blk & 7) * 64;
  int tid = threadIdx.x, wid = tid >> 6, l = tid & 63;
  int l15 = l & 15, lq = l >> 4;
  int m0 = (blk >> 3) * 64 + wid * 16;
  f32x4 zero = {0.f, 0.f, 0.f, 0.f};
  f32x4 acc[4];
#pragma unroll
  for (int j = 0; j < 4; j++) acc[j] = zero;
  for (int k0 = 0; k0 < 2560; k0 += 32) {
    short8 af = *(const short8*)(A + ((size_t)(m0 + l15) * 2560 + k0 + lq * 8));
    short8 bf[4];
#pragma unroll
    for (int nf = 0; nf < 4; nf++)
      bf[nf] = *(const short8*)(Bw + ((size_t)(n0 + nf * 16 + l15) * 2560 + k0 + lq * 8));
#pragma unroll
    for (int nf = 0; nf < 4; nf++)
      acc[nf] = __builtin_amdgcn_mfma_f32_16x16x32_bf16(af, bf[nf], acc[nf], 0, 0, 0);
  }
  int bb = m0 + lq * 4;
#pragma unroll
  for (int nf = 0; nf < 4; nf++) {
    int oc = n0 + nf * 16 + l15;
    float bi = bias[oc];
#pragma unroll
    for (int r = 0; r < 4; r++)
      out[(size_t)(bb + r) * 512 + oc] = fmaxf(acc[nf][r] + bi, 0.f);
  }
}

// ================= fused e_f2(sigmoid) + d_f1(relu): one block per batch row =================
__global__ __launch_bounds__(256) void ef2df1_k(const float* __restrict__ ef1, const float* __restrict__ ef2w,
                         const float* __restrict__ ef2b, const float* __restrict__ df1w,
                         const float* __restrict__ df1b, float* __restrict__ fea,
                         u16* __restrict__ df1bf) {
  __shared__ float row[512];
  __shared__ float part[256];
  __shared__ float fea_sh[64];
  int b = blockIdx.x, tid = threadIdx.x;
  row[tid] = ef1[(size_t)b * 512 + tid];
  row[tid + 256] = ef1[(size_t)b * 512 + tid + 256];
  __syncthreads();
  {
    int o = tid & 63, q = tid >> 6;
    const float4* wr = (const float4*)(ef2w + (size_t)o * 512 + q * 128);
    float s = 0.f;
    int base = q * 128;
#pragma unroll
    for (int i = 0; i < 32; i++) {
      float4 wv = wr[i];
      s += row[base + 4 * i] * wv.x + row[base + 4 * i + 1] * wv.y +
           row[base + 4 * i + 2] * wv.z + row[base + 4 * i + 3] * wv.w;
    }
    part[q * 64 + o] = s;
  }
  __syncthreads();
  if (tid < 64) {
    float v = part[tid] + part[64 + tid] + part[128 + tid] + part[192 + tid] + ef2b[tid];
    float sg = 1.f / (1.f + expf(-v));
    fea_sh[tid] = sg;
    fea[(size_t)b * 64 + tid] = sg;
  }
  __syncthreads();
  {
    const float4* wr = (const float4*)(df1w + (size_t)tid * 64);
    float s = 0.f;
#pragma unroll
    for (int i = 0; i < 16; i++) {
      float4 wv = wr[i];
      s += fea_sh[4 * i] * wv.x + fea_sh[4 * i + 1] * wv.y +
           fea_sh[4 * i + 2] * wv.z + fea_sh[4 * i + 3] * wv.w;
    }
    df1bf[(size_t)b * 256 + tid] = f2b(fmaxf(s + df1b[tid], 0.f));
  }
}

// ================= d_f2 GEMM MFMA fused with upT build =================
__global__ __launch_bounds__(256) void df2_gemm(const u16* __restrict__ A, const u16* __restrict__ Bw,
                         const float* __restrict__ bias, u16* __restrict__ upT) {
  int n0 = blockIdx.x * 64;
  int tid = threadIdx.x, wid = tid >> 6, l = tid & 63;
  int l15 = l & 15, lq = l >> 4;
  int m0 = wid * 64;
  f32x4 zero = {0.f, 0.f, 0.f, 0.f};
  f32x4 acc[4][4];
#pragma unroll
  for (int i = 0; i < 4; i++)
#pragma unroll
    for (int j = 0; j < 4; j++) acc[i][j] = zero;
  for (int k0 = 0; k0 < 256; k0 += 32) {
    short8 af[4], bf[4];
#pragma unroll
    for (int mf = 0; mf < 4; mf++)
      af[mf] = *(const short8*)(A + ((size_t)(m0 + mf * 16 + l15) * 256 + k0 + lq * 8));
#pragma unroll
    for (int nf = 0; nf < 4; nf++)
      bf[nf] = *(const short8*)(Bw + ((size_t)(n0 + nf * 16 + l15) * 256 + k0 + lq * 8));
#pragma unroll
    for (int mf = 0; mf < 4; mf++)
#pragma unroll
      for (int nf = 0; nf < 4; nf++)
        acc[mf][nf] = __builtin_amdgcn_mfma_f32_16x16x32_bf16(af[mf], bf[nf], acc[mf][nf], 0, 0, 0);
  }
#pragma unroll
  for (int nf = 0; nf < 4; nf++) {
    int o = n0 + nf * 16 + l15;
    float bi = bias[o];
    int ch = o / 20, t = o - ch * 20;
#pragma unroll
    for (int mf = 0; mf < 4; mf++) {
      int bb = m0 + mf * 16 + lq * 4;
#pragma unroll
      for (int r = 0; r < 4; r++)
        upT[((size_t)(bb + r) * 24 + 1 + t) * 128 + ch] = f2b(fmaxf(acc[mf][nf][r] + bi, 0.f));
    }
  }
}

// ================= decoder conv2 implicit-GEMM MFMA (LDS-staged skip tile) -> dc2T ==========
// stage skipT rows w0+3 .. w0+92 (90 rows x 128ch, pitch 136)
__global__ __launch_bounds__(256) void convd2_mfma(const u16* __restrict__ upT, const u16* __restrict__ skipT,
                            const u16* __restrict__ Wd2p, const float* __restrict__ bias,
                            u16* __restrict__ dc2T) {
  __shared__ u16 smem[90 * 136];
  int blk = blockIdx.x;
  int b = blk >> 1, wh = blk & 1;
  int tid = threadIdx.x, wid = tid >> 6, l = tid & 63;
  int l15 = l & 15, lq = l >> 4;
  int oc0 = wid * 16;
  int w0 = wh * 80;
  const u16* sb = skipT + (size_t)b * 176 * 128;
  for (int i = tid; i < 1440; i += 256) {            // 90 rows x 16 seg(16B)
    int row = i >> 4, seg = i & 15;
    *(uint4*)(&smem[row * 136 + seg * 8]) = *(const uint4*)(sb + ((size_t)(w0 + 3 + row)) * 128 + seg * 8);
  }
  __syncthreads();
  f32x4 zero = {0.f, 0.f, 0.f, 0.f};
  f32x4 acc[5];
#pragma unroll
  for (int j = 0; j < 5; j++) acc[j] = zero;
  const u16* ub = upT + (size_t)b * 24 * 128;
  for (int k = 0; k < 11; k++) {
    for (int ic0 = 0; ic0 < 128; ic0 += 32) {
      short8 a = *(const short8*)(Wd2p + ((k * 64 + oc0 + l15) * 256 + ic0 + lq * 8));
#pragma unroll
      for (int nf = 0; nf < 5; nf++) {
        int w = w0 + nf * 16 + l15;
        int r = (w + k + 3) >> 3;
        short8 bf = *(const short8*)(ub + (r * 128 + ic0 + lq * 8));
        acc[nf] = __builtin_amdgcn_mfma_f32_16x16x32_bf16(a, bf, acc[nf], 0, 0, 0);
      }
    }
    for (int ic0 = 0; ic0 < 128; ic0 += 32) {
      short8 a = *(const short8*)(Wd2p + ((k * 64 + oc0 + l15) * 256 + 128 + ic0 + lq * 8));
#pragma unroll
      for (int nf = 0; nf < 5; nf++) {
        short8 bf = *(const short8*)(&smem[(nf * 16 + l15 + k) * 136 + ic0 + lq * 8]);
        acc[nf] = __builtin_amdgcn_mfma_f32_16x16x32_bf16(a, bf, acc[nf], 0, 0, 0);
      }
    }
  }
  int ocb = oc0 + lq * 4;
  float bb0 = bias[ocb], bb1 = bias[ocb + 1], bb2 = bias[ocb + 2], bb3 = bias[ocb + 3];
#pragma unroll
  for (int nf = 0; nf < 5; nf++) {
    int w = w0 + nf * 16 + l15;
    uint2 st;
    st.x = (unsigned)f2b(fmaxf(acc[nf][0] + bb0, 0.f)) | ((unsigned)f2b(fmaxf(acc[nf][1] + bb1, 0.f)) << 16);
    st.y = (unsigned)f2b(fmaxf(acc[nf][2] + bb2, 0.f)) | ((unsigned)f2b(fmaxf(acc[nf][3] + bb3, 0.f)) << 16);
    *(uint2*)(dc2T + ((size_t)b * 162 + w + 1) * 64 + ocb) = st;
  }
}

// ================= decoder conv1 MFMA (LDS-staged back1T tile) -> d_out =================
// block covers 320 w; stage back1T rows q*320 .. +329 (330 rows x 64ch, pitch 72)
__global__ __launch_bounds__(256) void convd1_mfma(const u16* __restrict__ dc2T, const u16* __restrict__ back1T,
                            const u16* __restrict__ Wd1p, const float* __restrict__ bias,
                            float* __restrict__ out) {
  __shared__ u16 smem[330 * 72];
  int blk = blockIdx.x;
  int b = blk >> 2, q = blk & 3;
  int tid = threadIdx.x, wid = tid >> 6, l = tid & 63;
  int l15 = l & 15, lq = l >> 4;
  int base = q * 320;
  int wloc0 = wid * 80;                              // local w within tile
  const u16* sb = back1T + (size_t)b * 1296 * 64;
  for (int i = tid; i < 2640; i += 256) {            // 330 rows x 8 seg(16B)
    int row = i >> 3, seg = i & 7;
    *(uint4*)(&smem[row * 72 + seg * 8]) = *(const uint4*)(sb + ((size_t)(base + row)) * 64 + seg * 8);
  }
  __syncthreads();
  f32x4 zero = {0.f, 0.f, 0.f, 0.f};
  f32x4 acc[5];
#pragma unroll
  for (int j = 0; j < 5; j++) acc[j] = zero;
  const u16* ub = dc2T + (size_t)b * 162 * 64;
  for (int k = 0; k < 11; k++) {
#pragma unroll
    for (int ch = 0; ch < 2; ch++) {                 // up chunks (concat ch 0..63)
      short8 wf = *(const short8*)(Wd1p + ((k * 4 + ch) * 16 + l15) * 32 + lq * 8);
#pragma unroll
      for (int nf = 0; nf < 5; nf++) {
        int w = base + wloc0 + nf * 16 + l15;
        int r = (w + k + 3) >> 3;
        short8 af = *(const short8*)(ub + (r * 64 + ch * 32 + lq * 8));
        acc[nf] = __builtin_amdgcn_mfma_f32_16x16x32_bf16(af, wf, acc[nf], 0, 0, 0);
      }
    }
#pragma unroll
    for (int ch = 0; ch < 2; ch++) {                 // skip chunks (concat ch 64..127)
      short8 wf = *(const short8*)(Wd1p + ((k * 4 + 2 + ch) * 16 + l15) * 32 + lq * 8);
#pragma unroll
      for (int nf = 0; nf < 5; nf++) {
        int lrow = wloc0 + nf * 16 + l15 + k;        // (w+k) - base
        short8 af = *(const short8*)(&smem[lrow * 72 + ch * 32 + lq * 8]);
        acc[nf] = __builtin_amdgcn_mfma_f32_16x16x32_bf16(af, wf, acc[nf], 0, 0, 0);
      }
    }
  }
  if (l15 < 2) {
    float bi = bias[l15];
    float* ob = out + ((size_t)b * 2 + l15) * 1280;
#pragma unroll
    for (int nf = 0; nf < 5; nf++) {
      int wbase = base + wloc0 + nf * 16 + lq * 4;
      float4 v;
      v.x = fmaxf(acc[nf][0] + bi, 0.f);
      v.y = fmaxf(acc[nf][1] + bi, 0.f);
      v.z = fmaxf(acc[nf][2] + bi, 0.f);
      v.w = fmaxf(acc[nf][3] + bi, 0.f);
      *(float4*)(ob + wbase) = v;
    }
  }
}

// ================= KL: sort -> build -> pair-dots -> finalize =================
__global__ void kl_sort_k(const int* __restrict__ lab_s, const int* __restrict__ lab_t,
                          int* __restrict__ srt) {
  int t = threadIdx.x;
  {
    int lab = lab_s[t];
    int pos = 0;
    for (int b = 0; b < BB; b++) {
      int lb = lab_s[b];
      pos += (lb < lab) + ((b < t) && (lb == lab));
    }
    srt[pos] = t;
  }
  {
    int lab = lab_t[t];
    int pos = 0;
    for (int b = 0; b < BB; b++) {
      int lb = lab_t[b];
      pos += (lb < lab) + ((b < t) && (lb == lab));
    }
    srt[256 + pos] = t;
  }
}

__global__ void kl_build_k(const float* __restrict__ fea_s, const float* __restrict__ fea_t,
                           const int* __restrict__ srt,
                           float* __restrict__ T, float* __restrict__ logT) {
  int idx = blockIdx.x * 256 + threadIdx.x;          // 8192 threads, 4 elems each
#pragma unroll
  for (int r = 0; r < 4; r++) {
    int e = idx + r * 8192;
    int d = e & 63;
    int m = (e >> 6) & 63;
    int l = e >> 12;
    float v;
    if (m < GSc) v = fea_s[srt[l * GSc + m] * DDc + d];
    else         v = fea_t[srt[256 + l * GSc + (m - GSc)] * DDc + d];
    T[e]    = v;
    logT[e] = logf(v);
  }
}

__global__ void kl_pairs_k(const float* __restrict__ T, const float* __restrict__ logT,
                           float* __restrict__ C) {
  int blk = blockIdx.x;                              // 64 blocks: (i,j)
  int i = blk >> 3, j = blk & 7;
  int t = threadIdx.x;
  __shared__ float wsum[4];
  const float* li = logT + i * 4096;
  const float* tj = T + j * 4096;
  float s = 0.f;
  for (int e = t; e < 4096; e += 256) s += li[e] * tj[e];
  for (int off = 32; off > 0; off >>= 1) s += __shfl_down(s, off, 64);
  if ((t & 63) == 0) wsum[t >> 6] = s;
  __syncthreads();
  if (t == 0) C[blk] = wsum[0] + wsum[1] + wsum[2] + wsum[3];
}

__global__ void kl_final_k(const float* __restrict__ C, float* __restrict__ out) {
  int t = threadIdx.x;                               // 64 threads
  float c = C[t];
  float tr = ((t >> 3) == (t & 7)) ? c : 0.f;
  for (int off = 32; off > 0; off >>= 1) {
    c  += __shfl_down(c, off, 64);
    tr += __shfl_down(tr, off, 64);
  }
  if (t == 0) out[0] = (LLc * tr - c) / 4096.f / (LLc * LLc / 2.0f);
}

extern "C" void kernel_launch(void* const* d_in, const int* in_sizes, int n_in,
                              void* d_out, int out_size, void* d_ws, size_t ws_size,
                              hipStream_t stream) {
  const float* x_s  = (const float*)d_in[0];
  const float* x_t  = (const float*)d_in[1];
  const int* lab_s  = (const int*)d_in[2];
  const int* lab_t  = (const int*)d_in[3];
  const float* ec1w = (const float*)d_in[5];  const float* ec1b = (const float*)d_in[6];
  const float* ec2w = (const float*)d_in[7];  const float* ec2b = (const float*)d_in[8];
  const float* ef1w = (const float*)d_in[9];  const float* ef1b = (const float*)d_in[10];
  const float* ef2w = (const float*)d_in[11]; const float* ef2b = (const float*)d_in[12];
  const float* df1w = (const float*)d_in[13]; const float* df1b = (const float*)d_in[14];
  const float* df2w = (const float*)d_in[15]; const float* df2b = (const float*)d_in[16];
  const float* dc2w = (const float*)d_in[17]; const float* dc2b = (const float*)d_in[18];
  const float* dc1w = (const float*)d_in[19]; const float* dc1b = (const float*)d_in[20];

  char* p = (char*)d_ws;
  auto alloc = [&](size_t bytes) -> char* {
    char* r = p;
    p += (bytes + 255) & ~(size_t)255;
    return r;
  };
  u16*   b1T_s   = (u16*)alloc((size_t)BB * 1296 * 64 * 2);
  u16*   b1T_t   = (u16*)alloc((size_t)BB * 1296 * 64 * 2);
  u16*   xcol_s  = (u16*)alloc((size_t)BB * 1280 * 32 * 2);
  u16*   xcol_t  = (u16*)alloc((size_t)BB * 1280 * 32 * 2);
  u16*   p1T_s   = (u16*)alloc((size_t)BB * 176 * 64 * 2);
  u16*   p1T_t   = (u16*)alloc((size_t)BB * 176 * 64 * 2);
  u16*   b2T_s   = (u16*)alloc((size_t)BB * 176 * 128 * 2);
  u16*   b2T_t   = (u16*)alloc((size_t)BB * 176 * 128 * 2);
  u16*   upT_s   = (u16*)alloc((size_t)BB * 24 * 128 * 2);
  u16*   upT_t   = (u16*)alloc((size_t)BB * 24 * 128 * 2);
  u16*   p2bf_s  = (u16*)alloc((size_t)BB * 2560 * 2);
  u16*   p2bf_t  = (u16*)alloc((size_t)BB * 2560 * 2);
  float* ef1_s   = (float*)alloc((size_t)BB * 512 * 4);
  float* ef1_t   = (float*)alloc((size_t)BB * 512 * 4);
  float* fea_s   = (float*)alloc((size_t)BB * 64 * 4);
  float* fea_t   = (float*)alloc((size_t)BB * 64 * 4);
  u16*   df1bf_s = (u16*)alloc((size_t)BB * 256 * 2);
  u16*   df1bf_t = (u16*)alloc((size_t)BB * 256 * 2);
  u16*   d2T_s   = (u16*)alloc((size_t)BB * 162 * 64 * 2);
  u16*   d2T_t   = (u16*)alloc((size_t)BB * 162 * 64 * 2);
  u16*   W2p     = (u16*)alloc(90112 * 2);
  u16*   Wd2p    = (u16*)alloc(180224 * 2);
  u16*   Wd1p    = (u16*)alloc(22528 * 2);
  u16*   ef1wbf  = (u16*)alloc((size_t)1310720 * 2);
  u16*   df2wbf  = (u16*)alloc((size_t)655360 * 2);
  u16*   W1p     = (u16*)alloc(2048 * 2);
  float* Tbuf    = (float*)alloc((size_t)32768 * 4);
  float* logTbuf = (float*)alloc((size_t)32768 * 4);
  int*   srt     = (int*)alloc(512 * 4);
  float* Cbuf    = (float*)alloc(64 * 4);

  float* out_s  = (float*)d_out;
  float* out_t  = out_s + (size_t)BB * 2 * 1280;
  float* out_kl = out_s + (size_t)2 * BB * 2 * 1280;

  dim3 blk(256);

  // weight prepack + pad zeros (PRE_D2T/256 = 16256 blocks exactly)
  prep_k<<<dim3(16256), blk, 0, stream>>>(ec2w, dc2w, dc1w, ef1w, df2w, ec1w,
                                          W2p, Wd2p, Wd1p, ef1wbf, df2wbf, W1p,
                                          upT_s, upT_t, b2T_s, b2T_t,
                                          b1T_s, b1T_t, d2T_s, d2T_t);

  // encoders
  im2col1_k<<<dim3(320), blk, 0, stream>>>(x_s, xcol_s);
  im2col1_k<<<dim3(320), blk, 0, stream>>>(x_t, xcol_t);
  conv1_mfma<<<dim3(1024), blk, 0, stream>>>(xcol_s, W1p, ec1b, b1T_s);
  conv1_mfma<<<dim3(1024), blk, 0, stream>>>(xcol_t, W1p, ec1b, b1T_t);
  pool1T_k<<<dim3(11264), blk, 0, stream>>>(b1T_s, p1T_s);
  pool1T_k<<<dim3(11264), blk, 0, stream>>>(b1T_t, p1T_t);
  conv2_mfma<<<dim3(512), blk, 0, stream>>>(p1T_s, W2p, ec2b, b2T_s);
  conv2_mfma<<<dim3(512), blk, 0, stream>>>(p1T_t, W2p, ec2b, b2T_t);
  pool2_k<<<dim3(2560), blk, 0, stream>>>(b2T_s, p2bf_s);
  pool2_k<<<dim3(2560), blk, 0, stream>>>(b2T_t, p2bf_t);
  ef1_gemm<<<dim3(32), blk, 0, stream>>>(p2bf_s, ef1wbf, ef1b, ef1_s);
  ef1_gemm<<<dim3(32), blk, 0, stream>>>(p2bf_t, ef1wbf, ef1b, ef1_t);
  ef2df1_k<<<dim3(256), blk, 0, stream>>>(ef1_s, ef2w, ef2b, df1w, df1b, fea_s, df1bf_s);
  ef2df1_k<<<dim3(256), blk, 0, stream>>>(ef1_t, ef2w, ef2b, df1w, df1b, fea_t, df1bf_t);

  // d_f2 GEMM fused with upT build
  df2_gemm<<<dim3(40), blk, 0, stream>>>(df1bf_s, df2wbf, df2b, upT_s);
  df2_gemm<<<dim3(40), blk, 0, stream>>>(df1bf_t, df2wbf, df2b, upT_t);

  // decoder conv2 (cross skips: out_s uses back2_t) -> dc2T bf16
  convd2_mfma<<<dim3(512), blk, 0, stream>>>(upT_s, b2T_t, Wd2p, dc2b, d2T_s);
  convd2_mfma<<<dim3(512), blk, 0, stream>>>(upT_t, b2T_s, Wd2p, dc2b, d2T_t);

  // decoder conv1 MFMA (cross skips: out_s uses back1_t) — writes d_out directly
  convd1_mfma<<<dim3(1024), blk, 0, stream>>>(d2T_s, b1T_t, Wd1p, dc1b, out_s);
  convd1_mfma<<<dim3(1024), blk, 0, stream>>>(d2T_t, b1T_s, Wd1p, dc1b, out_t);

  // pairwise KL
  kl_sort_k<<<dim3(1), blk, 0, stream>>>(lab_s, lab_t, srt);
  kl_build_k<<<dim3(32), blk, 0, stream>>>(fea_s, fea_t, srt, Tbuf, logTbuf);
  kl_pairs_k<<<dim3(64), blk, 0, stream>>>(Tbuf, logTbuf, Cbuf);
  kl_final_k<<<dim3(1), dim3(64), 0, stream>>>(Cbuf, out_kl);
}

// Round 10
// 525.866 us; speedup vs baseline: 13.6985x; 1.1790x over previous
//
#include <hip/hip_runtime.h>
#include <hip/hip_bf16.h>
#include <math.h>

#define BB   256
#define W1c  1280
#define W2c  160
#define C1c  64
#define C2c  128
#define KKc  11
#define LLc  8
#define DDc  64
#define GSc  32

typedef __attribute__((ext_vector_type(8))) short short8;
typedef __attribute__((ext_vector_type(4))) float f32x4;
typedef unsigned short u16;

__device__ inline float b2f(u16 h) { return __uint_as_float(((unsigned)h) << 16); }
__device__ inline u16 f2b(float f) {
  unsigned u = __float_as_uint(f);
  return (u16)((u + 0x7fffu + ((u >> 16) & 1u)) >> 16);
}

// ================= weight prepack + pad-zero (one kernel, index ranges) =================
#define PRE_W2P   90112
#define PRE_WD2P  270336
#define PRE_WD1P  292864
#define PRE_EF1   1603584
#define PRE_DF2   2258944
#define PRE_UPT   2521088
#define PRE_B2T   3569664
#define PRE_W1P   3571712
#define PRE_B1T   4096000
#define PRE_D2T   4161536
__global__ __launch_bounds__(256) void prep_k(const float* __restrict__ ec2w, const float* __restrict__ dc2w,
                       const float* __restrict__ dc1w, const float* __restrict__ ef1w,
                       const float* __restrict__ df2w, const float* __restrict__ ec1w,
                       u16* __restrict__ W2p, u16* __restrict__ Wd2p, u16* __restrict__ Wd1p,
                       u16* __restrict__ ef1wbf, u16* __restrict__ df2wbf, u16* __restrict__ W1p,
                       u16* __restrict__ upT_s, u16* __restrict__ upT_t,
                       u16* __restrict__ b2T_s, u16* __restrict__ b2T_t,
                       u16* __restrict__ b1T_s, u16* __restrict__ b1T_t,
                       u16* __restrict__ d2T_s, u16* __restrict__ d2T_t) {
  int idx = blockIdx.x * 256 + threadIdx.x;
  if (idx < PRE_W2P) {
    int k = idx / 8192, oc = (idx / 64) % 128, ic = idx % 64;
    W2p[idx] = f2b(ec2w[(oc * 64 + ic) * 11 + k]);
  } else if (idx < PRE_WD2P) {
    int j = idx - PRE_W2P;
    int k = j / 16384, oc = (j / 256) % 64, icc = j % 256;
    Wd2p[j] = f2b(dc2w[(oc * 256 + icc) * 11 + k]);
  } else if (idx < PRE_WD1P) {
    int j = idx - PRE_WD2P;                          // [11][4][16][32]
    int k = j / 2048, rem = j % 2048;
    int chunk = rem / 512, oc = (rem / 32) % 16, c = rem % 32;
    Wd1p[j] = (oc < 2) ? f2b(dc1w[((size_t)oc * 128 + chunk * 32 + c) * 11 + k]) : 0;
  } else if (idx < PRE_EF1) {
    int j = idx - PRE_WD1P;
    ef1wbf[j] = f2b(ef1w[j]);
  } else if (idx < PRE_DF2) {
    int j = idx - PRE_EF1;
    df2wbf[j] = f2b(df2w[j]);
  } else if (idx < PRE_UPT) {
    int j = idx - PRE_DF2;
    int ic = j % 128, r4 = (j / 128) % 4, b = (j / 512) % 256, side = j / 131072;
    int row = (r4 == 0) ? 0 : (20 + r4);             // rows 0,21,22,23
    (side ? upT_t : upT_s)[((size_t)b * 24 + row) * 128 + ic] = 0;
  } else if (idx < PRE_B2T) {
    int j = idx - PRE_UPT;
    int ic = j % 128, pr = (j / 128) % 16, b = (j / 2048) % 256, side = j / 524288;
    int row = (pr < 8) ? pr : pr + 160;
    (side ? b2T_t : b2T_s)[((size_t)b * 176 + row) * 128 + ic] = 0;
  } else if (idx < PRE_W1P) {
    int j = idx - PRE_B2T;
    int oc = j >> 5, kk = j & 31, ic = kk >> 4, k = kk & 15;
    W1p[j] = (k < 11) ? f2b(ec1w[oc * 22 + ic * 11 + k]) : 0;
  } else if (idx < PRE_B1T) {
    int j = idx - PRE_W1P;                           // rows 0-4, 1285-1295
    int ic = j % 64, pr = (j / 64) % 16, b = (j / 1024) % 256, side = j / 262144;
    int row = (pr < 5) ? pr : 1280 + pr;             // pr 5..15 -> 1285..1295
    (side ? b1T_t : b1T_s)[((size_t)b * 1296 + row) * 64 + ic] = 0;
  } else if (idx < PRE_D2T) {
    int j = idx - PRE_B1T;                           // rows 0, 161
    int ic = j % 64, pr = (j / 64) & 1, b = (j / 128) % 256, side = j / 32768;
    int row = pr ? 161 : 0;
    (side ? d2T_t : d2T_s)[((size_t)b * 162 + row) * 64 + ic] = 0;
  }
}

// ================= im2col for conv1: x[b][2][1280]f32 -> xcol[b][w][32]bf16 =================
__global__ __launch_bounds__(256) void im2col1_k(const float* __restrict__ x, u16* __restrict__ xcol) {
  int idx = blockIdx.x * 256 + threadIdx.x;          // 256*2*160
  int wg = idx % 160, ic = (idx / 160) & 1, b = idx / 320;
  int w0 = wg * 8;
  const float* xb = x + (size_t)(b * 2 + ic) * 1280;
  u16 win[18];
#pragma unroll
  for (int j = 0; j < 18; j++) {
    int p = w0 - 5 + j;
    win[j] = (p >= 0 && p < 1280) ? f2b(xb[p]) : 0;
  }
#pragma unroll
  for (int r = 0; r < 8; r++) {
    uint4 s0, s1;
    s0.x = (unsigned)win[r + 0] | ((unsigned)win[r + 1] << 16);
    s0.y = (unsigned)win[r + 2] | ((unsigned)win[r + 3] << 16);
    s0.z = (unsigned)win[r + 4] | ((unsigned)win[r + 5] << 16);
    s0.w = (unsigned)win[r + 6] | ((unsigned)win[r + 7] << 16);
    s1.x = (unsigned)win[r + 8] | ((unsigned)win[r + 9] << 16);
    s1.y = (unsigned)win[r + 10];
    s1.z = 0; s1.w = 0;
    u16* dst = xcol + ((size_t)(b * 1280 + w0 + r) * 32 + ic * 16);
    *(uint4*)dst = s0;
    *(uint4*)(dst + 8) = s1;
  }
}

// ================= conv1 MFMA: W1p[64][32] x xcol -> back1T[b][1296][64] (bias+relu) ========
__global__ __launch_bounds__(256) void conv1_mfma(const u16* __restrict__ xcol, const u16* __restrict__ W1p,
                           const float* __restrict__ bias, u16* __restrict__ back1T) {
  int blk = blockIdx.x;
  int b = blk >> 2, wq = blk & 3;
  int tid = threadIdx.x, wid = tid >> 6, l = tid & 63;
  int l15 = l & 15, lq = l >> 4;
  int oc0 = wid * 16;
  int w0 = wq * 320;
  short8 a = *(const short8*)(W1p + (oc0 + l15) * 32 + lq * 8);
  f32x4 zero = {0.f, 0.f, 0.f, 0.f};
  f32x4 acc[20];
#pragma unroll
  for (int j = 0; j < 20; j++) acc[j] = zero;
  const u16* xb = xcol + (size_t)b * 1280 * 32;
#pragma unroll
  for (int nf = 0; nf < 20; nf++) {
    int w = w0 + nf * 16 + l15;
    short8 bf = *(const short8*)(xb + (size_t)w * 32 + lq * 8);
    acc[nf] = __builtin_amdgcn_mfma_f32_16x16x32_bf16(a, bf, acc[nf], 0, 0, 0);
  }
  int ocb = oc0 + lq * 4;
  float b0 = bias[ocb], b1 = bias[ocb + 1], b2 = bias[ocb + 2], b3 = bias[ocb + 3];
#pragma unroll
  for (int nf = 0; nf < 20; nf++) {
    int w = w0 + nf * 16 + l15;
    uint2 st;
    st.x = (unsigned)f2b(fmaxf(acc[nf][0] + b0, 0.f)) | ((unsigned)f2b(fmaxf(acc[nf][1] + b1, 0.f)) << 16);
    st.y = (unsigned)f2b(fmaxf(acc[nf][2] + b2, 0.f)) | ((unsigned)f2b(fmaxf(acc[nf][3] + b3, 0.f)) << 16);
    *(uint2*)(back1T + ((size_t)b * 1296 + w + 5) * 64 + ocb) = st;
  }
}

// ================= pool8 + transpose: back1T -> p1T[b][176][64] (pad rows zero) =============
__global__ __launch_bounds__(256) void pool1T_k(const u16* __restrict__ back1T, u16* __restrict__ p1T) {
  int idx = blockIdx.x * 256 + threadIdx.x;          // 256*176*64
  int ic = idx % 64, row = (idx / 64) % 176, b = idx / 11264;
  u16 val = 0;
  if (row >= 8 && row < 168) {
    const u16* pp = back1T + ((size_t)b * 1296 + (row - 8) * 8 + 5) * 64 + ic;
    float m = b2f(pp[0]);
#pragma unroll
    for (int j = 1; j < 8; j++) m = fmaxf(m, b2f(pp[j * 64]));
    val = f2b(m);
  }
  p1T[idx] = val;
}

// ================= conv2 implicit-GEMM MFMA (LDS-staged input tile) =========
__global__ __launch_bounds__(256) void conv2_mfma(const u16* __restrict__ p1T, const u16* __restrict__ W2p,
                           const float* __restrict__ bias, u16* __restrict__ back2T) {
  __shared__ u16 smem[90 * 72];
  int blk = blockIdx.x;
  int b = blk >> 1, wh = blk & 1;
  int tid = threadIdx.x, wid = tid >> 6, l = tid & 63;
  int l15 = l & 15, lq = l >> 4;
  int oc0 = wid * 32;
  int w0 = wh * 80;
  const u16* pb = p1T + (size_t)b * 176 * 64;
  for (int i = tid; i < 720; i += 256) {             // 90 rows x 8 seg(16B)
    int row = i >> 3, seg = i & 7;
    *(uint4*)(&smem[row * 72 + seg * 8]) = *(const uint4*)(pb + ((size_t)(w0 + 3 + row)) * 64 + seg * 8);
  }
  __syncthreads();
  f32x4 zero = {0.f, 0.f, 0.f, 0.f};
  f32x4 acc[2][5];
#pragma unroll
  for (int i = 0; i < 2; i++)
#pragma unroll
    for (int j = 0; j < 5; j++) acc[i][j] = zero;
  for (int k = 0; k < 11; k++) {
    for (int ic0 = 0; ic0 < 64; ic0 += 32) {
      short8 a0 = *(const short8*)(W2p + ((k * 128 + oc0 + l15) * 64 + ic0 + lq * 8));
      short8 a1 = *(const short8*)(W2p + ((k * 128 + oc0 + 16 + l15) * 64 + ic0 + lq * 8));
      short8 bf[5];
#pragma unroll
      for (int nf = 0; nf < 5; nf++)
        bf[nf] = *(const short8*)(&smem[(nf * 16 + l15 + k) * 72 + ic0 + lq * 8]);
#pragma unroll
      for (int nf = 0; nf < 5; nf++) {
        acc[0][nf] = __builtin_amdgcn_mfma_f32_16x16x32_bf16(a0, bf[nf], acc[0][nf], 0, 0, 0);
        acc[1][nf] = __builtin_amdgcn_mfma_f32_16x16x32_bf16(a1, bf[nf], acc[1][nf], 0, 0, 0);
      }
    }
  }
#pragma unroll
  for (int mf = 0; mf < 2; mf++) {
    int ocb = oc0 + mf * 16 + lq * 4;
    float b0 = bias[ocb], b1 = bias[ocb + 1], b2 = bias[ocb + 2], b3 = bias[ocb + 3];
#pragma unroll
    for (int nf = 0; nf < 5; nf++) {
      int w = w0 + nf * 16 + l15;
      f32x4 v = acc[mf][nf];
      unsigned r0 = (unsigned)f2b(fmaxf(v[0] + b0, 0.f)) | ((unsigned)f2b(fmaxf(v[1] + b1, 0.f)) << 16);
      unsigned r1 = (unsigned)f2b(fmaxf(v[2] + b2, 0.f)) | ((unsigned)f2b(fmaxf(v[3] + b3, 0.f)) << 16);
      uint2 st; st.x = r0; st.y = r1;
      *(uint2*)(back2T + ((size_t)(b * 176 + 8 + w) * 128 + ocb)) = st;
    }
  }
}

// ================= pool2: back2T -> pool2bf[b][2560] bf16 =================
__global__ __launch_bounds__(256) void pool2_k(const u16* __restrict__ b2T, u16* __restrict__ pool2bf) {
  int idx = blockIdx.x * 256 + threadIdx.x;          // 256*128*20
  int wo = idx % 20, oc = (idx / 20) % 128, b = idx / 2560;
  float m = -1e30f;
#pragma unroll
  for (int j = 0; j < 8; j++)
    m = fmaxf(m, b2f(b2T[((size_t)b * 176 + 8 + wo * 8 + j) * 128 + oc]));
  pool2bf[idx] = f2b(m);
}

// ================= e_f1 GEMM k-split: partials pbuf[side][kc][256][512] f32 ===============
// grid 512 = 2 side x 8 kc x 8 nb x 4 mb ; K-chunk = 320
__global__ __launch_bounds__(256) void ef1_split(const u16* __restrict__ A_s, const u16* __restrict__ A_t,
                          const u16* __restrict__ Bw, float* __restrict__ pbuf) {
  int blk = blockIdx.x;
  int side = blk >> 8;
  int r = blk & 255;
  int kc = r >> 5;
  int q = r & 31;
  int n0 = (q & 7) * 64;
  int tid = threadIdx.x, wid = tid >> 6, l = tid & 63;
  int l15 = l & 15, lq = l >> 4;
  int m0 = (q >> 3) * 64 + wid * 16;
  const u16* A = side ? A_t : A_s;
  f32x4 zero = {0.f, 0.f, 0.f, 0.f};
  f32x4 acc[4];
#pragma unroll
  for (int j = 0; j < 4; j++) acc[j] = zero;
  int kbase = kc * 320;
  for (int k0 = kbase; k0 < kbase + 320; k0 += 32) {
    short8 af = *(const short8*)(A + ((size_t)(m0 + l15) * 2560 + k0 + lq * 8));
    short8 bf[4];
#pragma unroll
    for (int nf = 0; nf < 4; nf++)
      bf[nf] = *(const short8*)(Bw + ((size_t)(n0 + nf * 16 + l15) * 2560 + k0 + lq * 8));
#pragma unroll
    for (int nf = 0; nf < 4; nf++)
      acc[nf] = __builtin_amdgcn_mfma_f32_16x16x32_bf16(af, bf[nf], acc[nf], 0, 0, 0);
  }
  int bb = m0 + lq * 4;
  float* pb = pbuf + (size_t)(side * 8 + kc) * 131072;
#pragma unroll
  for (int nf = 0; nf < 4; nf++) {
    int oc = n0 + nf * 16 + l15;
#pragma unroll
    for (int rr = 0; rr < 4; rr++)
      pb[(size_t)(bb + rr) * 512 + oc] = acc[nf][rr];
  }
}

// ================= e_f1 reduce: sum 8 k-chunks + bias + relu -> ef1_s/ef1_t f32 ============
__global__ __launch_bounds__(256) void ef1_red(const float* __restrict__ pbuf, const float* __restrict__ bias,
                        float* __restrict__ ef1_s, float* __restrict__ ef1_t) {
  int e = blockIdx.x * 256 + threadIdx.x;            // 2*131072
  int side = e >> 17;
  int j = e & 131071;
  const float* pb = pbuf + (size_t)side * 8 * 131072;
  float s = 0.f;
#pragma unroll
  for (int kc = 0; kc < 8; kc++) s += pb[(size_t)kc * 131072 + j];
  s += bias[j & 511];
  (side ? ef1_t : ef1_s)[j] = fmaxf(s, 0.f);
}

// ================= fused e_f2(sigmoid) + d_f1(relu): one block per batch row =================
__global__ __launch_bounds__(256) void ef2df1_k(const float* __restrict__ ef1, const float* __restrict__ ef2w,
                         const float* __restrict__ ef2b, const float* __restrict__ df1w,
                         const float* __restrict__ df1b, float* __restrict__ fea,
                         u16* __restrict__ df1bf) {
  __shared__ float row[512];
  __shared__ float part[256];
  __shared__ float fea_sh[64];
  int b = blockIdx.x, tid = threadIdx.x;
  row[tid] = ef1[(size_t)b * 512 + tid];
  row[tid + 256] = ef1[(size_t)b * 512 + tid + 256];
  __syncthreads();
  {
    int o = tid & 63, q = tid >> 6;
    const float4* wr = (const float4*)(ef2w + (size_t)o * 512 + q * 128);
    float s = 0.f;
    int base = q * 128;
#pragma unroll
    for (int i = 0; i < 32; i++) {
      float4 wv = wr[i];
      s += row[base + 4 * i] * wv.x + row[base + 4 * i + 1] * wv.y +
           row[base + 4 * i + 2] * wv.z + row[base + 4 * i + 3] * wv.w;
    }
    part[q * 64 + o] = s;
  }
  __syncthreads();
  if (tid < 64) {
    float v = part[tid] + part[64 + tid] + part[128 + tid] + part[192 + tid] + ef2b[tid];
    float sg = 1.f / (1.f + expf(-v));
    fea_sh[tid] = sg;
    fea[(size_t)b * 64 + tid] = sg;
  }
  __syncthreads();
  {
    const float4* wr = (const float4*)(df1w + (size_t)tid * 64);
    float s = 0.f;
#pragma unroll
    for (int i = 0; i < 16; i++) {
      float4 wv = wr[i];
      s += fea_sh[4 * i] * wv.x + fea_sh[4 * i + 1] * wv.y +
           fea_sh[4 * i + 2] * wv.z + fea_sh[4 * i + 3] * wv.w;
    }
    df1bf[(size_t)b * 256 + tid] = f2b(fmaxf(s + df1b[tid], 0.f));
  }
}

// ================= d_f2 GEMM MFMA fused with upT build =================
__global__ __launch_bounds__(256) void df2_gemm(const u16* __restrict__ A, const u16* __restrict__ Bw,
                         const float* __restrict__ bias, u16* __restrict__ upT) {
  int n0 = blockIdx.x * 64;
  int tid = threadIdx.x, wid = tid >> 6, l = tid & 63;
  int l15 = l & 15, lq = l >> 4;
  int m0 = wid * 64;
  f32x4 zero = {0.f, 0.f, 0.f, 0.f};
  f32x4 acc[4][4];
#pragma unroll
  for (int i = 0; i < 4; i++)
#pragma unroll
    for (int j = 0; j < 4; j++) acc[i][j] = zero;
  for (int k0 = 0; k0 < 256; k0 += 32) {
    short8 af[4], bf[4];
#pragma unroll
    for (int mf = 0; mf < 4; mf++)
      af[mf] = *(const short8*)(A + ((size_t)(m0 + mf * 16 + l15) * 256 + k0 + lq * 8));
#pragma unroll
    for (int nf = 0; nf < 4; nf++)
      bf[nf] = *(const short8*)(Bw + ((size_t)(n0 + nf * 16 + l15) * 256 + k0 + lq * 8));
#pragma unroll
    for (int mf = 0; mf < 4; mf++)
#pragma unroll
      for (int nf = 0; nf < 4; nf++)
        acc[mf][nf] = __builtin_amdgcn_mfma_f32_16x16x32_bf16(af[mf], bf[nf], acc[mf][nf], 0, 0, 0);
  }
#pragma unroll
  for (int nf = 0; nf < 4; nf++) {
    int o = n0 + nf * 16 + l15;
    float bi = bias[o];
    int ch = o / 20, t = o - ch * 20;
#pragma unroll
    for (int mf = 0; mf < 4; mf++) {
      int bb = m0 + mf * 16 + lq * 4;
#pragma unroll
      for (int r = 0; r < 4; r++)
        upT[((size_t)(bb + r) * 24 + 1 + t) * 128 + ch] = f2b(fmaxf(acc[mf][nf][r] + bi, 0.f));
    }
  }
}

// ================= decoder conv2 implicit-GEMM MFMA (LDS-staged skip tile) -> dc2T ==========
__global__ __launch_bounds__(256) void convd2_mfma(const u16* __restrict__ upT, const u16* __restrict__ skipT,
                            const u16* __restrict__ Wd2p, const float* __restrict__ bias,
                            u16* __restrict__ dc2T) {
  __shared__ u16 smem[90 * 136];
  int blk = blockIdx.x;
  int b = blk >> 1, wh = blk & 1;
  int tid = threadIdx.x, wid = tid >> 6, l = tid & 63;
  int l15 = l & 15, lq = l >> 4;
  int oc0 = wid * 16;
  int w0 = wh * 80;
  const u16* sb = skipT + (size_t)b * 176 * 128;
  for (int i = tid; i < 1440; i += 256) {            // 90 rows x 16 seg(16B)
    int row = i >> 4, seg = i & 15;
    *(uint4*)(&smem[row * 136 + seg * 8]) = *(const uint4*)(sb + ((size_t)(w0 + 3 + row)) * 128 + seg * 8);
  }
  __syncthreads();
  f32x4 zero = {0.f, 0.f, 0.f, 0.f};
  f32x4 acc[5];
#pragma unroll
  for (int j = 0; j < 5; j++) acc[j] = zero;
  const u16* ub = upT + (size_t)b * 24 * 128;
  for (int k = 0; k < 11; k++) {
    for (int ic0 = 0; ic0 < 128; ic0 += 32) {
      short8 a = *(const short8*)(Wd2p + ((k * 64 + oc0 + l15) * 256 + ic0 + lq * 8));
#pragma unroll
      for (int nf = 0; nf < 5; nf++) {
        int w = w0 + nf * 16 + l15;
        int r = (w + k + 3) >> 3;
        short8 bf = *(const short8*)(ub + (r * 128 + ic0 + lq * 8));
        acc[nf] = __builtin_amdgcn_mfma_f32_16x16x32_bf16(a, bf, acc[nf], 0, 0, 0);
      }
    }
    for (int ic0 = 0; ic0 < 128; ic0 += 32) {
      short8 a = *(const short8*)(Wd2p + ((k * 64 + oc0 + l15) * 256 + 128 + ic0 + lq * 8));
#pragma unroll
      for (int nf = 0; nf < 5; nf++) {
        short8 bf = *(const short8*)(&smem[(nf * 16 + l15 + k) * 136 + ic0 + lq * 8]);
        acc[nf] = __builtin_amdgcn_mfma_f32_16x16x32_bf16(a, bf, acc[nf], 0, 0, 0);
      }
    }
  }
  int ocb = oc0 + lq * 4;
  float bb0 = bias[ocb], bb1 = bias[ocb + 1], bb2 = bias[ocb + 2], bb3 = bias[ocb + 3];
#pragma unroll
  for (int nf = 0; nf < 5; nf++) {
    int w = w0 + nf * 16 + l15;
    uint2 st;
    st.x = (unsigned)f2b(fmaxf(acc[nf][0] + bb0, 0.f)) | ((unsigned)f2b(fmaxf(acc[nf][1] + bb1, 0.f)) << 16);
    st.y = (unsigned)f2b(fmaxf(acc[nf][2] + bb2, 0.f)) | ((unsigned)f2b(fmaxf(acc[nf][3] + bb3, 0.f)) << 16);
    *(uint2*)(dc2T + ((size_t)b * 162 + w + 1) * 64 + ocb) = st;
  }
}

// ================= decoder conv1 MFMA (LDS-staged back1T tile) -> d_out =================
__global__ __launch_bounds__(256) void convd1_mfma(const u16* __restrict__ dc2T, const u16* __restrict__ back1T,
                            const u16* __restrict__ Wd1p, const float* __restrict__ bias,
                            float* __restrict__ out) {
  __shared__ u16 smem[330 * 72];
  int blk = blockIdx.x;
  int b = blk >> 2, q = blk & 3;
  int tid = threadIdx.x, wid = tid >> 6, l = tid & 63;
  int l15 = l & 15, lq = l >> 4;
  int base = q * 320;
  int wloc0 = wid * 80;                              // local w within tile
  const u16* sb = back1T + (size_t)b * 1296 * 64;
  for (int i = tid; i < 2640; i += 256) {            // 330 rows x 8 seg(16B)
    int row = i >> 3, seg = i & 7;
    *(uint4*)(&smem[row * 72 + seg * 8]) = *(const uint4*)(sb + ((size_t)(base + row)) * 64 + seg * 8);
  }
  __syncthreads();
  f32x4 zero = {0.f, 0.f, 0.f, 0.f};
  f32x4 acc[5];
#pragma unroll
  for (int j = 0; j < 5; j++) acc[j] = zero;
  const u16* ub = dc2T + (size_t)b * 162 * 64;
  for (int k = 0; k < 11; k++) {
#pragma unroll
    for (int ch = 0; ch < 2; ch++) {                 // up chunks (concat ch 0..63)
      short8 wf = *(const short8*)(Wd1p + ((k * 4 + ch) * 16 + l15) * 32 + lq * 8);
#pragma unroll
      for (int nf = 0; nf < 5; nf++) {
        int w = base + wloc0 + nf * 16 + l15;
        int r = (w + k + 3) >> 3;
        short8 af = *(const short8*)(ub + (r * 64 + ch * 32 + lq * 8));
        acc[nf] = __builtin_amdgcn_mfma_f32_16x16x32_bf16(af, wf, acc[nf], 0, 0, 0);
      }
    }
#pragma unroll
    for (int ch = 0; ch < 2; ch++) {                 // skip chunks (concat ch 64..127)
      short8 wf = *(const short8*)(Wd1p + ((k * 4 + 2 + ch) * 16 + l15) * 32 + lq * 8);
#pragma unroll
      for (int nf = 0; nf < 5; nf++) {
        int lrow = wloc0 + nf * 16 + l15 + k;        // (w+k) - base
        short8 af = *(const short8*)(&smem[lrow * 72 + ch * 32 + lq * 8]);
        acc[nf] = __builtin_amdgcn_mfma_f32_16x16x32_bf16(af, wf, acc[nf], 0, 0, 0);
      }
    }
  }
  if (l15 < 2) {
    float bi = bias[l15];
    float* ob = out + ((size_t)b * 2 + l15) * 1280;
#pragma unroll
    for (int nf = 0; nf < 5; nf++) {
      int wbase = base + wloc0 + nf * 16 + lq * 4;
      float4 v;
      v.x = fmaxf(acc[nf][0] + bi, 0.f);
      v.y = fmaxf(acc[nf][1] + bi, 0.f);
      v.z = fmaxf(acc[nf][2] + bi, 0.f);
      v.w = fmaxf(acc[nf][3] + bi, 0.f);
      *(float4*)(ob + wbase) = v;
    }
  }
}

// ================= KL: sort -> build -> pair-dots -> finalize =================
__global__ void kl_sort_k(const int* __restrict__ lab_s, const int* __restrict__ lab_t,
                          int* __restrict__ srt) {
  int t = threadIdx.x;
  {
    int lab = lab_s[t];
    int pos = 0;
    for (int b = 0; b < BB; b++) {
      int lb = lab_s[b];
      pos += (lb < lab) + ((b < t) && (lb == lab));
    }
    srt[pos] = t;
  }
  {
    int lab = lab_t[t];
    int pos = 0;
    for (int b = 0; b < BB; b++) {
      int lb = lab_t[b];
      pos += (lb < lab) + ((b < t) && (lb == lab));
    }
    srt[256 + pos] = t;
  }
}

__global__ void kl_build_k(const float* __restrict__ fea_s, const float* __restrict__ fea_t,
                           const int* __restrict__ srt,
                           float* __restrict__ T, float* __restrict__ logT) {
  int idx = blockIdx.x * 256 + threadIdx.x;          // 8192 threads, 4 elems each
#pragma unroll
  for (int r = 0; r < 4; r++) {
    int e = idx + r * 8192;
    int d = e & 63;
    int m = (e >> 6) & 63;
    int l = e >> 12;
    float v;
    if (m < GSc) v = fea_s[srt[l * GSc + m] * DDc + d];
    else         v = fea_t[srt[256 + l * GSc + (m - GSc)] * DDc + d];
    T[e]    = v;
    logT[e] = logf(v);
  }
}

__global__ void kl_pairs_k(const float* __restrict__ T, const float* __restrict__ logT,
                           float* __restrict__ C) {
  int blk = blockIdx.x;                              // 64 blocks: (i,j)
  int i = blk >> 3, j = blk & 7;
  int t = threadIdx.x;
  __shared__ float wsum[4];
  const float* li = logT + i * 4096;
  const float* tj = T + j * 4096;
  float s = 0.f;
  for (int e = t; e < 4096; e += 256) s += li[e] * tj[e];
  for (int off = 32; off > 0; off >>= 1) s += __shfl_down(s, off, 64);
  if ((t & 63) == 0) wsum[t >> 6] = s;
  __syncthreads();
  if (t == 0) C[blk] = wsum[0] + wsum[1] + wsum[2] + wsum[3];
}

__global__ void kl_final_k(const float* __restrict__ C, float* __restrict__ out) {
  int t = threadIdx.x;                               // 64 threads
  float c = C[t];
  float tr = ((t >> 3) == (t & 7)) ? c : 0.f;
  for (int off = 32; off > 0; off >>= 1) {
    c  += __shfl_down(c, off, 64);
    tr += __shfl_down(tr, off, 64);
  }
  if (t == 0) out[0] = (LLc * tr - c) / 4096.f / (LLc * LLc / 2.0f);
}

extern "C" void kernel_launch(void* const* d_in, const int* in_sizes, int n_in,
                              void* d_out, int out_size, void* d_ws, size_t ws_size,
                              hipStream_t stream) {
  const float* x_s  = (const float*)d_in[0];
  const float* x_t  = (const float*)d_in[1];
  const int* lab_s  = (const int*)d_in[2];
  const int* lab_t  = (const int*)d_in[3];
  const float* ec1w = (const float*)d_in[5];  const float* ec1b = (const float*)d_in[6];
  const float* ec2w = (const float*)d_in[7];  const float* ec2b = (const float*)d_in[8];
  const float* ef1w = (const float*)d_in[9];  const float* ef1b = (const float*)d_in[10];
  const float* ef2w = (const float*)d_in[11]; const float* ef2b = (const float*)d_in[12];
  const float* df1w = (const float*)d_in[13]; const float* df1b = (const float*)d_in[14];
  const float* df2w = (const float*)d_in[15]; const float* df2b = (const float*)d_in[16];
  const float* dc2w = (const float*)d_in[17]; const float* dc2b = (const float*)d_in[18];
  const float* dc1w = (const float*)d_in[19]; const float* dc1b = (const float*)d_in[20];

  char* p = (char*)d_ws;
  auto alloc = [&](size_t bytes) -> char* {
    char* r = p;
    p += (bytes + 255) & ~(size_t)255;
    return r;
  };
  u16*   b1T_s   = (u16*)alloc((size_t)BB * 1296 * 64 * 2);
  u16*   b1T_t   = (u16*)alloc((size_t)BB * 1296 * 64 * 2);
  u16*   xcol_s  = (u16*)alloc((size_t)BB * 1280 * 32 * 2);
  u16*   xcol_t  = (u16*)alloc((size_t)BB * 1280 * 32 * 2);
  u16*   p1T_s   = (u16*)alloc((size_t)BB * 176 * 64 * 2);
  u16*   p1T_t   = (u16*)alloc((size_t)BB * 176 * 64 * 2);
  u16*   b2T_s   = (u16*)alloc((size_t)BB * 176 * 128 * 2);
  u16*   b2T_t   = (u16*)alloc((size_t)BB * 176 * 128 * 2);
  u16*   upT_s   = (u16*)alloc((size_t)BB * 24 * 128 * 2);
  u16*   upT_t   = (u16*)alloc((size_t)BB * 24 * 128 * 2);
  u16*   p2bf_s  = (u16*)alloc((size_t)BB * 2560 * 2);
  u16*   p2bf_t  = (u16*)alloc((size_t)BB * 2560 * 2);
  float* ef1_s   = (float*)alloc((size_t)BB * 512 * 4);
  float* ef1_t   = (float*)alloc((size_t)BB * 512 * 4);
  float* fea_s   = (float*)alloc((size_t)BB * 64 * 4);
  float* fea_t   = (float*)alloc((size_t)BB * 64 * 4);
  u16*   df1bf_s = (u16*)alloc((size_t)BB * 256 * 2);
  u16*   df1bf_t = (u16*)alloc((size_t)BB * 256 * 2);
  u16*   d2T_s   = (u16*)alloc((size_t)BB * 162 * 64 * 2);
  u16*   d2T_t   = (u16*)alloc((size_t)BB * 162 * 64 * 2);
  u16*   W2p     = (u16*)alloc(90112 * 2);
  u16*   Wd2p    = (u16*)alloc(180224 * 2);
  u16*   Wd1p    = (u16*)alloc(22528 * 2);
  u16*   ef1wbf  = (u16*)alloc((size_t)1310720 * 2);
  u16*   df2wbf  = (u16*)alloc((size_t)655360 * 2);
  u16*   W1p     = (u16*)alloc(2048 * 2);
  float* Tbuf    = (float*)alloc((size_t)32768 * 4);
  float* logTbuf = (float*)alloc((size_t)32768 * 4);
  int*   srt     = (int*)alloc(512 * 4);
  float* Cbuf    = (float*)alloc(64 * 4);
  // pbuf (8 MB, f32[2][8][256][512]) aliases xcol_s: xcol lifetime ends at conv1_mfma,
  // ef1_split runs strictly after. xcol_s is 21 MB > 8 MB. 256-B aligned by alloc.
  float* pbuf    = (float*)xcol_s;

  float* out_s  = (float*)d_out;
  float* out_t  = out_s + (size_t)BB * 2 * 1280;
  float* out_kl = out_s + (size_t)2 * BB * 2 * 1280;

  dim3 blk(256);

  // weight prepack + pad zeros (PRE_D2T/256 = 16256 blocks exactly)
  prep_k<<<dim3(16256), blk, 0, stream>>>(ec2w, dc2w, dc1w, ef1w, df2w, ec1w,
                                          W2p, Wd2p, Wd1p, ef1wbf, df2wbf, W1p,
                                          upT_s, upT_t, b2T_s, b2T_t,
                                          b1T_s, b1T_t, d2T_s, d2T_t);

  // encoders
  im2col1_k<<<dim3(320), blk, 0, stream>>>(x_s, xcol_s);
  im2col1_k<<<dim3(320), blk, 0, stream>>>(x_t, xcol_t);
  conv1_mfma<<<dim3(1024), blk, 0, stream>>>(xcol_s, W1p, ec1b, b1T_s);
  conv1_mfma<<<dim3(1024), blk, 0, stream>>>(xcol_t, W1p, ec1b, b1T_t);
  pool1T_k<<<dim3(11264), blk, 0, stream>>>(b1T_s, p1T_s);
  pool1T_k<<<dim3(11264), blk, 0, stream>>>(b1T_t, p1T_t);
  conv2_mfma<<<dim3(512), blk, 0, stream>>>(p1T_s, W2p, ec2b, b2T_s);
  conv2_mfma<<<dim3(512), blk, 0, stream>>>(p1T_t, W2p, ec2b, b2T_t);
  pool2_k<<<dim3(2560), blk, 0, stream>>>(b2T_s, p2bf_s);
  pool2_k<<<dim3(2560), blk, 0, stream>>>(b2T_t, p2bf_t);

  // e_f1 as k-split GEMM (both sides, one dispatch) + reduce epilogue
  ef1_split<<<dim3(512), blk, 0, stream>>>(p2bf_s, p2bf_t, ef1wbf, pbuf);
  ef1_red<<<dim3(1024), blk, 0, stream>>>(pbuf, ef1b, ef1_s, ef1_t);

  ef2df1_k<<<dim3(256), blk, 0, stream>>>(ef1_s, ef2w, ef2b, df1w, df1b, fea_s, df1bf_s);
  ef2df1_k<<<dim3(256), blk, 0, stream>>>(ef1_t, ef2w, ef2b, df1w, df1b, fea_t, df1bf_t);

  // d_f2 GEMM fused with upT build
  df2_gemm<<<dim3(40), blk, 0, stream>>>(df1bf_s, df2wbf, df2b, upT_s);
  df2_gemm<<<dim3(40), blk, 0, stream>>>(df1bf_t, df2wbf, df2b, upT_t);

  // decoder conv2 (cross skips: out_s uses back2_t) -> dc2T bf16
  convd2_mfma<<<dim3(512), blk, 0, stream>>>(upT_s, b2T_t, Wd2p, dc2b, d2T_s);
  convd2_mfma<<<dim3(512), blk, 0, stream>>>(upT_t, b2T_s, Wd2p, dc2b, d2T_t);

  // decoder conv1 MFMA (cross skips: out_s uses back1_t) — writes d_out directly
  convd1_mfma<<<dim3(1024), blk, 0, stream>>>(d2T_s, b1T_t, Wd1p, dc1b, out_s);
  convd1_mfma<<<dim3(1024), blk, 0, stream>>>(d2T_t, b1T_s, Wd1p, dc1b, out_t);

  // pairwise KL
  kl_sort_k<<<dim3(1), blk, 0, stream>>>(lab_s, lab_t, srt);
  kl_build_k<<<dim3(32), blk, 0, stream>>>(fea_s, fea_t, srt, Tbuf, logTbuf);
  kl_pairs_k<<<dim3(64), blk, 0, stream>>>(Tbuf, logTbuf, Cbuf);
  kl_final_k<<<dim3(1), dim3(64), 0, stream>>>(Cbuf, out_kl);
}

// Round 11
// 489.663 us; speedup vs baseline: 14.7113x; 1.0739x over previous
//
#include <hip/hip_runtime.h>
#include <hip/hip_bf16.h>
#include <math.h>

#define BB   256
#define LLc  8
#define DDc  64
#define GSc  32

typedef __attribute__((ext_vector_type(8))) short short8;
typedef __attribute__((ext_vector_type(4))) float f32x4;
typedef unsigned short u16;

__device__ inline float b2f(u16 h) { return __uint_as_float(((unsigned)h) << 16); }
__device__ inline u16 f2b(float f) {
  unsigned u = __float_as_uint(f);
  return (u16)((u + 0x7fffu + ((u >> 16) & 1u)) >> 16);
}

// ================= weight prepack + pad-zero (one kernel, index ranges) =================
#define PRE_W2P   90112
#define PRE_WD2P  270336
#define PRE_WD1P  292864
#define PRE_EF1   1603584
#define PRE_DF2   2258944
#define PRE_UPT   2521088
#define PRE_B2T   3569664
#define PRE_W1P   3571712
#define PRE_B1T   4096000
#define PRE_D2T   4161536
__global__ __launch_bounds__(256) void prep_k(const float* __restrict__ ec2w, const float* __restrict__ dc2w,
                       const float* __restrict__ dc1w, const float* __restrict__ ef1w,
                       const float* __restrict__ df2w, const float* __restrict__ ec1w,
                       u16* __restrict__ W2p, u16* __restrict__ Wd2p, u16* __restrict__ Wd1p,
                       u16* __restrict__ ef1wbf, u16* __restrict__ df2wbf, u16* __restrict__ W1p,
                       u16* __restrict__ upT_s, u16* __restrict__ upT_t,
                       u16* __restrict__ b2T_s, u16* __restrict__ b2T_t,
                       u16* __restrict__ b1T_s, u16* __restrict__ b1T_t,
                       u16* __restrict__ d2T_s, u16* __restrict__ d2T_t) {
  int idx = blockIdx.x * 256 + threadIdx.x;
  if (idx < PRE_W2P) {
    int k = idx / 8192, oc = (idx / 64) % 128, ic = idx % 64;
    W2p[idx] = f2b(ec2w[(oc * 64 + ic) * 11 + k]);
  } else if (idx < PRE_WD2P) {
    int j = idx - PRE_W2P;
    int k = j / 16384, oc = (j / 256) % 64, icc = j % 256;
    Wd2p[j] = f2b(dc2w[(oc * 256 + icc) * 11 + k]);
  } else if (idx < PRE_WD1P) {
    int j = idx - PRE_WD2P;                          // [11][4][16][32]
    int k = j / 2048, rem = j % 2048;
    int chunk = rem / 512, oc = (rem / 32) % 16, c = rem % 32;
    Wd1p[j] = (oc < 2) ? f2b(dc1w[((size_t)oc * 128 + chunk * 32 + c) * 11 + k]) : 0;
  } else if (idx < PRE_EF1) {
    int j = idx - PRE_WD1P;
    ef1wbf[j] = f2b(ef1w[j]);
  } else if (idx < PRE_DF2) {
    int j = idx - PRE_EF1;
    df2wbf[j] = f2b(df2w[j]);
  } else if (idx < PRE_UPT) {
    int j = idx - PRE_DF2;
    int ic = j % 128, r4 = (j / 128) % 4, b = (j / 512) % 256, side = j / 131072;
    int row = (r4 == 0) ? 0 : (20 + r4);             // rows 0,21,22,23
    (side ? upT_t : upT_s)[((size_t)b * 24 + row) * 128 + ic] = 0;
  } else if (idx < PRE_B2T) {
    int j = idx - PRE_UPT;
    int ic = j % 128, pr = (j / 128) % 16, b = (j / 2048) % 256, side = j / 524288;
    int row = (pr < 8) ? pr : pr + 160;
    (side ? b2T_t : b2T_s)[((size_t)b * 176 + row) * 128 + ic] = 0;
  } else if (idx < PRE_W1P) {
    int j = idx - PRE_B2T;
    int oc = j >> 5, kk = j & 31, ic = kk >> 4, k = kk & 15;
    W1p[j] = (k < 11) ? f2b(ec1w[oc * 22 + ic * 11 + k]) : 0;
  } else if (idx < PRE_B1T) {
    int j = idx - PRE_W1P;                           // rows 0-4, 1285-1295
    int ic = j % 64, pr = (j / 64) % 16, b = (j / 1024) % 256, side = j / 262144;
    int row = (pr < 5) ? pr : 1280 + pr;
    (side ? b1T_t : b1T_s)[((size_t)b * 1296 + row) * 64 + ic] = 0;
  } else if (idx < PRE_D2T) {
    int j = idx - PRE_B1T;                           // rows 0, 161
    int ic = j % 64, pr = (j / 64) & 1, b = (j / 128) % 256, side = j / 32768;
    int row = pr ? 161 : 0;
    (side ? d2T_t : d2T_s)[((size_t)b * 162 + row) * 64 + ic] = 0;
  }
}

// ================= im2col conv1 (both sides): x -> xcol[b][w][32]bf16 =================
__global__ __launch_bounds__(256) void im2col1_k(const float* __restrict__ x_s, const float* __restrict__ x_t,
                          u16* __restrict__ xcol_s, u16* __restrict__ xcol_t) {
  int bk = blockIdx.x;
  int side = bk >= 320;
  int idx = (bk - (side ? 320 : 0)) * 256 + threadIdx.x;  // 256*2*160 per side
  int wg = idx % 160, ic = (idx / 160) & 1, b = idx / 320;
  int w0 = wg * 8;
  const float* xb = (side ? x_t : x_s) + (size_t)(b * 2 + ic) * 1280;
  u16* xcol = side ? xcol_t : xcol_s;
  u16 win[18];
#pragma unroll
  for (int j = 0; j < 18; j++) {
    int p = w0 - 5 + j;
    win[j] = (p >= 0 && p < 1280) ? f2b(xb[p]) : 0;
  }
#pragma unroll
  for (int r = 0; r < 8; r++) {
    uint4 s0, s1;
    s0.x = (unsigned)win[r + 0] | ((unsigned)win[r + 1] << 16);
    s0.y = (unsigned)win[r + 2] | ((unsigned)win[r + 3] << 16);
    s0.z = (unsigned)win[r + 4] | ((unsigned)win[r + 5] << 16);
    s0.w = (unsigned)win[r + 6] | ((unsigned)win[r + 7] << 16);
    s1.x = (unsigned)win[r + 8] | ((unsigned)win[r + 9] << 16);
    s1.y = (unsigned)win[r + 10];
    s1.z = 0; s1.w = 0;
    u16* dst = xcol + ((size_t)(b * 1280 + w0 + r) * 32 + ic * 16);
    *(uint4*)dst = s0;
    *(uint4*)(dst + 8) = s1;
  }
}

// ================= conv1 MFMA (both sides): -> back1T[b][1296][64] =================
__global__ __launch_bounds__(256) void conv1_mfma(const u16* __restrict__ xcol_s, const u16* __restrict__ xcol_t,
                           const u16* __restrict__ W1p, const float* __restrict__ bias,
                           u16* __restrict__ b1T_s, u16* __restrict__ b1T_t) {
  int blk = blockIdx.x;                              // 2048
  int side = blk >> 10;
  int r = blk & 1023;
  int b = r >> 2, wq = r & 3;
  const u16* xcol = side ? xcol_t : xcol_s;
  u16* back1T = side ? b1T_t : b1T_s;
  int tid = threadIdx.x, wid = tid >> 6, l = tid & 63;
  int l15 = l & 15, lq = l >> 4;
  int oc0 = wid * 16;
  int w0 = wq * 320;
  short8 a = *(const short8*)(W1p + (oc0 + l15) * 32 + lq * 8);
  f32x4 zero = {0.f, 0.f, 0.f, 0.f};
  f32x4 acc[20];
#pragma unroll
  for (int j = 0; j < 20; j++) acc[j] = zero;
  const u16* xb = xcol + (size_t)b * 1280 * 32;
#pragma unroll
  for (int nf = 0; nf < 20; nf++) {
    int w = w0 + nf * 16 + l15;
    short8 bf = *(const short8*)(xb + (size_t)w * 32 + lq * 8);
    acc[nf] = __builtin_amdgcn_mfma_f32_16x16x32_bf16(a, bf, acc[nf], 0, 0, 0);
  }
  int ocb = oc0 + lq * 4;
  float b0 = bias[ocb], b1 = bias[ocb + 1], b2 = bias[ocb + 2], b3 = bias[ocb + 3];
#pragma unroll
  for (int nf = 0; nf < 20; nf++) {
    int w = w0 + nf * 16 + l15;
    uint2 st;
    st.x = (unsigned)f2b(fmaxf(acc[nf][0] + b0, 0.f)) | ((unsigned)f2b(fmaxf(acc[nf][1] + b1, 0.f)) << 16);
    st.y = (unsigned)f2b(fmaxf(acc[nf][2] + b2, 0.f)) | ((unsigned)f2b(fmaxf(acc[nf][3] + b3, 0.f)) << 16);
    *(uint2*)(back1T + ((size_t)b * 1296 + w + 5) * 64 + ocb) = st;
  }
}

// ================= pool8 + transpose (both sides): back1T -> p1T[b][176][64] ===============
__global__ __launch_bounds__(256) void pool1T_k(const u16* __restrict__ b1T_s, const u16* __restrict__ b1T_t,
                         u16* __restrict__ p1T_s, u16* __restrict__ p1T_t) {
  int bk = blockIdx.x;                               // 22528
  int side = bk >= 11264;
  int idx = (bk - (side ? 11264 : 0)) * 256 + threadIdx.x;
  int ic = idx % 64, row = (idx / 64) % 176, b = idx / 11264;
  const u16* back1T = side ? b1T_t : b1T_s;
  u16 val = 0;
  if (row >= 8 && row < 168) {
    const u16* pp = back1T + ((size_t)b * 1296 + (row - 8) * 8 + 5) * 64 + ic;
    float m = b2f(pp[0]);
#pragma unroll
    for (int j = 1; j < 8; j++) m = fmaxf(m, b2f(pp[j * 64]));
    val = f2b(m);
  }
  (side ? p1T_t : p1T_s)[idx] = val;
}

// ================= conv2 MFMA (sides merged + oc-split; LDS-staged tile) ===============
// grid 2048 = side x b x wh x ochalf ; block: 4 waves x (16 oc, 80 w)
__global__ __launch_bounds__(256) void conv2_split(const u16* __restrict__ p1T_s, const u16* __restrict__ p1T_t,
                            const u16* __restrict__ W2p, const float* __restrict__ bias,
                            u16* __restrict__ b2T_s, u16* __restrict__ b2T_t) {
  __shared__ u16 smem[90 * 72];
  int blk = blockIdx.x;
  int side = blk >> 10;
  int r = blk & 1023;
  int b = r >> 2, wh = (r >> 1) & 1, oh = r & 1;
  const u16* p1T = side ? p1T_t : p1T_s;
  u16* back2T = side ? b2T_t : b2T_s;
  int tid = threadIdx.x, wid = tid >> 6, l = tid & 63;
  int l15 = l & 15, lq = l >> 4;
  int oc0 = oh * 64 + wid * 16;
  int w0 = wh * 80;
  const u16* pb = p1T + (size_t)b * 176 * 64;
  for (int i = tid; i < 720; i += 256) {             // 90 rows x 8 seg(16B)
    int row = i >> 3, seg = i & 7;
    *(uint4*)(&smem[row * 72 + seg * 8]) = *(const uint4*)(pb + ((size_t)(w0 + 3 + row)) * 64 + seg * 8);
  }
  __syncthreads();
  f32x4 zero = {0.f, 0.f, 0.f, 0.f};
  f32x4 acc[5];
#pragma unroll
  for (int j = 0; j < 5; j++) acc[j] = zero;
  for (int k = 0; k < 11; k++) {
    for (int ic0 = 0; ic0 < 64; ic0 += 32) {
      short8 a = *(const short8*)(W2p + ((k * 128 + oc0 + l15) * 64 + ic0 + lq * 8));
      short8 bf[5];
#pragma unroll
      for (int nf = 0; nf < 5; nf++)
        bf[nf] = *(const short8*)(&smem[(nf * 16 + l15 + k) * 72 + ic0 + lq * 8]);
#pragma unroll
      for (int nf = 0; nf < 5; nf++)
        acc[nf] = __builtin_amdgcn_mfma_f32_16x16x32_bf16(a, bf[nf], acc[nf], 0, 0, 0);
    }
  }
  int ocb = oc0 + lq * 4;
  float b0 = bias[ocb], b1 = bias[ocb + 1], b2 = bias[ocb + 2], b3 = bias[ocb + 3];
#pragma unroll
  for (int nf = 0; nf < 5; nf++) {
    int w = w0 + nf * 16 + l15;
    f32x4 v = acc[nf];
    uint2 st;
    st.x = (unsigned)f2b(fmaxf(v[0] + b0, 0.f)) | ((unsigned)f2b(fmaxf(v[1] + b1, 0.f)) << 16);
    st.y = (unsigned)f2b(fmaxf(v[2] + b2, 0.f)) | ((unsigned)f2b(fmaxf(v[3] + b3, 0.f)) << 16);
    *(uint2*)(back2T + ((size_t)(b * 176 + 8 + w) * 128 + ocb)) = st;
  }
}

// ================= pool2 (both sides): back2T -> pool2bf[b][2560] bf16 =================
__global__ __launch_bounds__(256) void pool2_k(const u16* __restrict__ b2T_s, const u16* __restrict__ b2T_t,
                        u16* __restrict__ p2bf_s, u16* __restrict__ p2bf_t) {
  int bk = blockIdx.x;                               // 5120
  int side = bk >= 2560;
  int idx = (bk - (side ? 2560 : 0)) * 256 + threadIdx.x;
  int wo = idx % 20, oc = (idx / 20) % 128, b = idx / 2560;
  const u16* b2T = side ? b2T_t : b2T_s;
  float m = -1e30f;
#pragma unroll
  for (int j = 0; j < 8; j++)
    m = fmaxf(m, b2f(b2T[((size_t)b * 176 + 8 + wo * 8 + j) * 128 + oc]));
  (side ? p2bf_t : p2bf_s)[idx] = f2b(m);
}

// ================= e_f1 GEMM k-split: partials pbuf[side][kc][256][512] f32 ===============
__global__ __launch_bounds__(256) void ef1_split(const u16* __restrict__ A_s, const u16* __restrict__ A_t,
                          const u16* __restrict__ Bw, float* __restrict__ pbuf) {
  int blk = blockIdx.x;                              // 512
  int side = blk >> 8;
  int r = blk & 255;
  int kc = r >> 5;
  int q = r & 31;
  int n0 = (q & 7) * 64;
  int tid = threadIdx.x, wid = tid >> 6, l = tid & 63;
  int l15 = l & 15, lq = l >> 4;
  int m0 = (q >> 3) * 64 + wid * 16;
  const u16* A = side ? A_t : A_s;
  f32x4 zero = {0.f, 0.f, 0.f, 0.f};
  f32x4 acc[4];
#pragma unroll
  for (int j = 0; j < 4; j++) acc[j] = zero;
  int kbase = kc * 320;
  for (int k0 = kbase; k0 < kbase + 320; k0 += 32) {
    short8 af = *(const short8*)(A + ((size_t)(m0 + l15) * 2560 + k0 + lq * 8));
    short8 bf[4];
#pragma unroll
    for (int nf = 0; nf < 4; nf++)
      bf[nf] = *(const short8*)(Bw + ((size_t)(n0 + nf * 16 + l15) * 2560 + k0 + lq * 8));
#pragma unroll
    for (int nf = 0; nf < 4; nf++)
      acc[nf] = __builtin_amdgcn_mfma_f32_16x16x32_bf16(af, bf[nf], acc[nf], 0, 0, 0);
  }
  int bb = m0 + lq * 4;
  float* pb = pbuf + (size_t)(side * 8 + kc) * 131072;
#pragma unroll
  for (int nf = 0; nf < 4; nf++) {
    int oc = n0 + nf * 16 + l15;
#pragma unroll
    for (int rr = 0; rr < 4; rr++)
      pb[(size_t)(bb + rr) * 512 + oc] = acc[nf][rr];
  }
}

__global__ __launch_bounds__(256) void ef1_red(const float* __restrict__ pbuf, const float* __restrict__ bias,
                        float* __restrict__ ef1_s, float* __restrict__ ef1_t) {
  int e = blockIdx.x * 256 + threadIdx.x;            // 2*131072
  int side = e >> 17;
  int j = e & 131071;
  const float* pb = pbuf + (size_t)side * 8 * 131072;
  float s = 0.f;
#pragma unroll
  for (int kc = 0; kc < 8; kc++) s += pb[(size_t)kc * 131072 + j];
  s += bias[j & 511];
  (side ? ef1_t : ef1_s)[j] = fmaxf(s, 0.f);
}

// ================= fused e_f2(sigmoid) + d_f1(relu), both sides =================
__global__ __launch_bounds__(256) void ef2df1_k(const float* __restrict__ ef1_s, const float* __restrict__ ef1_t,
                         const float* __restrict__ ef2w, const float* __restrict__ ef2b,
                         const float* __restrict__ df1w, const float* __restrict__ df1b,
                         float* __restrict__ fea_s, float* __restrict__ fea_t,
                         u16* __restrict__ df1bf_s, u16* __restrict__ df1bf_t) {
  __shared__ float row[512];
  __shared__ float part[256];
  __shared__ float fea_sh[64];
  int side = blockIdx.x >> 8;
  int b = blockIdx.x & 255;
  const float* ef1 = side ? ef1_t : ef1_s;
  float* fea = side ? fea_t : fea_s;
  u16* df1bf = side ? df1bf_t : df1bf_s;
  int tid = threadIdx.x;
  row[tid] = ef1[(size_t)b * 512 + tid];
  row[tid + 256] = ef1[(size_t)b * 512 + tid + 256];
  __syncthreads();
  {
    int o = tid & 63, q = tid >> 6;
    const float4* wr = (const float4*)(ef2w + (size_t)o * 512 + q * 128);
    float s = 0.f;
    int base = q * 128;
#pragma unroll
    for (int i = 0; i < 32; i++) {
      float4 wv = wr[i];
      s += row[base + 4 * i] * wv.x + row[base + 4 * i + 1] * wv.y +
           row[base + 4 * i + 2] * wv.z + row[base + 4 * i + 3] * wv.w;
    }
    part[q * 64 + o] = s;
  }
  __syncthreads();
  if (tid < 64) {
    float v = part[tid] + part[64 + tid] + part[128 + tid] + part[192 + tid] + ef2b[tid];
    float sg = 1.f / (1.f + expf(-v));
    fea_sh[tid] = sg;
    fea[(size_t)b * 64 + tid] = sg;
  }
  __syncthreads();
  {
    const float4* wr = (const float4*)(df1w + (size_t)tid * 64);
    float s = 0.f;
#pragma unroll
    for (int i = 0; i < 16; i++) {
      float4 wv = wr[i];
      s += fea_sh[4 * i] * wv.x + fea_sh[4 * i + 1] * wv.y +
           fea_sh[4 * i + 2] * wv.z + fea_sh[4 * i + 3] * wv.w;
    }
    df1bf[(size_t)b * 256 + tid] = f2b(fmaxf(s + df1b[tid], 0.f));
  }
}

// ================= d_f2 GEMM fused with upT build, both sides =================
__global__ __launch_bounds__(256) void df2_gemm(const u16* __restrict__ A_s, const u16* __restrict__ A_t,
                         const u16* __restrict__ Bw, const float* __restrict__ bias,
                         u16* __restrict__ upT_s, u16* __restrict__ upT_t) {
  int blk = blockIdx.x;                              // 80
  int side = blk >= 40;
  int n0 = (blk - (side ? 40 : 0)) * 64;
  const u16* A = side ? A_t : A_s;
  u16* upT = side ? upT_t : upT_s;
  int tid = threadIdx.x, wid = tid >> 6, l = tid & 63;
  int l15 = l & 15, lq = l >> 4;
  int m0 = wid * 64;
  f32x4 zero = {0.f, 0.f, 0.f, 0.f};
  f32x4 acc[4][4];
#pragma unroll
  for (int i = 0; i < 4; i++)
#pragma unroll
    for (int j = 0; j < 4; j++) acc[i][j] = zero;
  for (int k0 = 0; k0 < 256; k0 += 32) {
    short8 af[4], bf[4];
#pragma unroll
    for (int mf = 0; mf < 4; mf++)
      af[mf] = *(const short8*)(A + ((size_t)(m0 + mf * 16 + l15) * 256 + k0 + lq * 8));
#pragma unroll
    for (int nf = 0; nf < 4; nf++)
      bf[nf] = *(const short8*)(Bw + ((size_t)(n0 + nf * 16 + l15) * 256 + k0 + lq * 8));
#pragma unroll
    for (int mf = 0; mf < 4; mf++)
#pragma unroll
      for (int nf = 0; nf < 4; nf++)
        acc[mf][nf] = __builtin_amdgcn_mfma_f32_16x16x32_bf16(af[mf], bf[nf], acc[mf][nf], 0, 0, 0);
  }
#pragma unroll
  for (int nf = 0; nf < 4; nf++) {
    int o = n0 + nf * 16 + l15;
    float bi = bias[o];
    int ch = o / 20, t = o - ch * 20;
#pragma unroll
    for (int mf = 0; mf < 4; mf++) {
      int bb = m0 + mf * 16 + lq * 4;
#pragma unroll
      for (int r = 0; r < 4; r++)
        upT[((size_t)(bb + r) * 24 + 1 + t) * 128 + ch] = f2b(fmaxf(acc[mf][nf][r] + bi, 0.f));
    }
  }
}

// ================= decoder conv2: sides merged + tap-split -> f32 partials ===============
// grid 2048 = side x b x wh x khalf ; stage 90-row skip tile
__global__ __launch_bounds__(256) void convd2_split(const u16* __restrict__ upT_s, const u16* __restrict__ upT_t,
                             const u16* __restrict__ b2T_s, const u16* __restrict__ b2T_t,
                             const u16* __restrict__ Wd2p, float* __restrict__ part) {
  __shared__ u16 smem[90 * 136];
  int blk = blockIdx.x;
  int side = blk >> 10;
  int r = blk & 1023;
  int b = r >> 2, wh = (r >> 1) & 1, khalf = r & 1;
  const u16* upT   = side ? upT_t : upT_s;
  const u16* skipT = side ? b2T_s : b2T_t;           // cross skips
  int tid = threadIdx.x, wid = tid >> 6, l = tid & 63;
  int l15 = l & 15, lq = l >> 4;
  int oc0 = wid * 16;
  int w0 = wh * 80;
  const u16* sb = skipT + (size_t)b * 176 * 128;
  for (int i = tid; i < 1440; i += 256) {            // 90 rows x 16 seg(16B)
    int row = i >> 4, seg = i & 15;
    *(uint4*)(&smem[row * 136 + seg * 8]) = *(const uint4*)(sb + ((size_t)(w0 + 3 + row)) * 128 + seg * 8);
  }
  __syncthreads();
  f32x4 zero = {0.f, 0.f, 0.f, 0.f};
  f32x4 acc[5];
#pragma unroll
  for (int j = 0; j < 5; j++) acc[j] = zero;
  const u16* ub = upT + (size_t)b * 24 * 128;
  int kbeg = khalf ? 6 : 0, kend = khalf ? 11 : 6;
  for (int k = kbeg; k < kend; k++) {
    for (int ic0 = 0; ic0 < 128; ic0 += 32) {
      short8 a = *(const short8*)(Wd2p + ((k * 64 + oc0 + l15) * 256 + ic0 + lq * 8));
#pragma unroll
      for (int nf = 0; nf < 5; nf++) {
        int w = w0 + nf * 16 + l15;
        int rr = (w + k + 3) >> 3;
        short8 bf = *(const short8*)(ub + (rr * 128 + ic0 + lq * 8));
        acc[nf] = __builtin_amdgcn_mfma_f32_16x16x32_bf16(a, bf, acc[nf], 0, 0, 0);
      }
    }
    for (int ic0 = 0; ic0 < 128; ic0 += 32) {
      short8 a = *(const short8*)(Wd2p + ((k * 64 + oc0 + l15) * 256 + 128 + ic0 + lq * 8));
#pragma unroll
      for (int nf = 0; nf < 5; nf++) {
        short8 bf = *(const short8*)(&smem[(nf * 16 + l15 + k) * 136 + ic0 + lq * 8]);
        acc[nf] = __builtin_amdgcn_mfma_f32_16x16x32_bf16(a, bf, acc[nf], 0, 0, 0);
      }
    }
  }
  // partial store: part[side][khalf][b][w][oc] f32
  float* pp = part + (((size_t)(side * 2 + khalf) * 256 + b) * 160) * 64;
  int ocb = oc0 + lq * 4;
#pragma unroll
  for (int nf = 0; nf < 5; nf++) {
    int w = w0 + nf * 16 + l15;
    *(f32x4*)(pp + (size_t)w * 64 + ocb) = acc[nf];
  }
}

// ================= convd2 reduce: sum 2 k-halves + bias + relu -> dc2T bf16 ==============
__global__ __launch_bounds__(256) void convd2_red(const float* __restrict__ part, const float* __restrict__ bias,
                           u16* __restrict__ d2T_s, u16* __restrict__ d2T_t) {
  int idx = blockIdx.x * 256 + threadIdx.x;          // 2*256*160*16 = 1,310,720
  int oc4 = (idx & 15) * 4;
  int w = (idx >> 4) % 160;
  int rb = (idx >> 4) / 160;                         // 0..511
  int b = rb & 255;
  int side = rb >> 8;
  const float* p0 = part + (((size_t)(side * 2 + 0) * 256 + b) * 160 + w) * 64 + oc4;
  const float* p1 = part + (((size_t)(side * 2 + 1) * 256 + b) * 160 + w) * 64 + oc4;
  float4 a = *(const float4*)p0;
  float4 c = *(const float4*)p1;
  float b0 = bias[oc4], b1 = bias[oc4 + 1], b2 = bias[oc4 + 2], b3 = bias[oc4 + 3];
  uint2 st;
  st.x = (unsigned)f2b(fmaxf(a.x + c.x + b0, 0.f)) | ((unsigned)f2b(fmaxf(a.y + c.y + b1, 0.f)) << 16);
  st.y = (unsigned)f2b(fmaxf(a.z + c.z + b2, 0.f)) | ((unsigned)f2b(fmaxf(a.w + c.w + b3, 0.f)) << 16);
  u16* dst = side ? d2T_t : d2T_s;
  *(uint2*)(dst + ((size_t)b * 162 + w + 1) * 64 + oc4) = st;
}

// ================= decoder conv1 MFMA (sides merged; LDS-staged back1T tile) -> d_out ======
__global__ __launch_bounds__(256) void convd1_mfma(const u16* __restrict__ d2T_s, const u16* __restrict__ d2T_t,
                            const u16* __restrict__ b1T_s, const u16* __restrict__ b1T_t,
                            const u16* __restrict__ Wd1p, const float* __restrict__ bias,
                            float* __restrict__ out_s, float* __restrict__ out_t) {
  __shared__ u16 smem[330 * 72];
  int blk = blockIdx.x;                              // 2048
  int side = blk >> 10;
  int r = blk & 1023;
  int b = r >> 2, q = r & 3;
  const u16* dc2T   = side ? d2T_t : d2T_s;
  const u16* back1T = side ? b1T_s : b1T_t;          // cross skips
  float* out = side ? out_t : out_s;
  int tid = threadIdx.x, wid = tid >> 6, l = tid & 63;
  int l15 = l & 15, lq = l >> 4;
  int base = q * 320;
  int wloc0 = wid * 80;
  const u16* sb = back1T + (size_t)b * 1296 * 64;
  for (int i = tid; i < 2640; i += 256) {            // 330 rows x 8 seg(16B)
    int row = i >> 3, seg = i & 7;
    *(uint4*)(&smem[row * 72 + seg * 8]) = *(const uint4*)(sb + ((size_t)(base + row)) * 64 + seg * 8);
  }
  __syncthreads();
  f32x4 zero = {0.f, 0.f, 0.f, 0.f};
  f32x4 acc[5];
#pragma unroll
  for (int j = 0; j < 5; j++) acc[j] = zero;
  const u16* ub = dc2T + (size_t)b * 162 * 64;
  for (int k = 0; k < 11; k++) {
#pragma unroll
    for (int ch = 0; ch < 2; ch++) {
      short8 wf = *(const short8*)(Wd1p + ((k * 4 + ch) * 16 + l15) * 32 + lq * 8);
#pragma unroll
      for (int nf = 0; nf < 5; nf++) {
        int w = base + wloc0 + nf * 16 + l15;
        int rr = (w + k + 3) >> 3;
        short8 af = *(const short8*)(ub + (rr * 64 + ch * 32 + lq * 8));
        acc[nf] = __builtin_amdgcn_mfma_f32_16x16x32_bf16(af, wf, acc[nf], 0, 0, 0);
      }
    }
#pragma unroll
    for (int ch = 0; ch < 2; ch++) {
      short8 wf = *(const short8*)(Wd1p + ((k * 4 + 2 + ch) * 16 + l15) * 32 + lq * 8);
#pragma unroll
      for (int nf = 0; nf < 5; nf++) {
        int lrow = wloc0 + nf * 16 + l15 + k;
        short8 af = *(const short8*)(&smem[lrow * 72 + ch * 32 + lq * 8]);
        acc[nf] = __builtin_amdgcn_mfma_f32_16x16x32_bf16(af, wf, acc[nf], 0, 0, 0);
      }
    }
  }
  if (l15 < 2) {
    float bi = bias[l15];
    float* ob = out + ((size_t)b * 2 + l15) * 1280;
#pragma unroll
    for (int nf = 0; nf < 5; nf++) {
      int wbase = base + wloc0 + nf * 16 + lq * 4;
      float4 v;
      v.x = fmaxf(acc[nf][0] + bi, 0.f);
      v.y = fmaxf(acc[nf][1] + bi, 0.f);
      v.z = fmaxf(acc[nf][2] + bi, 0.f);
      v.w = fmaxf(acc[nf][3] + bi, 0.f);
      *(float4*)(ob + wbase) = v;
    }
  }
}

// ================= KL: sort -> build -> pair-dots -> finalize =================
__global__ void kl_sort_k(const int* __restrict__ lab_s, const int* __restrict__ lab_t,
                          int* __restrict__ srt) {
  int t = threadIdx.x;
  {
    int lab = lab_s[t];
    int pos = 0;
    for (int b = 0; b < BB; b++) {
      int lb = lab_s[b];
      pos += (lb < lab) + ((b < t) && (lb == lab));
    }
    srt[pos] = t;
  }
  {
    int lab = lab_t[t];
    int pos = 0;
    for (int b = 0; b < BB; b++) {
      int lb = lab_t[b];
      pos += (lb < lab) + ((b < t) && (lb == lab));
    }
    srt[256 + pos] = t;
  }
}

__global__ void kl_build_k(const float* __restrict__ fea_s, const float* __restrict__ fea_t,
                           const int* __restrict__ srt,
                           float* __restrict__ T, float* __restrict__ logT) {
  int idx = blockIdx.x * 256 + threadIdx.x;
#pragma unroll
  for (int r = 0; r < 4; r++) {
    int e = idx + r * 8192;
    int d = e & 63;
    int m = (e >> 6) & 63;
    int l = e >> 12;
    float v;
    if (m < GSc) v = fea_s[srt[l * GSc + m] * DDc + d];
    else         v = fea_t[srt[256 + l * GSc + (m - GSc)] * DDc + d];
    T[e]    = v;
    logT[e] = logf(v);
  }
}

__global__ void kl_pairs_k(const float* __restrict__ T, const float* __restrict__ logT,
                           float* __restrict__ C) {
  int blk = blockIdx.x;
  int i = blk >> 3, j = blk & 7;
  int t = threadIdx.x;
  __shared__ float wsum[4];
  const float* li = logT + i * 4096;
  const float* tj = T + j * 4096;
  float s = 0.f;
  for (int e = t; e < 4096; e += 256) s += li[e] * tj[e];
  for (int off = 32; off > 0; off >>= 1) s += __shfl_down(s, off, 64);
  if ((t & 63) == 0) wsum[t >> 6] = s;
  __syncthreads();
  if (t == 0) C[blk] = wsum[0] + wsum[1] + wsum[2] + wsum[3];
}

__global__ void kl_final_k(const float* __restrict__ C, float* __restrict__ out) {
  int t = threadIdx.x;
  float c = C[t];
  float tr = ((t >> 3) == (t & 7)) ? c : 0.f;
  for (int off = 32; off > 0; off >>= 1) {
    c  += __shfl_down(c, off, 64);
    tr += __shfl_down(tr, off, 64);
  }
  if (t == 0) out[0] = (LLc * tr - c) / 4096.f / (LLc * LLc / 2.0f);
}

extern "C" void kernel_launch(void* const* d_in, const int* in_sizes, int n_in,
                              void* d_out, int out_size, void* d_ws, size_t ws_size,
                              hipStream_t stream) {
  const float* x_s  = (const float*)d_in[0];
  const float* x_t  = (const float*)d_in[1];
  const int* lab_s  = (const int*)d_in[2];
  const int* lab_t  = (const int*)d_in[3];
  const float* ec1w = (const float*)d_in[5];  const float* ec1b = (const float*)d_in[6];
  const float* ec2w = (const float*)d_in[7];  const float* ec2b = (const float*)d_in[8];
  const float* ef1w = (const float*)d_in[9];  const float* ef1b = (const float*)d_in[10];
  const float* ef2w = (const float*)d_in[11]; const float* ef2b = (const float*)d_in[12];
  const float* df1w = (const float*)d_in[13]; const float* df1b = (const float*)d_in[14];
  const float* df2w = (const float*)d_in[15]; const float* df2b = (const float*)d_in[16];
  const float* dc2w = (const float*)d_in[17]; const float* dc2b = (const float*)d_in[18];
  const float* dc1w = (const float*)d_in[19]; const float* dc1b = (const float*)d_in[20];

  char* p = (char*)d_ws;
  auto alloc = [&](size_t bytes) -> char* {
    char* r = p;
    p += (bytes + 255) & ~(size_t)255;
    return r;
  };
  u16*   b1T_s   = (u16*)alloc((size_t)BB * 1296 * 64 * 2);
  u16*   b1T_t   = (u16*)alloc((size_t)BB * 1296 * 64 * 2);
  u16*   xcol_s  = (u16*)alloc((size_t)BB * 1280 * 32 * 2);
  u16*   xcol_t  = (u16*)alloc((size_t)BB * 1280 * 32 * 2);
  u16*   p1T_s   = (u16*)alloc((size_t)BB * 176 * 64 * 2);
  u16*   p1T_t   = (u16*)alloc((size_t)BB * 176 * 64 * 2);
  u16*   b2T_s   = (u16*)alloc((size_t)BB * 176 * 128 * 2);
  u16*   b2T_t   = (u16*)alloc((size_t)BB * 176 * 128 * 2);
  u16*   upT_s   = (u16*)alloc((size_t)BB * 24 * 128 * 2);
  u16*   upT_t   = (u16*)alloc((size_t)BB * 24 * 128 * 2);
  u16*   p2bf_s  = (u16*)alloc((size_t)BB * 2560 * 2);
  u16*   p2bf_t  = (u16*)alloc((size_t)BB * 2560 * 2);
  float* ef1_s   = (float*)alloc((size_t)BB * 512 * 4);
  float* ef1_t   = (float*)alloc((size_t)BB * 512 * 4);
  float* fea_s   = (float*)alloc((size_t)BB * 64 * 4);
  float* fea_t   = (float*)alloc((size_t)BB * 64 * 4);
  u16*   df1bf_s = (u16*)alloc((size_t)BB * 256 * 2);
  u16*   df1bf_t = (u16*)alloc((size_t)BB * 256 * 2);
  u16*   d2T_s   = (u16*)alloc((size_t)BB * 162 * 64 * 2);
  u16*   d2T_t   = (u16*)alloc((size_t)BB * 162 * 64 * 2);
  u16*   W2p     = (u16*)alloc(90112 * 2);
  u16*   Wd2p    = (u16*)alloc(180224 * 2);
  u16*   Wd1p    = (u16*)alloc(22528 * 2);
  u16*   ef1wbf  = (u16*)alloc((size_t)1310720 * 2);
  u16*   df2wbf  = (u16*)alloc((size_t)655360 * 2);
  u16*   W1p     = (u16*)alloc(2048 * 2);
  float* Tbuf    = (float*)alloc((size_t)32768 * 4);
  float* logTbuf = (float*)alloc((size_t)32768 * 4);
  int*   srt     = (int*)alloc(512 * 4);
  float* Cbuf    = (float*)alloc(64 * 4);
  // pbuf (8 MB) aliases xcol_s; part (21 MB = [2][2][256][160][64] f32) aliases xcol_t.
  // Both xcol lifetimes end at conv1_mfma; ef1_split / convd2_split run strictly after.
  float* pbuf    = (float*)xcol_s;
  float* part    = (float*)xcol_t;

  float* out_s  = (float*)d_out;
  float* out_t  = out_s + (size_t)BB * 2 * 1280;
  float* out_kl = out_s + (size_t)2 * BB * 2 * 1280;

  dim3 blk(256);

  prep_k<<<dim3(16256), blk, 0, stream>>>(ec2w, dc2w, dc1w, ef1w, df2w, ec1w,
                                          W2p, Wd2p, Wd1p, ef1wbf, df2wbf, W1p,
                                          upT_s, upT_t, b2T_s, b2T_t,
                                          b1T_s, b1T_t, d2T_s, d2T_t);

  // encoders (sides merged)
  im2col1_k<<<dim3(640), blk, 0, stream>>>(x_s, x_t, xcol_s, xcol_t);
  conv1_mfma<<<dim3(2048), blk, 0, stream>>>(xcol_s, xcol_t, W1p, ec1b, b1T_s, b1T_t);
  pool1T_k<<<dim3(22528), blk, 0, stream>>>(b1T_s, b1T_t, p1T_s, p1T_t);
  conv2_split<<<dim3(2048), blk, 0, stream>>>(p1T_s, p1T_t, W2p, ec2b, b2T_s, b2T_t);
  pool2_k<<<dim3(5120), blk, 0, stream>>>(b2T_s, b2T_t, p2bf_s, p2bf_t);
  ef1_split<<<dim3(512), blk, 0, stream>>>(p2bf_s, p2bf_t, ef1wbf, pbuf);
  ef1_red<<<dim3(1024), blk, 0, stream>>>(pbuf, ef1b, ef1_s, ef1_t);
  ef2df1_k<<<dim3(512), blk, 0, stream>>>(ef1_s, ef1_t, ef2w, ef2b, df1w, df1b,
                                          fea_s, fea_t, df1bf_s, df1bf_t);

  // decoders
  df2_gemm<<<dim3(80), blk, 0, stream>>>(df1bf_s, df1bf_t, df2wbf, df2b, upT_s, upT_t);
  convd2_split<<<dim3(2048), blk, 0, stream>>>(upT_s, upT_t, b2T_s, b2T_t, Wd2p, part);
  convd2_red<<<dim3(5120), blk, 0, stream>>>(part, dc2b, d2T_s, d2T_t);
  convd1_mfma<<<dim3(2048), blk, 0, stream>>>(d2T_s, d2T_t, b1T_s, b1T_t, Wd1p, dc1b, out_s, out_t);

  // pairwise KL
  kl_sort_k<<<dim3(1), blk, 0, stream>>>(lab_s, lab_t, srt);
  kl_build_k<<<dim3(32), blk, 0, stream>>>(fea_s, fea_t, srt, Tbuf, logTbuf);
  kl_pairs_k<<<dim3(64), blk, 0, stream>>>(Tbuf, logTbuf, Cbuf);
  kl_final_k<<<dim3(1), dim3(64), 0, stream>>>(Cbuf, out_kl);
}

// Round 13
// 469.976 us; speedup vs baseline: 15.3275x; 1.0419x over previous
//
#include <hip/hip_runtime.h>
#include <hip/hip_bf16.h>
#include <math.h>

#define BB   256
#define LLc  8
#define DDc  64
#define GSc  32

typedef __attribute__((ext_vector_type(8))) short short8;
typedef __attribute__((ext_vector_type(4))) float f32x4;
typedef unsigned short u16;

__device__ inline float b2f(u16 h) { return __uint_as_float(((unsigned)h) << 16); }
__device__ inline u16 f2b(float f) {
  unsigned u = __float_as_uint(f);
  return (u16)((u + 0x7fffu + ((u >> 16) & 1u)) >> 16);
}

// ================= weight prepack + pad-zero (one kernel, index ranges) =================
#define PRE_W2P   90112
#define PRE_WD2P  270336
#define PRE_WD1P  292864
#define PRE_EF1   1603584
#define PRE_DF2   2258944
#define PRE_UPT   2521088
#define PRE_B2T   3569664
#define PRE_W1P   3571712
#define PRE_B1T   4096000
#define PRE_D2T   4161536
__global__ __launch_bounds__(256) void prep_k(const float* __restrict__ ec2w, const float* __restrict__ dc2w,
                       const float* __restrict__ dc1w, const float* __restrict__ ef1w,
                       const float* __restrict__ df2w, const float* __restrict__ ec1w,
                       u16* __restrict__ W2p, u16* __restrict__ Wd2p, u16* __restrict__ Wd1p,
                       u16* __restrict__ ef1wbf, u16* __restrict__ df2wbf, u16* __restrict__ W1p,
                       u16* __restrict__ upT_s, u16* __restrict__ upT_t,
                       u16* __restrict__ b2T_s, u16* __restrict__ b2T_t,
                       u16* __restrict__ b1T_s, u16* __restrict__ b1T_t,
                       u16* __restrict__ d2T_s, u16* __restrict__ d2T_t) {
  int idx = blockIdx.x * 256 + threadIdx.x;
  if (idx < PRE_W2P) {
    int k = idx / 8192, oc = (idx / 64) % 128, ic = idx % 64;
    W2p[idx] = f2b(ec2w[(oc * 64 + ic) * 11 + k]);
  } else if (idx < PRE_WD2P) {
    int j = idx - PRE_W2P;
    int k = j / 16384, oc = (j / 256) % 64, icc = j % 256;
    Wd2p[j] = f2b(dc2w[(oc * 256 + icc) * 11 + k]);
  } else if (idx < PRE_WD1P) {
    int j = idx - PRE_WD2P;                          // [11][4][16][32]
    int k = j / 2048, rem = j % 2048;
    int chunk = rem / 512, oc = (rem / 32) % 16, c = rem % 32;
    Wd1p[j] = (oc < 2) ? f2b(dc1w[((size_t)oc * 128 + chunk * 32 + c) * 11 + k]) : 0;
  } else if (idx < PRE_EF1) {
    int j = idx - PRE_WD1P;
    ef1wbf[j] = f2b(ef1w[j]);
  } else if (idx < PRE_DF2) {
    int j = idx - PRE_EF1;
    df2wbf[j] = f2b(df2w[j]);
  } else if (idx < PRE_UPT) {
    int j = idx - PRE_DF2;
    int ic = j % 128, r4 = (j / 128) % 4, b = (j / 512) % 256, side = j / 131072;
    int row = (r4 == 0) ? 0 : (20 + r4);             // rows 0,21,22,23
    (side ? upT_t : upT_s)[((size_t)b * 24 + row) * 128 + ic] = 0;
  } else if (idx < PRE_B2T) {
    int j = idx - PRE_UPT;
    int ic = j % 128, pr = (j / 128) % 16, b = (j / 2048) % 256, side = j / 524288;
    int row = (pr < 8) ? pr : pr + 160;
    (side ? b2T_t : b2T_s)[((size_t)b * 176 + row) * 128 + ic] = 0;
  } else if (idx < PRE_W1P) {
    int j = idx - PRE_B2T;
    int oc = j >> 5, kk = j & 31, ic = kk >> 4, k = kk & 15;
    W1p[j] = (k < 11) ? f2b(ec1w[oc * 22 + ic * 11 + k]) : 0;
  } else if (idx < PRE_B1T) {
    int j = idx - PRE_W1P;                           // rows 0-4, 1285-1295
    int ic = j % 64, pr = (j / 64) % 16, b = (j / 1024) % 256, side = j / 262144;
    int row = (pr < 5) ? pr : 1280 + pr;
    (side ? b1T_t : b1T_s)[((size_t)b * 1296 + row) * 64 + ic] = 0;
  } else if (idx < PRE_D2T) {
    int j = idx - PRE_B1T;                           // rows 0, 161
    int ic = j % 64, pr = (j / 64) & 1, b = (j / 128) % 256, side = j / 32768;
    int row = pr ? 161 : 0;
    (side ? d2T_t : d2T_s)[((size_t)b * 162 + row) * 64 + ic] = 0;
  }
}

// ================= im2col conv1 (both sides): x -> xcol[b][w][32]bf16 =================
__global__ __launch_bounds__(256) void im2col1_k(const float* __restrict__ x_s, const float* __restrict__ x_t,
                          u16* __restrict__ xcol_s, u16* __restrict__ xcol_t) {
  int bk = blockIdx.x;
  int side = bk >= 320;
  int idx = (bk - (side ? 320 : 0)) * 256 + threadIdx.x;
  int wg = idx % 160, ic = (idx / 160) & 1, b = idx / 320;
  int w0 = wg * 8;
  const float* xb = (side ? x_t : x_s) + (size_t)(b * 2 + ic) * 1280;
  u16* xcol = side ? xcol_t : xcol_s;
  u16 win[18];
#pragma unroll
  for (int j = 0; j < 18; j++) {
    int p = w0 - 5 + j;
    win[j] = (p >= 0 && p < 1280) ? f2b(xb[p]) : 0;
  }
#pragma unroll
  for (int r = 0; r < 8; r++) {
    uint4 s0, s1;
    s0.x = (unsigned)win[r + 0] | ((unsigned)win[r + 1] << 16);
    s0.y = (unsigned)win[r + 2] | ((unsigned)win[r + 3] << 16);
    s0.z = (unsigned)win[r + 4] | ((unsigned)win[r + 5] << 16);
    s0.w = (unsigned)win[r + 6] | ((unsigned)win[r + 7] << 16);
    s1.x = (unsigned)win[r + 8] | ((unsigned)win[r + 9] << 16);
    s1.y = (unsigned)win[r + 10];
    s1.z = 0; s1.w = 0;
    u16* dst = xcol + ((size_t)(b * 1280 + w0 + r) * 32 + ic * 16);
    *(uint4*)dst = s0;
    *(uint4*)(dst + 8) = s1;
  }
}

// ================= conv1 MFMA (both sides): -> back1T[b][1296][64] =================
__global__ __launch_bounds__(256) void conv1_mfma(const u16* __restrict__ xcol_s, const u16* __restrict__ xcol_t,
                           const u16* __restrict__ W1p, const float* __restrict__ bias,
                           u16* __restrict__ b1T_s, u16* __restrict__ b1T_t) {
  int blk = blockIdx.x;                              // 2048
  int side = blk >> 10;
  int r = blk & 1023;
  int b = r >> 2, wq = r & 3;
  const u16* xcol = side ? xcol_t : xcol_s;
  u16* back1T = side ? b1T_t : b1T_s;
  int tid = threadIdx.x, wid = tid >> 6, l = tid & 63;
  int l15 = l & 15, lq = l >> 4;
  int oc0 = wid * 16;
  int w0 = wq * 320;
  short8 a = *(const short8*)(W1p + (oc0 + l15) * 32 + lq * 8);
  f32x4 zero = {0.f, 0.f, 0.f, 0.f};
  f32x4 acc[20];
#pragma unroll
  for (int j = 0; j < 20; j++) acc[j] = zero;
  const u16* xb = xcol + (size_t)b * 1280 * 32;
#pragma unroll
  for (int nf = 0; nf < 20; nf++) {
    int w = w0 + nf * 16 + l15;
    short8 bf = *(const short8*)(xb + (size_t)w * 32 + lq * 8);
    acc[nf] = __builtin_amdgcn_mfma_f32_16x16x32_bf16(a, bf, acc[nf], 0, 0, 0);
  }
  int ocb = oc0 + lq * 4;
  float b0 = bias[ocb], b1 = bias[ocb + 1], b2 = bias[ocb + 2], b3 = bias[ocb + 3];
#pragma unroll
  for (int nf = 0; nf < 20; nf++) {
    int w = w0 + nf * 16 + l15;
    uint2 st;
    st.x = (unsigned)f2b(fmaxf(acc[nf][0] + b0, 0.f)) | ((unsigned)f2b(fmaxf(acc[nf][1] + b1, 0.f)) << 16);
    st.y = (unsigned)f2b(fmaxf(acc[nf][2] + b2, 0.f)) | ((unsigned)f2b(fmaxf(acc[nf][3] + b3, 0.f)) << 16);
    *(uint2*)(back1T + ((size_t)b * 1296 + w + 5) * 64 + ocb) = st;
  }
}

// ================= pool8 + transpose (both sides): back1T -> p1T[b][176][64] ===============
__global__ __launch_bounds__(256) void pool1T_k(const u16* __restrict__ b1T_s, const u16* __restrict__ b1T_t,
                         u16* __restrict__ p1T_s, u16* __restrict__ p1T_t) {
  int bk = blockIdx.x;                               // 22528
  int side = bk >= 11264;
  int idx = (bk - (side ? 11264 : 0)) * 256 + threadIdx.x;
  int ic = idx % 64, row = (idx / 64) % 176, b = idx / 11264;
  const u16* back1T = side ? b1T_t : b1T_s;
  u16 val = 0;
  if (row >= 8 && row < 168) {
    const u16* pp = back1T + ((size_t)b * 1296 + (row - 8) * 8 + 5) * 64 + ic;
    float m = b2f(pp[0]);
#pragma unroll
    for (int j = 1; j < 8; j++) m = fmaxf(m, b2f(pp[j * 64]));
    val = f2b(m);
  }
  (side ? p1T_t : p1T_s)[idx] = val;
}

// ================= conv2 MFMA (sides merged + oc-split; swizzled LDS tile) ===============
// grid 2048 ; pitch 72 u16, 8 slots/row, slot' = (slot + 2*row) & 7
__global__ __launch_bounds__(256) void conv2_split(const u16* __restrict__ p1T_s, const u16* __restrict__ p1T_t,
                            const u16* __restrict__ W2p, const float* __restrict__ bias,
                            u16* __restrict__ b2T_s, u16* __restrict__ b2T_t) {
  __shared__ u16 smem[90 * 72];
  int blk = blockIdx.x;
  int side = blk >> 10;
  int r = blk & 1023;
  int b = r >> 2, wh = (r >> 1) & 1, oh = r & 1;
  const u16* p1T = side ? p1T_t : p1T_s;
  u16* back2T = side ? b2T_t : b2T_s;
  int tid = threadIdx.x, wid = tid >> 6, l = tid & 63;
  int l15 = l & 15, lq = l >> 4;
  int oc0 = oh * 64 + wid * 16;
  int w0 = wh * 80;
  const u16* pb = p1T + (size_t)b * 176 * 64;
  for (int i = tid; i < 720; i += 256) {             // 90 rows x 8 slots(16B)
    int row = i >> 3, seg = i & 7;
    int sl = (seg + 2 * row) & 7;
    *(uint4*)(&smem[row * 72 + sl * 8]) = *(const uint4*)(pb + ((size_t)(w0 + 3 + row)) * 64 + seg * 8);
  }
  __syncthreads();
  f32x4 zero = {0.f, 0.f, 0.f, 0.f};
  f32x4 acc[5];
#pragma unroll
  for (int j = 0; j < 5; j++) acc[j] = zero;
  for (int k = 0; k < 11; k++) {
    for (int ic0 = 0; ic0 < 64; ic0 += 32) {
      short8 a = *(const short8*)(W2p + ((k * 128 + oc0 + l15) * 64 + ic0 + lq * 8));
      short8 bf[5];
#pragma unroll
      for (int nf = 0; nf < 5; nf++) {
        int lrow = nf * 16 + l15 + k;
        int sl = ((ic0 >> 3) + lq + 2 * lrow) & 7;
        bf[nf] = *(const short8*)(&smem[lrow * 72 + (sl << 3)]);
      }
#pragma unroll
      for (int nf = 0; nf < 5; nf++)
        acc[nf] = __builtin_amdgcn_mfma_f32_16x16x32_bf16(a, bf[nf], acc[nf], 0, 0, 0);
    }
  }
  int ocb = oc0 + lq * 4;
  float b0 = bias[ocb], b1 = bias[ocb + 1], b2 = bias[ocb + 2], b3 = bias[ocb + 3];
#pragma unroll
  for (int nf = 0; nf < 5; nf++) {
    int w = w0 + nf * 16 + l15;
    f32x4 v = acc[nf];
    uint2 st;
    st.x = (unsigned)f2b(fmaxf(v[0] + b0, 0.f)) | ((unsigned)f2b(fmaxf(v[1] + b1, 0.f)) << 16);
    st.y = (unsigned)f2b(fmaxf(v[2] + b2, 0.f)) | ((unsigned)f2b(fmaxf(v[3] + b3, 0.f)) << 16);
    *(uint2*)(back2T + ((size_t)(b * 176 + 8 + w) * 128 + ocb)) = st;
  }
}

// ================= pool2 (both sides): back2T -> pool2bf[b][2560] bf16 =================
__global__ __launch_bounds__(256) void pool2_k(const u16* __restrict__ b2T_s, const u16* __restrict__ b2T_t,
                        u16* __restrict__ p2bf_s, u16* __restrict__ p2bf_t) {
  int bk = blockIdx.x;                               // 5120
  int side = bk >= 2560;
  int idx = (bk - (side ? 2560 : 0)) * 256 + threadIdx.x;
  int wo = idx % 20, oc = (idx / 20) % 128, b = idx / 2560;
  const u16* b2T = side ? b2T_t : b2T_s;
  float m = -1e30f;
#pragma unroll
  for (int j = 0; j < 8; j++)
    m = fmaxf(m, b2f(b2T[((size_t)b * 176 + 8 + wo * 8 + j) * 128 + oc]));
  (side ? p2bf_t : p2bf_s)[idx] = f2b(m);
}

// ================= e_f1 GEMM k-split: partials pbuf[side][kc][256][512] f32 ===============
__global__ __launch_bounds__(256) void ef1_split(const u16* __restrict__ A_s, const u16* __restrict__ A_t,
                          const u16* __restrict__ Bw, float* __restrict__ pbuf) {
  int blk = blockIdx.x;                              // 512
  int side = blk >> 8;
  int r = blk & 255;
  int kc = r >> 5;
  int q = r & 31;
  int n0 = (q & 7) * 64;
  int tid = threadIdx.x, wid = tid >> 6, l = tid & 63;
  int l15 = l & 15, lq = l >> 4;
  int m0 = (q >> 3) * 64 + wid * 16;
  const u16* A = side ? A_t : A_s;
  f32x4 zero = {0.f, 0.f, 0.f, 0.f};
  f32x4 acc[4];
#pragma unroll
  for (int j = 0; j < 4; j++) acc[j] = zero;
  int kbase = kc * 320;
  for (int k0 = kbase; k0 < kbase + 320; k0 += 32) {
    short8 af = *(const short8*)(A + ((size_t)(m0 + l15) * 2560 + k0 + lq * 8));
    short8 bf[4];
#pragma unroll
    for (int nf = 0; nf < 4; nf++)
      bf[nf] = *(const short8*)(Bw + ((size_t)(n0 + nf * 16 + l15) * 2560 + k0 + lq * 8));
#pragma unroll
    for (int nf = 0; nf < 4; nf++)
      acc[nf] = __builtin_amdgcn_mfma_f32_16x16x32_bf16(af, bf[nf], acc[nf], 0, 0, 0);
  }
  int bb = m0 + lq * 4;
  float* pb = pbuf + (size_t)(side * 8 + kc) * 131072;
#pragma unroll
  for (int nf = 0; nf < 4; nf++) {
    int oc = n0 + nf * 16 + l15;
#pragma unroll
    for (int rr = 0; rr < 4; rr++)
      pb[(size_t)(bb + rr) * 512 + oc] = acc[nf][rr];
  }
}

__global__ __launch_bounds__(256) void ef1_red(const float* __restrict__ pbuf, const float* __restrict__ bias,
                        float* __restrict__ ef1_s, float* __restrict__ ef1_t) {
  int e = blockIdx.x * 256 + threadIdx.x;            // 2*131072
  int side = e >> 17;
  int j = e & 131071;
  const float* pb = pbuf + (size_t)side * 8 * 131072;
  float s = 0.f;
#pragma unroll
  for (int kc = 0; kc < 8; kc++) s += pb[(size_t)kc * 131072 + j];
  s += bias[j & 511];
  (side ? ef1_t : ef1_s)[j] = fmaxf(s, 0.f);
}

// ================= fused e_f2(sigmoid) + d_f1(relu), both sides =================
__global__ __launch_bounds__(256) void ef2df1_k(const float* __restrict__ ef1_s, const float* __restrict__ ef1_t,
                         const float* __restrict__ ef2w, const float* __restrict__ ef2b,
                         const float* __restrict__ df1w, const float* __restrict__ df1b,
                         float* __restrict__ fea_s, float* __restrict__ fea_t,
                         u16* __restrict__ df1bf_s, u16* __restrict__ df1bf_t) {
  __shared__ float row[512];
  __shared__ float part[256];
  __shared__ float fea_sh[64];
  int side = blockIdx.x >> 8;
  int b = blockIdx.x & 255;
  const float* ef1 = side ? ef1_t : ef1_s;
  float* fea = side ? fea_t : fea_s;
  u16* df1bf = side ? df1bf_t : df1bf_s;
  int tid = threadIdx.x;
  row[tid] = ef1[(size_t)b * 512 + tid];
  row[tid + 256] = ef1[(size_t)b * 512 + tid + 256];
  __syncthreads();
  {
    int o = tid & 63, q = tid >> 6;
    const float4* wr = (const float4*)(ef2w + (size_t)o * 512 + q * 128);
    float s = 0.f;
    int base = q * 128;
#pragma unroll
    for (int i = 0; i < 32; i++) {
      float4 wv = wr[i];
      s += row[base + 4 * i] * wv.x + row[base + 4 * i + 1] * wv.y +
           row[base + 4 * i + 2] * wv.z + row[base + 4 * i + 3] * wv.w;
    }
    part[q * 64 + o] = s;
  }
  __syncthreads();
  if (tid < 64) {
    float v = part[tid] + part[64 + tid] + part[128 + tid] + part[192 + tid] + ef2b[tid];
    float sg = 1.f / (1.f + expf(-v));
    fea_sh[tid] = sg;
    fea[(size_t)b * 64 + tid] = sg;
  }
  __syncthreads();
  {
    const float4* wr = (const float4*)(df1w + (size_t)tid * 64);
    float s = 0.f;
#pragma unroll
    for (int i = 0; i < 16; i++) {
      float4 wv = wr[i];
      s += fea_sh[4 * i] * wv.x + fea_sh[4 * i + 1] * wv.y +
           fea_sh[4 * i + 2] * wv.z + fea_sh[4 * i + 3] * wv.w;
    }
    df1bf[(size_t)b * 256 + tid] = f2b(fmaxf(s + df1b[tid], 0.f));
  }
}

// ================= d_f2 GEMM fused with upT build, both sides =================
__global__ __launch_bounds__(256) void df2_gemm(const u16* __restrict__ A_s, const u16* __restrict__ A_t,
                         const u16* __restrict__ Bw, const float* __restrict__ bias,
                         u16* __restrict__ upT_s, u16* __restrict__ upT_t) {
  int blk = blockIdx.x;                              // 80
  int side = blk >= 40;
  int n0 = (blk - (side ? 40 : 0)) * 64;
  const u16* A = side ? A_t : A_s;
  u16* upT = side ? upT_t : upT_s;
  int tid = threadIdx.x, wid = tid >> 6, l = tid & 63;
  int l15 = l & 15, lq = l >> 4;
  int m0 = wid * 64;
  f32x4 zero = {0.f, 0.f, 0.f, 0.f};
  f32x4 acc[4][4];
#pragma unroll
  for (int i = 0; i < 4; i++)
#pragma unroll
    for (int j = 0; j < 4; j++) acc[i][j] = zero;
  for (int k0 = 0; k0 < 256; k0 += 32) {
    short8 af[4], bf[4];
#pragma unroll
    for (int mf = 0; mf < 4; mf++)
      af[mf] = *(const short8*)(A + ((size_t)(m0 + mf * 16 + l15) * 256 + k0 + lq * 8));
#pragma unroll
    for (int nf = 0; nf < 4; nf++)
      bf[nf] = *(const short8*)(Bw + ((size_t)(n0 + nf * 16 + l15) * 256 + k0 + lq * 8));
#pragma unroll
    for (int mf = 0; mf < 4; mf++)
#pragma unroll
      for (int nf = 0; nf < 4; nf++)
        acc[mf][nf] = __builtin_amdgcn_mfma_f32_16x16x32_bf16(af[mf], bf[nf], acc[mf][nf], 0, 0, 0);
  }
#pragma unroll
  for (int nf = 0; nf < 4; nf++) {
    int o = n0 + nf * 16 + l15;
    float bi = bias[o];
    int ch = o / 20, t = o - ch * 20;
#pragma unroll
    for (int mf = 0; mf < 4; mf++) {
      int bb = m0 + mf * 16 + lq * 4;
#pragma unroll
      for (int r = 0; r < 4; r++)
        upT[((size_t)(bb + r) * 24 + 1 + t) * 128 + ch] = f2b(fmaxf(acc[mf][nf][r] + bi, 0.f));
    }
  }
}

// ================= decoder conv2 MFMA (sides merged; swizzled LDS skip tile) -> dc2T =======
// grid 1024 ; pitch 136 u16, 16 slots/row, slot' = (slot + 2*row) & 15
__global__ __launch_bounds__(256) void convd2_mfma(const u16* __restrict__ upT_s, const u16* __restrict__ upT_t,
                            const u16* __restrict__ b2T_s, const u16* __restrict__ b2T_t,
                            const u16* __restrict__ Wd2p, const float* __restrict__ bias,
                            u16* __restrict__ d2T_s, u16* __restrict__ d2T_t) {
  __shared__ u16 smem[90 * 136];
  int blk = blockIdx.x;
  int side = blk >> 9;
  int r = blk & 511;
  int b = r >> 1, wh = r & 1;
  const u16* upT   = side ? upT_t : upT_s;
  const u16* skipT = side ? b2T_s : b2T_t;           // cross skips
  u16* dc2T = side ? d2T_t : d2T_s;
  int tid = threadIdx.x, wid = tid >> 6, l = tid & 63;
  int l15 = l & 15, lq = l >> 4;
  int oc0 = wid * 16;
  int w0 = wh * 80;
  const u16* sb = skipT + (size_t)b * 176 * 128;
  for (int i = tid; i < 1440; i += 256) {            // 90 rows x 16 slots(16B)
    int row = i >> 4, seg = i & 15;
    int sl = (seg + 2 * row) & 15;
    *(uint4*)(&smem[row * 136 + sl * 8]) = *(const uint4*)(sb + ((size_t)(w0 + 3 + row)) * 128 + seg * 8);
  }
  __syncthreads();
  f32x4 zero = {0.f, 0.f, 0.f, 0.f};
  f32x4 acc[5];
#pragma unroll
  for (int j = 0; j < 5; j++) acc[j] = zero;
  const u16* ub = upT + (size_t)b * 24 * 128;
  for (int k = 0; k < 11; k++) {
    for (int ic0 = 0; ic0 < 128; ic0 += 32) {
      short8 a = *(const short8*)(Wd2p + ((k * 64 + oc0 + l15) * 256 + ic0 + lq * 8));
#pragma unroll
      for (int nf = 0; nf < 5; nf++) {
        int w = w0 + nf * 16 + l15;
        int rr = (w + k + 3) >> 3;
        short8 bf = *(const short8*)(ub + (rr * 128 + ic0 + lq * 8));
        acc[nf] = __builtin_amdgcn_mfma_f32_16x16x32_bf16(a, bf, acc[nf], 0, 0, 0);
      }
    }
    for (int ic0 = 0; ic0 < 128; ic0 += 32) {
      short8 a = *(const short8*)(Wd2p + ((k * 64 + oc0 + l15) * 256 + 128 + ic0 + lq * 8));
#pragma unroll
      for (int nf = 0; nf < 5; nf++) {
        int lrow = nf * 16 + l15 + k;
        int sl = ((ic0 >> 3) + lq + 2 * lrow) & 15;
        short8 bf = *(const short8*)(&smem[lrow * 136 + (sl << 3)]);
        acc[nf] = __builtin_amdgcn_mfma_f32_16x16x32_bf16(a, bf, acc[nf], 0, 0, 0);
      }
    }
  }
  int ocb = oc0 + lq * 4;
  float bb0 = bias[ocb], bb1 = bias[ocb + 1], bb2 = bias[ocb + 2], bb3 = bias[ocb + 3];
#pragma unroll
  for (int nf = 0; nf < 5; nf++) {
    int w = w0 + nf * 16 + l15;
    uint2 st;
    st.x = (unsigned)f2b(fmaxf(acc[nf][0] + bb0, 0.f)) | ((unsigned)f2b(fmaxf(acc[nf][1] + bb1, 0.f)) << 16);
    st.y = (unsigned)f2b(fmaxf(acc[nf][2] + bb2, 0.f)) | ((unsigned)f2b(fmaxf(acc[nf][3] + bb3, 0.f)) << 16);
    *(uint2*)(dc2T + ((size_t)b * 162 + w + 1) * 64 + ocb) = st;
  }
}

// ================= decoder conv1 MFMA (sides merged; swizzled LDS back1T tile) -> d_out ====
// pitch 72 u16, 8 slots/row, slot' = (slot + 2*row) & 7
__global__ __launch_bounds__(256) void convd1_mfma(const u16* __restrict__ d2T_s, const u16* __restrict__ d2T_t,
                            const u16* __restrict__ b1T_s, const u16* __restrict__ b1T_t,
                            const u16* __restrict__ Wd1p, const float* __restrict__ bias,
                            float* __restrict__ out_s, float* __restrict__ out_t) {
  __shared__ u16 smem[330 * 72];
  int blk = blockIdx.x;                              // 2048
  int side = blk >> 10;
  int r = blk & 1023;
  int b = r >> 2, q = r & 3;
  const u16* dc2T   = side ? d2T_t : d2T_s;
  const u16* back1T = side ? b1T_s : b1T_t;          // cross skips
  float* out = side ? out_t : out_s;
  int tid = threadIdx.x, wid = tid >> 6, l = tid & 63;
  int l15 = l & 15, lq = l >> 4;
  int base = q * 320;
  int wloc0 = wid * 80;
  const u16* sb = back1T + (size_t)b * 1296 * 64;
  for (int i = tid; i < 2640; i += 256) {            // 330 rows x 8 slots(16B)
    int row = i >> 3, seg = i & 7;
    int sl = (seg + 2 * row) & 7;
    *(uint4*)(&smem[row * 72 + sl * 8]) = *(const uint4*)(sb + ((size_t)(base + row)) * 64 + seg * 8);
  }
  __syncthreads();
  f32x4 zero = {0.f, 0.f, 0.f, 0.f};
  f32x4 acc[5];
#pragma unroll
  for (int j = 0; j < 5; j++) acc[j] = zero;
  const u16* ub = dc2T + (size_t)b * 162 * 64;
  for (int k = 0; k < 11; k++) {
#pragma unroll
    for (int ch = 0; ch < 2; ch++) {
      short8 wf = *(const short8*)(Wd1p + ((k * 4 + ch) * 16 + l15) * 32 + lq * 8);
#pragma unroll
      for (int nf = 0; nf < 5; nf++) {
        int w = base + wloc0 + nf * 16 + l15;
        int rr = (w + k + 3) >> 3;
        short8 af = *(const short8*)(ub + (rr * 64 + ch * 32 + lq * 8));
        acc[nf] = __builtin_amdgcn_mfma_f32_16x16x32_bf16(af, wf, acc[nf], 0, 0, 0);
      }
    }
#pragma unroll
    for (int ch = 0; ch < 2; ch++) {
      short8 wf = *(const short8*)(Wd1p + ((k * 4 + 2 + ch) * 16 + l15) * 32 + lq * 8);
#pragma unroll
      for (int nf = 0; nf < 5; nf++) {
        int lrow = wloc0 + nf * 16 + l15 + k;
        int sl = (ch * 4 + lq + 2 * lrow) & 7;
        short8 af = *(const short8*)(&smem[lrow * 72 + (sl << 3)]);
        acc[nf] = __builtin_amdgcn_mfma_f32_16x16x32_bf16(af, wf, acc[nf], 0, 0, 0);
      }
    }
  }
  if (l15 < 2) {
    float bi = bias[l15];
    float* ob = out + ((size_t)b * 2 + l15) * 1280;
#pragma unroll
    for (int nf = 0; nf < 5; nf++) {
      int wbase = base + wloc0 + nf * 16 + lq * 4;
      float4 v;
      v.x = fmaxf(acc[nf][0] + bi, 0.f);
      v.y = fmaxf(acc[nf][1] + bi, 0.f);
      v.z = fmaxf(acc[nf][2] + bi, 0.f);
      v.w = fmaxf(acc[nf][3] + bi, 0.f);
      *(float4*)(ob + wbase) = v;
    }
  }
}

// ================= KL: sort -> build -> pair-dots -> finalize =================
__global__ void kl_sort_k(const int* __restrict__ lab_s, const int* __restrict__ lab_t,
                          int* __restrict__ srt) {
  int t = threadIdx.x;
  {
    int lab = lab_s[t];
    int pos = 0;
    for (int b = 0; b < BB; b++) {
      int lb = lab_s[b];
      pos += (lb < lab) + ((b < t) && (lb == lab));
    }
    srt[pos] = t;
  }
  {
    int lab = lab_t[t];
    int pos = 0;
    for (int b = 0; b < BB; b++) {
      int lb = lab_t[b];
      pos += (lb < lab) + ((b < t) && (lb == lab));
    }
    srt[256 + pos] = t;
  }
}

__global__ void kl_build_k(const float* __restrict__ fea_s, const float* __restrict__ fea_t,
                           const int* __restrict__ srt,
                           float* __restrict__ T, float* __restrict__ logT) {
  int idx = blockIdx.x * 256 + threadIdx.x;
#pragma unroll
  for (int r = 0; r < 4; r++) {
    int e = idx + r * 8192;
    int d = e & 63;
    int m = (e >> 6) & 63;
    int l = e >> 12;
    float v;
    if (m < GSc) v = fea_s[srt[l * GSc + m] * DDc + d];
    else         v = fea_t[srt[256 + l * GSc + (m - GSc)] * DDc + d];
    T[e]    = v;
    logT[e] = logf(v);
  }
}

__global__ void kl_pairs_k(const float* __restrict__ T, const float* __restrict__ logT,
                           float* __restrict__ C) {
  int blk = blockIdx.x;
  int i = blk >> 3, j = blk & 7;
  int t = threadIdx.x;
  __shared__ float wsum[4];
  const float* li = logT + i * 4096;
  const float* tj = T + j * 4096;
  float s = 0.f;
  for (int e = t; e < 4096; e += 256) s += li[e] * tj[e];
  for (int off = 32; off > 0; off >>= 1) s += __shfl_down(s, off, 64);
  if ((t & 63) == 0) wsum[t >> 6] = s;
  __syncthreads();
  if (t == 0) C[blk] = wsum[0] + wsum[1] + wsum[2] + wsum[3];
}

__global__ void kl_final_k(const float* __restrict__ C, float* __restrict__ out) {
  int t = threadIdx.x;
  float c = C[t];
  float tr = ((t >> 3) == (t & 7)) ? c : 0.f;
  for (int off = 32; off > 0; off >>= 1) {
    c  += __shfl_down(c, off, 64);
    tr += __shfl_down(tr, off, 64);
  }
  if (t == 0) out[0] = (LLc * tr - c) / 4096.f / (LLc * LLc / 2.0f);
}

extern "C" void kernel_launch(void* const* d_in, const int* in_sizes, int n_in,
                              void* d_out, int out_size, void* d_ws, size_t ws_size,
                              hipStream_t stream) {
  const float* x_s  = (const float*)d_in[0];
  const float* x_t  = (const float*)d_in[1];
  const int* lab_s  = (const int*)d_in[2];
  const int* lab_t  = (const int*)d_in[3];
  const float* ec1w = (const float*)d_in[5];  const float* ec1b = (const float*)d_in[6];
  const float* ec2w = (const float*)d_in[7];  const float* ec2b = (const float*)d_in[8];
  const float* ef1w = (const float*)d_in[9];  const float* ef1b = (const float*)d_in[10];
  const float* ef2w = (const float*)d_in[11]; const float* ef2b = (const float*)d_in[12];
  const float* df1w = (const float*)d_in[13]; const float* df1b = (const float*)d_in[14];
  const float* df2w = (const float*)d_in[15]; const float* df2b = (const float*)d_in[16];
  const float* dc2w = (const float*)d_in[17]; const float* dc2b = (const float*)d_in[18];
  const float* dc1w = (const float*)d_in[19]; const float* dc1b = (const float*)d_in[20];

  char* p = (char*)d_ws;
  auto alloc = [&](size_t bytes) -> char* {
    char* r = p;
    p += (bytes + 255) & ~(size_t)255;
    return r;
  };
  u16*   b1T_s   = (u16*)alloc((size_t)BB * 1296 * 64 * 2);
  u16*   b1T_t   = (u16*)alloc((size_t)BB * 1296 * 64 * 2);
  u16*   xcol_s  = (u16*)alloc((size_t)BB * 1280 * 32 * 2);
  u16*   xcol_t  = (u16*)alloc((size_t)BB * 1280 * 32 * 2);
  u16*   p1T_s   = (u16*)alloc((size_t)BB * 176 * 64 * 2);
  u16*   p1T_t   = (u16*)alloc((size_t)BB * 176 * 64 * 2);
  u16*   b2T_s   = (u16*)alloc((size_t)BB * 176 * 128 * 2);
  u16*   b2T_t   = (u16*)alloc((size_t)BB * 176 * 128 * 2);
  u16*   upT_s   = (u16*)alloc((size_t)BB * 24 * 128 * 2);
  u16*   upT_t   = (u16*)alloc((size_t)BB * 24 * 128 * 2);
  u16*   p2bf_s  = (u16*)alloc((size_t)BB * 2560 * 2);
  u16*   p2bf_t  = (u16*)alloc((size_t)BB * 2560 * 2);
  float* ef1_s   = (float*)alloc((size_t)BB * 512 * 4);
  float* ef1_t   = (float*)alloc((size_t)BB * 512 * 4);
  float* fea_s   = (float*)alloc((size_t)BB * 64 * 4);
  float* fea_t   = (float*)alloc((size_t)BB * 64 * 4);
  u16*   df1bf_s = (u16*)alloc((size_t)BB * 256 * 2);
  u16*   df1bf_t = (u16*)alloc((size_t)BB * 256 * 2);
  u16*   d2T_s   = (u16*)alloc((size_t)BB * 162 * 64 * 2);
  u16*   d2T_t   = (u16*)alloc((size_t)BB * 162 * 64 * 2);
  u16*   W2p     = (u16*)alloc(90112 * 2);
  u16*   Wd2p    = (u16*)alloc(180224 * 2);
  u16*   Wd1p    = (u16*)alloc(22528 * 2);
  u16*   ef1wbf  = (u16*)alloc((size_t)1310720 * 2);
  u16*   df2wbf  = (u16*)alloc((size_t)655360 * 2);
  u16*   W1p     = (u16*)alloc(2048 * 2);
  float* Tbuf    = (float*)alloc((size_t)32768 * 4);
  float* logTbuf = (float*)alloc((size_t)32768 * 4);
  int*   srt     = (int*)alloc(512 * 4);
  float* Cbuf    = (float*)alloc(64 * 4);
  // pbuf (8 MB) aliases xcol_s (xcol lifetime ends at conv1_mfma; ef1_split runs after).
  float* pbuf    = (float*)xcol_s;

  float* out_s  = (float*)d_out;
  float* out_t  = out_s + (size_t)BB * 2 * 1280;
  float* out_kl = out_s + (size_t)2 * BB * 2 * 1280;

  dim3 blk(256);

  prep_k<<<dim3(16256), blk, 0, stream>>>(ec2w, dc2w, dc1w, ef1w, df2w, ec1w,
                                          W2p, Wd2p, Wd1p, ef1wbf, df2wbf, W1p,
                                          upT_s, upT_t, b2T_s, b2T_t,
                                          b1T_s, b1T_t, d2T_s, d2T_t);

  // encoders (sides merged)
  im2col1_k<<<dim3(640), blk, 0, stream>>>(x_s, x_t, xcol_s, xcol_t);
  conv1_mfma<<<dim3(2048), blk, 0, stream>>>(xcol_s, xcol_t, W1p, ec1b, b1T_s, b1T_t);
  pool1T_k<<<dim3(22528), blk, 0, stream>>>(b1T_s, b1T_t, p1T_s, p1T_t);
  conv2_split<<<dim3(2048), blk, 0, stream>>>(p1T_s, p1T_t, W2p, ec2b, b2T_s, b2T_t);
  pool2_k<<<dim3(5120), blk, 0, stream>>>(b2T_s, b2T_t, p2bf_s, p2bf_t);
  ef1_split<<<dim3(512), blk, 0, stream>>>(p2bf_s, p2bf_t, ef1wbf, pbuf);
  ef1_red<<<dim3(1024), blk, 0, stream>>>(pbuf, ef1b, ef1_s, ef1_t);
  ef2df1_k<<<dim3(512), blk, 0, stream>>>(ef1_s, ef1_t, ef2w, ef2b, df1w, df1b,
                                          fea_s, fea_t, df1bf_s, df1bf_t);

  // decoders
  df2_gemm<<<dim3(80), blk, 0, stream>>>(df1bf_s, df1bf_t, df2wbf, df2b, upT_s, upT_t);
  convd2_mfma<<<dim3(1024), blk, 0, stream>>>(upT_s, upT_t, b2T_s, b2T_t, Wd2p, dc2b, d2T_s, d2T_t);
  convd1_mfma<<<dim3(2048), blk, 0, stream>>>(d2T_s, d2T_t, b1T_s, b1T_t, Wd1p, dc1b, out_s, out_t);

  // pairwise KL
  kl_sort_k<<<dim3(1), blk, 0, stream>>>(lab_s, lab_t, srt);
  kl_build_k<<<dim3(32), blk, 0, stream>>>(fea_s, fea_t, srt, Tbuf, logTbuf);
  kl_pairs_k<<<dim3(64), blk, 0, stream>>>(Tbuf, logTbuf, Cbuf);
  kl_final_k<<<dim3(1), dim3(64), 0, stream>>>(Cbuf, out_kl);
}